// Round 10
// baseline (735.139 us; speedup 1.0000x reference)
//
#include <hip/hip_runtime.h>
#include <math.h>

// ---------------------------------------------------------------------------
// FastImageMamba forward. R10: R9 + __launch_bounds__(256,2) on MFMA kernels
// (R9's conv2 BK=64 spilled its reg-dbuf to scratch: VGPR=56, WRITE 116MB).
// B=4, DM=256, NL=4, NC=1000, DI=512, NS=16, DTR=32, K=4, L=1024, H=W=64
// ---------------------------------------------------------------------------

#define BN_RSQ 0.99999500003749969f   // 1/sqrt(1+1e-5)

typedef unsigned int uint;
typedef unsigned short ushort;
typedef __bf16 bf16x8 __attribute__((ext_vector_type(8)));
typedef float floatx4 __attribute__((ext_vector_type(4)));

__device__ __forceinline__ float gelu_f(float v) {
    return 0.5f * v * (1.0f + erff(v * 0.70710678118654752f));
}
__device__ __forceinline__ float softplus_f(float v) {
    return (v > 20.f) ? v : log1pf(expf(v));
}
__device__ __forceinline__ ushort f2bf(float f) {
    uint x = __float_as_uint(f);
    x += 0x7fffu + ((x >> 16) & 1u);
    return (ushort)(x >> 16);
}
__device__ __forceinline__ float bf2f(ushort u) {
    return __uint_as_float((uint)u << 16);
}

// ---------------------------------------------------------------------------
// Fused weight prep: all fp32->bf16 weight conversions in one dispatch.
// ---------------------------------------------------------------------------
__global__ void wprep(const float* __restrict__ ipw, const float* __restrict__ opw,
                      const float* __restrict__ c2w, const float* __restrict__ pw,
                      const float* __restrict__ xpw,
                      ushort* __restrict__ ipwb, ushort* __restrict__ opwb,
                      ushort* __restrict__ w2b, ushort* __restrict__ pwTb,
                      ushort* __restrict__ xpwb)
{
    int idx = blockIdx.x * 256 + threadIdx.x;
    if (idx < 1048576) {
        ipwb[idx] = f2bf(ipw[idx]);
    } else if (idx < 1572864) {
        int i = idx - 1048576;
        opwb[i] = f2bf(opw[i]);
    } else if (idx < 1867776) {
        int i = idx - 1572864;
        int oc = i / 1152, k = i % 1152;
        int s = k >> 7, ic = k & 127;
        w2b[i] = f2bf(c2w[(size_t)(oc * 128 + ic) * 9 + s]);
    } else if (idx < 2129920) {
        int i = idx - 1867776;
        int oc = i >> 10, k = i & 1023;
        int s = k >> 8, ic = k & 255;
        int ky = s >> 1, kx = s & 1;
        pwTb[i] = f2bf(pw[((size_t)(oc * 256 + ic) * 2 + ky) * 2 + kx]);
    } else if (idx < 2260992) {
        int i = idx - 2129920;
        xpwb[i] = f2bf(xpw[i]);
    }
}

// ---------------------------------------------------------------------------
// conv1: 3x3 s1p1, IC=3 -> OC=128, NCHW fp32 in, NHWC bf16 out (+bias+BN+GELU)
// ---------------------------------------------------------------------------
__global__ __launch_bounds__(256) void conv1_nhwc(
    const float* __restrict__ x, const float* __restrict__ w,
    const float* __restrict__ cb, const float* __restrict__ g,
    const float* __restrict__ bb, ushort* __restrict__ out)
{
    __shared__ float tin[3][3][64];
    __shared__ float ws[3456];
    int t = threadIdx.x;
    int b = blockIdx.x >> 6, y = blockIdx.x & 63;
    for (int i = t; i < 3456; i += 256) ws[i] = w[i];
    for (int i = t; i < 576; i += 256) {
        int ic = i / 192, r = (i >> 6) % 3, xx = i & 63;
        int gy = y + r - 1;
        tin[ic][r][xx] = ((unsigned)gy < 64u) ? x[((b * 3 + ic) * 64 + gy) * 64 + xx] : 0.f;
    }
    __syncthreads();
    int tx = t & 15, ty = t >> 4;
    int oc0 = tx * 8, px0 = ty * 4;
    float acc[4][8];
    #pragma unroll
    for (int p = 0; p < 4; ++p)
        #pragma unroll
        for (int o = 0; o < 8; ++o) acc[p][o] = 0.f;
    for (int ic = 0; ic < 3; ++ic)
        #pragma unroll
        for (int ky = 0; ky < 3; ++ky)
            #pragma unroll
            for (int kx = 0; kx < 3; ++kx) {
                float av[4];
                #pragma unroll
                for (int p = 0; p < 4; ++p) {
                    int xx = px0 + p + kx - 1;
                    av[p] = ((unsigned)xx < 64u) ? tin[ic][ky][xx] : 0.f;
                }
                #pragma unroll
                for (int o = 0; o < 8; ++o) {
                    float wv = ws[(oc0 + o) * 27 + ic * 9 + ky * 3 + kx];
                    #pragma unroll
                    for (int p = 0; p < 4; ++p) acc[p][o] = fmaf(av[p], wv, acc[p][o]);
                }
            }
    #pragma unroll
    for (int p = 0; p < 4; ++p) {
        uint pk[4];
        #pragma unroll
        for (int o2 = 0; o2 < 4; ++o2) {
            int oc = oc0 + o2 * 2;
            float v0 = gelu_f((acc[p][o2 * 2] + cb[oc]) * (g[oc] * BN_RSQ) + bb[oc]);
            float v1 = gelu_f((acc[p][o2 * 2 + 1] + cb[oc + 1]) * (g[oc + 1] * BN_RSQ) + bb[oc + 1]);
            pk[o2] = (uint)f2bf(v0) | ((uint)f2bf(v1) << 16);
        }
        uint4 vv = make_uint4(pk[0], pk[1], pk[2], pk[3]);
        *(uint4*)(out + ((size_t)((b * 64 + y) * 64 + px0 + p)) * 128 + oc0) = vv;
    }
}

// ---------------------------------------------------------------------------
// bf16 MFMA GEMM (A @ W^T), BMxBN tile, BK=32, 4 waves (2x2), reg dbuf.
// EPI: 0 = +bias -> fp32 Cf[ldc]
//      2 = +bias,BN,GELU -> fp32 Cf + bf16 Cb (same ldc)
//      3 = in_proj: n<512 -> bf16 Cb[m*512+n]; n>=512 -> bf16 silu -> Cb2
// launch_bounds(256,2): VGPR budget 256/wave -- reg dbuf must not spill.
// ---------------------------------------------------------------------------
template<int BM, int BN, int EPI>
__global__ __launch_bounds__(256, 2) void mfma_gemm_bt(
    const ushort* __restrict__ A, int lda,
    const ushort* __restrict__ W, int ldw,
    const float* __restrict__ bias,
    const float* __restrict__ bnG, const float* __restrict__ bnB,
    float* __restrict__ Cf, ushort* __restrict__ Cb, ushort* __restrict__ Cb2,
    int ldc, int K)
{
    constexpr int PAD = 40;
    constexpr int AP = BM / 64;
    constexpr int BP = BN / 64;
    constexpr int FM = BM / 32;
    constexpr int FN = BN / 32;
    __shared__ __align__(16) ushort As[BM * PAD];
    __shared__ __align__(16) ushort Bs[BN * PAD];
    int t = threadIdx.x;
    int m0 = blockIdx.x * BM, n0 = blockIdx.y * BN;
    int lane = t & 63, wid = t >> 6;
    int wm = (wid & 1) * (BM / 2), wn = (wid >> 1) * (BN / 2);
    int fr = lane & 15, fk = (lane >> 4) * 8;
    int r0 = t >> 2, c0 = (t & 3) * 8;
    floatx4 acc[FM][FN];
    #pragma unroll
    for (int i = 0; i < FM; ++i)
        #pragma unroll
        for (int j = 0; j < FN; ++j) acc[i][j] = {0.f, 0.f, 0.f, 0.f};
    uint4 ra[AP], rb[BP];
    #pragma unroll
    for (int p = 0; p < AP; ++p)
        ra[p] = *(const uint4*)(A + (size_t)(m0 + r0 + p * 64) * lda + c0);
    #pragma unroll
    for (int p = 0; p < BP; ++p)
        rb[p] = *(const uint4*)(W + (size_t)(n0 + r0 + p * 64) * ldw + c0);
    for (int k0 = 0; k0 < K; k0 += 32) {
        __syncthreads();
        #pragma unroll
        for (int p = 0; p < AP; ++p) *(uint4*)&As[(r0 + p * 64) * PAD + c0] = ra[p];
        #pragma unroll
        for (int p = 0; p < BP; ++p) *(uint4*)&Bs[(r0 + p * 64) * PAD + c0] = rb[p];
        __syncthreads();
        if (k0 + 32 < K) {
            #pragma unroll
            for (int p = 0; p < AP; ++p)
                ra[p] = *(const uint4*)(A + (size_t)(m0 + r0 + p * 64) * lda + k0 + 32 + c0);
            #pragma unroll
            for (int p = 0; p < BP; ++p)
                rb[p] = *(const uint4*)(W + (size_t)(n0 + r0 + p * 64) * ldw + k0 + 32 + c0);
        }
        bf16x8 af[FM], bw[FN];
        #pragma unroll
        for (int i = 0; i < FM; ++i)
            af[i] = *(const bf16x8*)&As[(wm + i * 16 + fr) * PAD + fk];
        #pragma unroll
        for (int j = 0; j < FN; ++j)
            bw[j] = *(const bf16x8*)&Bs[(wn + j * 16 + fr) * PAD + fk];
        #pragma unroll
        for (int i = 0; i < FM; ++i)
            #pragma unroll
            for (int j = 0; j < FN; ++j)
                acc[i][j] = __builtin_amdgcn_mfma_f32_16x16x32_bf16(af[i], bw[j], acc[i][j], 0, 0, 0);
    }
    int rbase = (lane >> 4) * 4, cc = lane & 15;
    #pragma unroll
    for (int j = 0; j < FN; ++j) {
        int n = n0 + wn + j * 16 + cc;
        float bv = bias ? bias[n] : 0.f;
        float scl = 0.f, shf = 0.f;
        if (EPI == 2) { scl = bnG[n] * BN_RSQ; shf = bnB[n]; }
        #pragma unroll
        for (int i = 0; i < FM; ++i) {
            #pragma unroll
            for (int r = 0; r < 4; ++r) {
                int m = m0 + wm + i * 16 + rbase + r;
                float v = acc[i][j][r] + bv;
                if (EPI == 2) v = gelu_f(v * scl + shf);
                if (EPI == 0) {
                    Cf[(size_t)m * ldc + n] = v;
                } else if (EPI == 2) {
                    Cf[(size_t)m * ldc + n] = v;
                    Cb[(size_t)m * ldc + n] = f2bf(v);
                } else {
                    if (n < 512) Cb[(size_t)m * 512 + n] = f2bf(v);
                    else Cb2[(size_t)m * 512 + (n - 512)] = f2bf(v / (1.f + __expf(-v)));
                }
            }
        }
    }
}

// ---------------------------------------------------------------------------
// conv2: 9-shift implicit MFMA GEMM, 128px x 64oc tile, BK=64 (18 steps),
// reg dbuf. grid (128,4). launch_bounds(256,2) to avoid scratch spill.
// ---------------------------------------------------------------------------
__global__ __launch_bounds__(256, 2) void conv2_mfma(
    const ushort* __restrict__ h1b, const ushort* __restrict__ w2b,
    const float* __restrict__ cb, const float* __restrict__ g,
    const float* __restrict__ bb, ushort* __restrict__ h2b)
{
    constexpr int PAD = 72;
    __shared__ __align__(16) ushort As[128 * PAD];
    __shared__ __align__(16) ushort Bs[64 * PAD];
    int t = threadIdx.x;
    int m0 = blockIdx.x * 128, n0 = blockIdx.y * 64;
    int b = m0 >> 12;
    int y0 = (m0 & 4095) >> 6;
    int lane = t & 63, wid = t >> 6;
    int wm = (wid & 1) * 64, wn = (wid >> 1) * 32;
    int fr = lane & 15, fk = (lane >> 4) * 8;
    int ra_row = t >> 1, ra_c = (t & 1) * 32;
    int rb_row = t >> 2, rb_c = (t & 3) * 16;
    floatx4 acc[4][2];
    #pragma unroll
    for (int i = 0; i < 4; ++i)
        #pragma unroll
        for (int j = 0; j < 2; ++j) acc[i][j] = {0.f, 0.f, 0.f, 0.f};
    const ushort* hb = h1b + (size_t)b * 4096 * 128;

    auto load_step = [&](int step, uint4 (&ra)[4], uint4 (&rb)[2]) {
        int s = step >> 1, ich = (step & 1) * 64;
        int ky = s / 3, kx = s % 3;
        int sy = y0 + (ra_row >> 6) + ky - 1;
        int sx = (ra_row & 63) + kx - 1;
        bool v = ((unsigned)sy < 64u) && ((unsigned)sx < 64u);
        const ushort* ap = hb + ((size_t)(sy * 64 + sx)) * 128 + ich + ra_c;
        uint4 zz = make_uint4(0u, 0u, 0u, 0u);
        #pragma unroll
        for (int q = 0; q < 4; ++q) ra[q] = v ? *(const uint4*)(ap + q * 8) : zz;
        const ushort* wp = w2b + (size_t)(n0 + rb_row) * 1152 + s * 128 + ich + rb_c;
        #pragma unroll
        for (int q = 0; q < 2; ++q) rb[q] = *(const uint4*)(wp + q * 8);
    };

    uint4 ra[4], rb[2];
    load_step(0, ra, rb);
    for (int step = 0; step < 18; ++step) {
        __syncthreads();
        #pragma unroll
        for (int q = 0; q < 4; ++q) *(uint4*)&As[ra_row * PAD + ra_c + q * 8] = ra[q];
        #pragma unroll
        for (int q = 0; q < 2; ++q) *(uint4*)&Bs[rb_row * PAD + rb_c + q * 8] = rb[q];
        __syncthreads();
        if (step + 1 < 18) load_step(step + 1, ra, rb);
        #pragma unroll
        for (int ks = 0; ks < 64; ks += 32) {
            bf16x8 af[4], bw[2];
            #pragma unroll
            for (int i = 0; i < 4; ++i)
                af[i] = *(const bf16x8*)&As[(wm + i * 16 + fr) * PAD + ks + fk];
            #pragma unroll
            for (int j = 0; j < 2; ++j)
                bw[j] = *(const bf16x8*)&Bs[(wn + j * 16 + fr) * PAD + ks + fk];
            #pragma unroll
            for (int i = 0; i < 4; ++i)
                #pragma unroll
                for (int j = 0; j < 2; ++j)
                    acc[i][j] = __builtin_amdgcn_mfma_f32_16x16x32_bf16(af[i], bw[j], acc[i][j], 0, 0, 0);
        }
    }
    int rbase = (lane >> 4) * 4, cc = lane & 15;
    #pragma unroll
    for (int j = 0; j < 2; ++j) {
        int n = n0 + wn + j * 16 + cc;
        float scl = g[n] * BN_RSQ, shf = bb[n], bv2 = cb[n];
        #pragma unroll
        for (int i = 0; i < 4; ++i) {
            #pragma unroll
            for (int r = 0; r < 4; ++r) {
                int m = m0 + wm + i * 16 + rbase + r;
                float v = gelu_f((acc[i][j][r] + bv2) * scl + shf);
                h2b[(size_t)m * 256 + n] = f2bf(v);
            }
        }
    }
}

// Apb[m][s*256+ic] = h2b[b, 2oy+ky, 2ox+kx, ic]
__global__ void im2col_bf16(const ushort* __restrict__ h2b, ushort* __restrict__ Apb)
{
    int idx = blockIdx.x * 256 + threadIdx.x;          // 524288 uint4 chunks
    int k8 = idx & 127;
    int m = idx >> 7;
    int b = m >> 10, oy = (m >> 5) & 31, ox = m & 31;
    int s = k8 >> 5, ic8 = k8 & 31;
    int ky = s >> 1, kx = s & 1;
    uint4 v = *(const uint4*)(h2b + ((size_t)(b * 4096 + (2 * oy + ky) * 64 + 2 * ox + kx)) * 256 + ic8 * 8);
    *(uint4*)(Apb + (size_t)m * 1024 + k8 * 8) = v;
}

// ---------------------------------------------------------------------------
// fp32 tiled GEMM (reg dbuf): C[m*ldc+n] = act(A @ W^T + bias). act 0/2.
// ---------------------------------------------------------------------------
template<int BM, int BN, int BK, int TM, int TN>
__global__ __launch_bounds__(256) void gemm_kernel(
    const float* __restrict__ A, int lda,
    const float* __restrict__ W, int ldw,
    const float* __restrict__ bias,
    float* __restrict__ C, int ldc,
    int M, int N, int K, int act)
{
    static_assert(BM * BK / 4 == 256 && BN * BK / 4 == 256, "staging shape");
    __shared__ float As[BK][BM + 4];
    __shared__ float Bs[BK][BN + 4];
    int t = threadIdx.x;
    int m0 = blockIdx.x * BM, n0 = blockIdx.y * BN;
    float acc[TM][TN];
    #pragma unroll
    for (int i = 0; i < TM; i++)
        #pragma unroll
        for (int j = 0; j < TN; j++) acc[i][j] = 0.f;
    const int LPR = BK / 4;
    int lr = t / LPR, lc4 = (t % LPR) * 4;
    int ty = t >> 4, tx = t & 15;
    int ma = m0 + lr, nb = n0 + lr;
    float4 va = make_float4(0.f, 0.f, 0.f, 0.f);
    float4 vb = make_float4(0.f, 0.f, 0.f, 0.f);
    if (ma < M) va = *(const float4*)(A + (size_t)ma * lda + lc4);
    if (nb < N) vb = *(const float4*)(W + (size_t)nb * ldw + lc4);
    for (int k0 = 0; k0 < K; k0 += BK) {
        __syncthreads();
        As[lc4 + 0][lr] = va.x; As[lc4 + 1][lr] = va.y;
        As[lc4 + 2][lr] = va.z; As[lc4 + 3][lr] = va.w;
        Bs[lc4 + 0][lr] = vb.x; Bs[lc4 + 1][lr] = vb.y;
        Bs[lc4 + 2][lr] = vb.z; Bs[lc4 + 3][lr] = vb.w;
        __syncthreads();
        if (k0 + BK < K) {
            if (ma < M) va = *(const float4*)(A + (size_t)ma * lda + k0 + BK + lc4);
            if (nb < N) vb = *(const float4*)(W + (size_t)nb * ldw + k0 + BK + lc4);
        }
        #pragma unroll
        for (int kk = 0; kk < BK; ++kk) {
            float a[TM], bfr[TN];
            #pragma unroll
            for (int i = 0; i < TM; i += 4)
                *(float4*)&a[i] = *(const float4*)&As[kk][ty * TM + i];
            #pragma unroll
            for (int j = 0; j < TN; j += 4)
                *(float4*)&bfr[j] = *(const float4*)&Bs[kk][tx * TN + j];
            #pragma unroll
            for (int i = 0; i < TM; i++)
                #pragma unroll
                for (int j = 0; j < TN; j++) acc[i][j] = fmaf(a[i], bfr[j], acc[i][j]);
        }
    }
    #pragma unroll
    for (int i = 0; i < TM; i++) {
        int m = m0 + ty * TM + i;
        if (m >= M) continue;
        #pragma unroll
        for (int j = 0; j < TN; j++) {
            int n = n0 + tx * TN + j;
            if (n >= N) continue;
            float v = acc[i][j];
            if (bias) v += bias[n];
            if (act == 2) v = softplus_f(v);
            C[(size_t)m * ldc + n] = v;
        }
    }
}

// ---------------------------------------------------------------------------
// Depthwise conv1d (K=4, pad(1,2)) in [b,l,d], bf16 input xib.
// Outputs xl fp32 (scan u) + xlb bf16 (x_proj A).
// ---------------------------------------------------------------------------
__global__ __launch_bounds__(256) void dwconv(
    const ushort* __restrict__ xib, const float* __restrict__ cw,
    const float* __restrict__ cb, float* __restrict__ xl, ushort* __restrict__ xlb)
{
    int idx = blockIdx.x * 256 + threadIdx.x;   // 524288
    int d4 = (idx & 127) * 4;
    int bl = idx >> 7;
    int b = bl >> 10, l = bl & 1023;
    float4 w0 = *(const float4*)(cw + d4 * 4);
    float4 w1 = *(const float4*)(cw + d4 * 4 + 4);
    float4 w2 = *(const float4*)(cw + d4 * 4 + 8);
    float4 w3 = *(const float4*)(cw + d4 * 4 + 12);
    float4 acc = *(const float4*)(cb + d4);
    const ushort* rowb = xib + ((size_t)b << 19) + d4;
    #pragma unroll
    for (int k = 0; k < 4; ++k) {
        int ll = l + k - 1;
        if ((unsigned)ll < 1024u) {
            uint2 p = *(const uint2*)(rowb + (size_t)ll * 512);
            acc.x = fmaf(bf2f((ushort)(p.x & 0xffffu)), ((const float*)&w0)[k], acc.x);
            acc.y = fmaf(bf2f((ushort)(p.x >> 16)),     ((const float*)&w1)[k], acc.y);
            acc.z = fmaf(bf2f((ushort)(p.y & 0xffffu)), ((const float*)&w2)[k], acc.z);
            acc.w = fmaf(bf2f((ushort)(p.y >> 16)),     ((const float*)&w3)[k], acc.w);
        }
    }
    *(float4*)(xl + (size_t)bl * 512 + d4) = acc;
    uint2 pk;
    pk.x = (uint)f2bf(acc.x) | ((uint)f2bf(acc.y) << 16);
    pk.y = (uint)f2bf(acc.z) | ((uint)f2bf(acc.w) << 16);
    *(uint2*)(xlb + (size_t)bl * 512 + d4) = pk;
}

// ---------------------------------------------------------------------------
// Chunked scan pass 1. Block = (b, dgG, ch): 512 thr, 8 waves x 4 d = 32 d.
// ---------------------------------------------------------------------------
__global__ __launch_bounds__(512) void scan_part1(
    const float* __restrict__ delta, const float* __restrict__ u,
    const float* __restrict__ xdbl, const float* __restrict__ alog,
    float* __restrict__ Psum, float* __restrict__ hFsum)
{
    __shared__ float Td[32][132];
    __shared__ float Tu[32][132];
    __shared__ float TB[16][132];
    int t = threadIdx.x;
    int bid = blockIdx.x;                 // 512 = b(4) x dgG(16) x ch(8)
    int ch = bid & 7, dgG = (bid >> 3) & 15, b = bid >> 7;
    int d0 = dgG * 32;
    int bl0 = b * 1024 + ch * 128;
    #pragma unroll
    for (int r = 0; r < 2; ++r) {
        int idx = r * 512 + t;
        int l = idx >> 3, d4 = (idx & 7) * 4;
        float4 dv = *(const float4*)(delta + (size_t)(bl0 + l) * 512 + d0 + d4);
        float4 uv = *(const float4*)(u + (size_t)(bl0 + l) * 512 + d0 + d4);
        Td[d4 + 0][l] = dv.x; Td[d4 + 1][l] = dv.y; Td[d4 + 2][l] = dv.z; Td[d4 + 3][l] = dv.w;
        Tu[d4 + 0][l] = uv.x; Tu[d4 + 1][l] = uv.y; Tu[d4 + 2][l] = uv.z; Tu[d4 + 3][l] = uv.w;
    }
    {
        int l = t >> 2, n4 = (t & 3) * 4;
        float4 bv = *(const float4*)(xdbl + (size_t)(bl0 + l) * 64 + 32 + n4);
        TB[n4 + 0][l] = bv.x; TB[n4 + 1][l] = bv.y; TB[n4 + 2][l] = bv.z; TB[n4 + 3][l] = bv.w;
    }
    __syncthreads();
    int w = t >> 6, lane = t & 63;
    int dl = lane >> 4, n = lane & 15;
    int col = w * 4 + dl;
    int d = d0 + col;
    float Ac = -__expf(alog[d * 16 + n]);
    float h = 0.f, P = 1.f;
    for (int l4 = 0; l4 < 32; ++l4) {
        float4 de = *(const float4*)&Td[col][l4 * 4];
        float4 uu = *(const float4*)&Tu[col][l4 * 4];
        float4 Bv = *(const float4*)&TB[n][l4 * 4];
        float a;
        a = __expf(de.x * Ac); h = a * h + de.x * Bv.x * uu.x; P *= a;
        a = __expf(de.y * Ac); h = a * h + de.y * Bv.y * uu.y; P *= a;
        a = __expf(de.z * Ac); h = a * h + de.z * Bv.z * uu.z; P *= a;
        a = __expf(de.w * Ac); h = a * h + de.w * Bv.w * uu.w; P *= a;
    }
    size_t si = ((size_t)(b * 128 + dgG * 8 + w) * 8 + ch) * 64 + lane;
    Psum[si] = P;
    hFsum[si] = h;
}

// ---------------------------------------------------------------------------
// Chunked scan pass 2: combine summaries, rerun chunk, y + gate -> ybb bf16.
// ---------------------------------------------------------------------------
__global__ __launch_bounds__(512) void scan_part2(
    const float* __restrict__ delta, const float* __restrict__ u,
    const float* __restrict__ xdbl,
    const float* __restrict__ alog, const float* __restrict__ dssm,
    const ushort* __restrict__ resb, ushort* __restrict__ ybb,
    const float* __restrict__ Psum, const float* __restrict__ hFsum)
{
    __shared__ float Td[32][132];
    __shared__ float Tu[32][132];
    __shared__ float TB[16][132];
    __shared__ float TC[16][132];
    __shared__ float yb[128][33];
    int t = threadIdx.x;
    int bid = blockIdx.x;                 // 512 = b(4) x dgG(16) x ch(8)
    int ch = bid & 7, dgG = (bid >> 3) & 15, b = bid >> 7;
    int d0 = dgG * 32;
    int bl0 = b * 1024 + ch * 128;
    #pragma unroll
    for (int r = 0; r < 2; ++r) {
        int idx = r * 512 + t;
        int l = idx >> 3, d4 = (idx & 7) * 4;
        float4 dv = *(const float4*)(delta + (size_t)(bl0 + l) * 512 + d0 + d4);
        float4 uv = *(const float4*)(u + (size_t)(bl0 + l) * 512 + d0 + d4);
        Td[d4 + 0][l] = dv.x; Td[d4 + 1][l] = dv.y; Td[d4 + 2][l] = dv.z; Td[d4 + 3][l] = dv.w;
        Tu[d4 + 0][l] = uv.x; Tu[d4 + 1][l] = uv.y; Tu[d4 + 2][l] = uv.z; Tu[d4 + 3][l] = uv.w;
    }
    {
        int l = t >> 2, n4 = (t & 3) * 4;
        float4 bv = *(const float4*)(xdbl + (size_t)(bl0 + l) * 64 + 32 + n4);
        float4 cv = *(const float4*)(xdbl + (size_t)(bl0 + l) * 64 + 48 + n4);
        TB[n4 + 0][l] = bv.x; TB[n4 + 1][l] = bv.y; TB[n4 + 2][l] = bv.z; TB[n4 + 3][l] = bv.w;
        TC[n4 + 0][l] = cv.x; TC[n4 + 1][l] = cv.y; TC[n4 + 2][l] = cv.z; TC[n4 + 3][l] = cv.w;
    }
    __syncthreads();
    int w = t >> 6, lane = t & 63;
    int dl = lane >> 4, n = lane & 15;
    int col = w * 4 + dl;
    int d = d0 + col;
    float Ac = -__expf(alog[d * 16 + n]);
    float Dd = dssm[d];
    float h = 0.f;
    {
        size_t sbase = (size_t)(b * 128 + dgG * 8 + w) * 512 + lane;
        for (int cc = 0; cc < ch; ++cc) {
            float Pv = Psum[sbase + (size_t)cc * 64];
            float hv = hFsum[sbase + (size_t)cc * 64];
            h = Pv * h + hv;
        }
    }
    for (int l4 = 0; l4 < 32; ++l4) {
        float4 de = *(const float4*)&Td[col][l4 * 4];
        float4 uu = *(const float4*)&Tu[col][l4 * 4];
        float4 Bv = *(const float4*)&TB[n][l4 * 4];
        float4 Cv = *(const float4*)&TC[n][l4 * 4];
        float p0, p1, p2, p3;
        h = __expf(de.x * Ac) * h + de.x * Bv.x * uu.x; p0 = h * Cv.x;
        h = __expf(de.y * Ac) * h + de.y * Bv.y * uu.y; p1 = h * Cv.y;
        h = __expf(de.z * Ac) * h + de.z * Bv.z * uu.z; p2 = h * Cv.z;
        h = __expf(de.w * Ac) * h + de.w * Bv.w * uu.w; p3 = h * Cv.w;
        #pragma unroll
        for (int off = 1; off < 16; off <<= 1) {
            p0 += __shfl_xor(p0, off);
            p1 += __shfl_xor(p1, off);
            p2 += __shfl_xor(p2, off);
            p3 += __shfl_xor(p3, off);
        }
        if (n == 0) {
            int l = l4 * 4;
            yb[l + 0][col] = fmaf(uu.x, Dd, p0);
            yb[l + 1][col] = fmaf(uu.y, Dd, p1);
            yb[l + 2][col] = fmaf(uu.z, Dd, p2);
            yb[l + 3][col] = fmaf(uu.w, Dd, p3);
        }
    }
    __syncthreads();
    size_t base = ((size_t)(b * 1024 + ch * 128)) * 512 + d0;   // ushort offset
    const uint* rp32 = (const uint*)(resb + base);
    uint* yp32 = (uint*)(ybb + base);
    #pragma unroll
    for (int j = 0; j < 4; ++j) {
        int idx = j * 512 + t;
        int l = idx >> 4, du = idx & 15;
        float v0 = yb[l][du * 2 + 0];
        float v1 = yb[l][du * 2 + 1];
        uint rr = rp32[(size_t)l * 256 + du];
        float y0 = v0 * bf2f((ushort)(rr & 0xffffu));
        float y1 = v1 * bf2f((ushort)(rr >> 16));
        yp32[(size_t)l * 256 + du] = (uint)f2bf(y0) | ((uint)f2bf(y1) << 16);
    }
}

// s[row] = LN(o[row])*g + b + s[row]; also writes bf16 copy sb. One wave/row.
__global__ __launch_bounds__(256) void ln_res_kernel(
    const float* __restrict__ o, const float* __restrict__ g,
    const float* __restrict__ bb, float* __restrict__ s, ushort* __restrict__ sb)
{
    int row = blockIdx.x * 4 + (threadIdx.x >> 6);
    int lane = threadIdx.x & 63;
    const float4* orow = (const float4*)(o + (size_t)row * 256);
    float4 v = orow[lane];
    float sum = v.x + v.y + v.z + v.w;
    float sq = v.x * v.x + v.y * v.y + v.z * v.z + v.w * v.w;
    #pragma unroll
    for (int off = 1; off < 64; off <<= 1) {
        sum += __shfl_xor(sum, off);
        sq += __shfl_xor(sq, off);
    }
    float m = sum * (1.f / 256.f);
    float var = sq * (1.f / 256.f) - m * m;
    float rstd = rsqrtf(var + 1e-5f);
    float4 gg = ((const float4*)g)[lane];
    float4 bv = ((const float4*)bb)[lane];
    float4* srow = (float4*)(s + (size_t)row * 256);
    float4 sv = srow[lane];
    sv.x += (v.x - m) * rstd * gg.x + bv.x;
    sv.y += (v.y - m) * rstd * gg.y + bv.y;
    sv.z += (v.z - m) * rstd * gg.z + bv.z;
    sv.w += (v.w - m) * rstd * gg.w + bv.w;
    srow[lane] = sv;
    uint2 pk;
    pk.x = (uint)f2bf(sv.x) | ((uint)f2bf(sv.y) << 16);
    pk.y = (uint)f2bf(sv.z) | ((uint)f2bf(sv.w) << 16);
    *(uint2*)(sb + (size_t)row * 256 + lane * 4) = pk;
}

// mean over l then LN over 256 channels. grid 4 x 256.
__global__ __launch_bounds__(256) void pool_ln_kernel(
    const float* __restrict__ s, const float* __restrict__ nw,
    const float* __restrict__ nb, float* __restrict__ sln)
{
    int b = blockIdx.x, c = threadIdx.x;
    const float* p = s + (size_t)b * 262144 + c;
    float acc = 0.f;
    for (int l = 0; l < 1024; ++l) acc += p[(size_t)l * 256];
    float pooled = acc * (1.f / 1024.f);
    __shared__ float rs[4], rq[4];
    float sum = pooled, sq = pooled * pooled;
    #pragma unroll
    for (int off = 1; off < 64; off <<= 1) {
        sum += __shfl_xor(sum, off);
        sq += __shfl_xor(sq, off);
    }
    int w = threadIdx.x >> 6;
    if ((threadIdx.x & 63) == 0) { rs[w] = sum; rq[w] = sq; }
    __syncthreads();
    sum = rs[0] + rs[1] + rs[2] + rs[3];
    sq = rq[0] + rq[1] + rq[2] + rq[3];
    float m = sum * (1.f / 256.f);
    float var = sq * (1.f / 256.f) - m * m;
    float rstd = rsqrtf(var + 1e-5f);
    sln[b * 256 + c] = (pooled - m) * rstd * nw[c] + nb[c];
}

// softmax over 1000 logits per b
__global__ __launch_bounds__(256) void softmax_kernel(float* __restrict__ out)
{
    int b = threadIdx.x >> 6, lane = threadIdx.x & 63;
    const float* lg = out + b * 1000;
    float v[16];
    float mx = -1e30f;
    #pragma unroll
    for (int j = 0; j < 16; ++j) {
        int i = lane + j * 64;
        v[j] = (i < 1000) ? lg[i] : -1e30f;
        mx = fmaxf(mx, v[j]);
    }
    #pragma unroll
    for (int off = 1; off < 64; off <<= 1) mx = fmaxf(mx, __shfl_xor(mx, off));
    float sum = 0.f;
    #pragma unroll
    for (int j = 0; j < 16; ++j) {
        int i = lane + j * 64;
        if (i < 1000) { v[j] = __expf(v[j] - mx); sum += v[j]; }
    }
    #pragma unroll
    for (int off = 1; off < 64; off <<= 1) sum += __shfl_xor(sum, off);
    float inv = 1.f / sum;
    float* so = out + 4000 + b * 1000;
    #pragma unroll
    for (int j = 0; j < 16; ++j) {
        int i = lane + j * 64;
        if (i < 1000) so[i] = v[j] * inv;
    }
}

// ---------------------------------------------------------------------------
extern "C" void kernel_launch(void* const* d_in, const int* in_sizes, int n_in,
                              void* d_out, int out_size, void* d_ws, size_t ws_size,
                              hipStream_t stream)
{
    const float* x    = (const float*)d_in[0];
    const float* c1w  = (const float*)d_in[1];
    const float* c1b  = (const float*)d_in[2];
    const float* g1   = (const float*)d_in[3];
    const float* b1   = (const float*)d_in[4];
    const float* c2w  = (const float*)d_in[5];
    const float* c2b  = (const float*)d_in[6];
    const float* g2   = (const float*)d_in[7];
    const float* b2   = (const float*)d_in[8];
    const float* pw   = (const float*)d_in[9];
    const float* pb   = (const float*)d_in[10];
    const float* g3   = (const float*)d_in[11];
    const float* b3   = (const float*)d_in[12];
    const float* ipw  = (const float*)d_in[13];
    const float* ipb  = (const float*)d_in[14];
    const float* cw   = (const float*)d_in[15];
    const float* cb   = (const float*)d_in[16];
    const float* xpw  = (const float*)d_in[17];
    const float* dpw  = (const float*)d_in[18];
    const float* dpb  = (const float*)d_in[19];
    const float* alog = (const float*)d_in[20];
    const float* dssm = (const float*)d_in[21];
    const float* opw  = (const float*)d_in[22];
    const float* opb  = (const float*)d_in[23];
    const float* lnw  = (const float*)d_in[24];
    const float* lnb  = (const float*)d_in[25];
    const float* nw   = (const float*)d_in[26];
    const float* nb   = (const float*)d_in[27];
    const float* fcw  = (const float*)d_in[28];
    const float* fcb  = (const float*)d_in[29];
    float* out = (float*)d_out;
    float* wsf = (float*)d_ws;

    float*  s_   = wsf;
    ushort* sb   = (ushort*)(wsf + 1048576);
    ushort* xib  = (ushort*)(wsf + 1572864);
    ushort* h2b  = (ushort*)(wsf + 1572864);
    float*  delta= wsf + 1572864;
    float*  obuf = wsf + 1572864;
    ushort* resb = (ushort*)(wsf + 3670016);
    ushort* xlb  = (ushort*)(wsf + 4718592);
    ushort* ybb  = (ushort*)(wsf + 4718592);
    ushort* h1b  = (ushort*)(wsf + 4718592);
    float*  xl   = wsf + 6815744;
    ushort* Apb  = (ushort*)(wsf + 6815744);
    float*  xdbl = wsf + 8912896;
    ushort* ipwb = (ushort*)(wsf + 9175040);
    ushort* opwb = (ushort*)(wsf + 9699328);
    ushort* w2b  = (ushort*)(wsf + 9961472);
    ushort* pwTb = (ushort*)(wsf + 10108928);
    float*  sln  = wsf + 10240000;
    float*  Psum = wsf + 10241024;
    float*  hFsum= wsf + 10503168;
    ushort* xpwb = (ushort*)(wsf + 10765312);

    // --- fused weight prep (1 dispatch) ---
    hipLaunchKernelGGL(wprep, dim3(8832), dim3(256), 0, stream,
                       ipw, opw, c2w, pw, xpw, ipwb, opwb, w2b, pwTb, xpwb);

    // --- conv stem ---
    hipLaunchKernelGGL(conv1_nhwc, dim3(256), dim3(256), 0, stream, x, c1w, c1b, g1, b1, h1b);
    hipLaunchKernelGGL(conv2_mfma, dim3(128, 4), dim3(256), 0, stream, h1b, w2b, c2b, g2, b2, h2b);
    hipLaunchKernelGGL(im2col_bf16, dim3(2048), dim3(256), 0, stream, h2b, Apb);
    hipLaunchKernelGGL((mfma_gemm_bt<64, 64, 2>), dim3(64, 4), dim3(256), 0, stream,
                       Apb, 1024, pwTb, 1024, pb, g3, b3, s_, sb, nullptr, 256, 1024);

    // --- mamba blocks ---
    for (int i = 0; i < 4; ++i) {
        const ushort* ipwb_i = ipwb + (size_t)i * 1024 * 256;
        const float*  ipb_i  = ipb + i * 1024;
        const float*  cw_i   = cw + i * 512 * 4;
        const float*  cb_i   = cb + i * 512;
        const ushort* xpwb_i = xpwb + (size_t)i * 64 * 512;
        const float*  dpw_i  = dpw + (size_t)i * 512 * 32;
        const float*  dpb_i  = dpb + i * 512;
        const float*  alog_i = alog + (size_t)i * 512 * 16;
        const float*  dssm_i = dssm + i * 512;
        const ushort* opwb_i = opwb + (size_t)i * 256 * 512;
        const float*  opb_i  = opb + i * 256;
        const float*  lnw_i  = lnw + i * 256;
        const float*  lnb_i  = lnb + i * 256;

        // in_proj (bf16 MFMA): xib bf16 + silu(res) bf16
        hipLaunchKernelGGL((mfma_gemm_bt<64, 128, 3>), dim3(64, 8), dim3(256), 0, stream,
                           sb, 256, ipwb_i, 256, ipb_i, nullptr, nullptr,
                           nullptr, xib, resb, 0, 256);
        // dwconv -> xl fp32 + xlb bf16
        hipLaunchKernelGGL(dwconv, dim3(2048), dim3(256), 0, stream, xib, cw_i, cb_i, xl, xlb);
        // x_proj (bf16 MFMA) -> xdbl fp32 [m,64]
        hipLaunchKernelGGL((mfma_gemm_bt<64, 64, 0>), dim3(64, 1), dim3(256), 0, stream,
                           xlb, 512, xpwb_i, 512, nullptr, nullptr, nullptr,
                           xdbl, nullptr, nullptr, 64, 512);
        // dt_proj + softplus -> delta fp32 [m,512]
        hipLaunchKernelGGL((gemm_kernel<64, 64, 16, 4, 4>), dim3(64, 8), dim3(256), 0, stream,
                           xdbl, 64, dpw_i, 32, dpb_i, delta, 512, 4096, 512, 32, 2);
        // chunked scan
        hipLaunchKernelGGL(scan_part1, dim3(512), dim3(512), 0, stream,
                           delta, xl, xdbl, alog_i, Psum, hFsum);
        hipLaunchKernelGGL(scan_part2, dim3(512), dim3(512), 0, stream,
                           delta, xl, xdbl, alog_i, dssm_i, resb, ybb, Psum, hFsum);
        // out_proj (bf16 MFMA) -> obuf fp32
        hipLaunchKernelGGL((mfma_gemm_bt<64, 64, 0>), dim3(64, 4), dim3(256), 0, stream,
                           ybb, 512, opwb_i, 512, opb_i, nullptr, nullptr,
                           obuf, nullptr, nullptr, 256, 512);
        hipLaunchKernelGGL(ln_res_kernel, dim3(1024), dim3(256), 0, stream,
                           obuf, lnw_i, lnb_i, s_, sb);
    }

    // --- head ---
    hipLaunchKernelGGL(pool_ln_kernel, dim3(4), dim3(256), 0, stream, s_, nw, nb, sln);
    hipLaunchKernelGGL((gemm_kernel<64, 64, 16, 4, 4>), dim3(1, 16), dim3(256), 0, stream,
                       sln, 256, fcw, 256, fcb, out, 1000, 4, 1000, 256, 0);
    hipLaunchKernelGGL(softmax_kernel, dim3(1), dim3(256), 0, stream, out);
}

// Round 11
// 670.117 us; speedup vs baseline: 1.0970x; 1.0970x over previous
//
#include <hip/hip_runtime.h>
#include <math.h>

// ---------------------------------------------------------------------------
// FastImageMamba forward. R11: conv2 prefetch via explicit scalar uint4s
// (R9/R10's array-by-reference lambda forced the dbuf to scratch: VGPR=44,
// WRITE_SIZE 117MB of scratch traffic). Everything else identical to R10.
// B=4, DM=256, NL=4, NC=1000, DI=512, NS=16, DTR=32, K=4, L=1024, H=W=64
// ---------------------------------------------------------------------------

#define BN_RSQ 0.99999500003749969f   // 1/sqrt(1+1e-5)

typedef unsigned int uint;
typedef unsigned short ushort;
typedef __bf16 bf16x8 __attribute__((ext_vector_type(8)));
typedef float floatx4 __attribute__((ext_vector_type(4)));

__device__ __forceinline__ float gelu_f(float v) {
    return 0.5f * v * (1.0f + erff(v * 0.70710678118654752f));
}
__device__ __forceinline__ float softplus_f(float v) {
    return (v > 20.f) ? v : log1pf(expf(v));
}
__device__ __forceinline__ ushort f2bf(float f) {
    uint x = __float_as_uint(f);
    x += 0x7fffu + ((x >> 16) & 1u);
    return (ushort)(x >> 16);
}
__device__ __forceinline__ float bf2f(ushort u) {
    return __uint_as_float((uint)u << 16);
}

// ---------------------------------------------------------------------------
// Fused weight prep: all fp32->bf16 weight conversions in one dispatch.
// ---------------------------------------------------------------------------
__global__ void wprep(const float* __restrict__ ipw, const float* __restrict__ opw,
                      const float* __restrict__ c2w, const float* __restrict__ pw,
                      const float* __restrict__ xpw,
                      ushort* __restrict__ ipwb, ushort* __restrict__ opwb,
                      ushort* __restrict__ w2b, ushort* __restrict__ pwTb,
                      ushort* __restrict__ xpwb)
{
    int idx = blockIdx.x * 256 + threadIdx.x;
    if (idx < 1048576) {
        ipwb[idx] = f2bf(ipw[idx]);
    } else if (idx < 1572864) {
        int i = idx - 1048576;
        opwb[i] = f2bf(opw[i]);
    } else if (idx < 1867776) {
        int i = idx - 1572864;
        int oc = i / 1152, k = i % 1152;
        int s = k >> 7, ic = k & 127;
        w2b[i] = f2bf(c2w[(size_t)(oc * 128 + ic) * 9 + s]);
    } else if (idx < 2129920) {
        int i = idx - 1867776;
        int oc = i >> 10, k = i & 1023;
        int s = k >> 8, ic = k & 255;
        int ky = s >> 1, kx = s & 1;
        pwTb[i] = f2bf(pw[((size_t)(oc * 256 + ic) * 2 + ky) * 2 + kx]);
    } else if (idx < 2260992) {
        int i = idx - 2129920;
        xpwb[i] = f2bf(xpw[i]);
    }
}

// ---------------------------------------------------------------------------
// conv1: 3x3 s1p1, IC=3 -> OC=128, NCHW fp32 in, NHWC bf16 out (+bias+BN+GELU)
// ---------------------------------------------------------------------------
__global__ __launch_bounds__(256) void conv1_nhwc(
    const float* __restrict__ x, const float* __restrict__ w,
    const float* __restrict__ cb, const float* __restrict__ g,
    const float* __restrict__ bb, ushort* __restrict__ out)
{
    __shared__ float tin[3][3][64];
    __shared__ float ws[3456];
    int t = threadIdx.x;
    int b = blockIdx.x >> 6, y = blockIdx.x & 63;
    for (int i = t; i < 3456; i += 256) ws[i] = w[i];
    for (int i = t; i < 576; i += 256) {
        int ic = i / 192, r = (i >> 6) % 3, xx = i & 63;
        int gy = y + r - 1;
        tin[ic][r][xx] = ((unsigned)gy < 64u) ? x[((b * 3 + ic) * 64 + gy) * 64 + xx] : 0.f;
    }
    __syncthreads();
    int tx = t & 15, ty = t >> 4;
    int oc0 = tx * 8, px0 = ty * 4;
    float acc[4][8];
    #pragma unroll
    for (int p = 0; p < 4; ++p)
        #pragma unroll
        for (int o = 0; o < 8; ++o) acc[p][o] = 0.f;
    for (int ic = 0; ic < 3; ++ic)
        #pragma unroll
        for (int ky = 0; ky < 3; ++ky)
            #pragma unroll
            for (int kx = 0; kx < 3; ++kx) {
                float av[4];
                #pragma unroll
                for (int p = 0; p < 4; ++p) {
                    int xx = px0 + p + kx - 1;
                    av[p] = ((unsigned)xx < 64u) ? tin[ic][ky][xx] : 0.f;
                }
                #pragma unroll
                for (int o = 0; o < 8; ++o) {
                    float wv = ws[(oc0 + o) * 27 + ic * 9 + ky * 3 + kx];
                    #pragma unroll
                    for (int p = 0; p < 4; ++p) acc[p][o] = fmaf(av[p], wv, acc[p][o]);
                }
            }
    #pragma unroll
    for (int p = 0; p < 4; ++p) {
        uint pk[4];
        #pragma unroll
        for (int o2 = 0; o2 < 4; ++o2) {
            int oc = oc0 + o2 * 2;
            float v0 = gelu_f((acc[p][o2 * 2] + cb[oc]) * (g[oc] * BN_RSQ) + bb[oc]);
            float v1 = gelu_f((acc[p][o2 * 2 + 1] + cb[oc + 1]) * (g[oc + 1] * BN_RSQ) + bb[oc + 1]);
            pk[o2] = (uint)f2bf(v0) | ((uint)f2bf(v1) << 16);
        }
        uint4 vv = make_uint4(pk[0], pk[1], pk[2], pk[3]);
        *(uint4*)(out + ((size_t)((b * 64 + y) * 64 + px0 + p)) * 128 + oc0) = vv;
    }
}

// ---------------------------------------------------------------------------
// bf16 MFMA GEMM (A @ W^T), BMxBN tile, BK=32, 4 waves (2x2), reg dbuf.
// EPI: 0 = +bias -> fp32 Cf[ldc]
//      2 = +bias,BN,GELU -> fp32 Cf + bf16 Cb (same ldc)
//      3 = in_proj: n<512 -> bf16 Cb[m*512+n]; n>=512 -> bf16 silu -> Cb2
// ---------------------------------------------------------------------------
template<int BM, int BN, int EPI>
__global__ __launch_bounds__(256, 2) void mfma_gemm_bt(
    const ushort* __restrict__ A, int lda,
    const ushort* __restrict__ W, int ldw,
    const float* __restrict__ bias,
    const float* __restrict__ bnG, const float* __restrict__ bnB,
    float* __restrict__ Cf, ushort* __restrict__ Cb, ushort* __restrict__ Cb2,
    int ldc, int K)
{
    constexpr int PAD = 40;
    constexpr int AP = BM / 64;
    constexpr int BP = BN / 64;
    constexpr int FM = BM / 32;
    constexpr int FN = BN / 32;
    __shared__ __align__(16) ushort As[BM * PAD];
    __shared__ __align__(16) ushort Bs[BN * PAD];
    int t = threadIdx.x;
    int m0 = blockIdx.x * BM, n0 = blockIdx.y * BN;
    int lane = t & 63, wid = t >> 6;
    int wm = (wid & 1) * (BM / 2), wn = (wid >> 1) * (BN / 2);
    int fr = lane & 15, fk = (lane >> 4) * 8;
    int r0 = t >> 2, c0 = (t & 3) * 8;
    floatx4 acc[FM][FN];
    #pragma unroll
    for (int i = 0; i < FM; ++i)
        #pragma unroll
        for (int j = 0; j < FN; ++j) acc[i][j] = {0.f, 0.f, 0.f, 0.f};
    uint4 ra[AP], rb[BP];
    #pragma unroll
    for (int p = 0; p < AP; ++p)
        ra[p] = *(const uint4*)(A + (size_t)(m0 + r0 + p * 64) * lda + c0);
    #pragma unroll
    for (int p = 0; p < BP; ++p)
        rb[p] = *(const uint4*)(W + (size_t)(n0 + r0 + p * 64) * ldw + c0);
    for (int k0 = 0; k0 < K; k0 += 32) {
        __syncthreads();
        #pragma unroll
        for (int p = 0; p < AP; ++p) *(uint4*)&As[(r0 + p * 64) * PAD + c0] = ra[p];
        #pragma unroll
        for (int p = 0; p < BP; ++p) *(uint4*)&Bs[(r0 + p * 64) * PAD + c0] = rb[p];
        __syncthreads();
        if (k0 + 32 < K) {
            #pragma unroll
            for (int p = 0; p < AP; ++p)
                ra[p] = *(const uint4*)(A + (size_t)(m0 + r0 + p * 64) * lda + k0 + 32 + c0);
            #pragma unroll
            for (int p = 0; p < BP; ++p)
                rb[p] = *(const uint4*)(W + (size_t)(n0 + r0 + p * 64) * ldw + k0 + 32 + c0);
        }
        bf16x8 af[FM], bw[FN];
        #pragma unroll
        for (int i = 0; i < FM; ++i)
            af[i] = *(const bf16x8*)&As[(wm + i * 16 + fr) * PAD + fk];
        #pragma unroll
        for (int j = 0; j < FN; ++j)
            bw[j] = *(const bf16x8*)&Bs[(wn + j * 16 + fr) * PAD + fk];
        #pragma unroll
        for (int i = 0; i < FM; ++i)
            #pragma unroll
            for (int j = 0; j < FN; ++j)
                acc[i][j] = __builtin_amdgcn_mfma_f32_16x16x32_bf16(af[i], bw[j], acc[i][j], 0, 0, 0);
    }
    int rbase = (lane >> 4) * 4, cc = lane & 15;
    #pragma unroll
    for (int j = 0; j < FN; ++j) {
        int n = n0 + wn + j * 16 + cc;
        float bv = bias ? bias[n] : 0.f;
        float scl = 0.f, shf = 0.f;
        if (EPI == 2) { scl = bnG[n] * BN_RSQ; shf = bnB[n]; }
        #pragma unroll
        for (int i = 0; i < FM; ++i) {
            #pragma unroll
            for (int r = 0; r < 4; ++r) {
                int m = m0 + wm + i * 16 + rbase + r;
                float v = acc[i][j][r] + bv;
                if (EPI == 2) v = gelu_f(v * scl + shf);
                if (EPI == 0) {
                    Cf[(size_t)m * ldc + n] = v;
                } else if (EPI == 2) {
                    Cf[(size_t)m * ldc + n] = v;
                    Cb[(size_t)m * ldc + n] = f2bf(v);
                } else {
                    if (n < 512) Cb[(size_t)m * 512 + n] = f2bf(v);
                    else Cb2[(size_t)m * 512 + (n - 512)] = f2bf(v / (1.f + __expf(-v)));
                }
            }
        }
    }
}

// ---------------------------------------------------------------------------
// conv2: 9-shift implicit MFMA GEMM, 128px x 64oc tile, BK=64 (18 steps),
// reg dbuf with EXPLICIT SCALAR uint4s (no array-by-ref: that spilled).
// ---------------------------------------------------------------------------
#define C2_LOAD(step)                                                            \
    {                                                                            \
        int s_ = (step) >> 1, ich_ = ((step) & 1) * 64;                          \
        int ky_ = s_ / 3, kx_ = s_ % 3;                                          \
        int sy_ = y0 + (ra_row >> 6) + ky_ - 1;                                  \
        int sx_ = (ra_row & 63) + kx_ - 1;                                       \
        bool v_ = ((unsigned)sy_ < 64u) && ((unsigned)sx_ < 64u);                \
        const ushort* ap_ = hb + ((size_t)(sy_ * 64 + sx_)) * 128 + ich_ + ra_c; \
        uint4 zz_ = make_uint4(0u, 0u, 0u, 0u);                                  \
        ra0 = v_ ? *(const uint4*)(ap_ + 0)  : zz_;                              \
        ra1 = v_ ? *(const uint4*)(ap_ + 8)  : zz_;                              \
        ra2 = v_ ? *(const uint4*)(ap_ + 16) : zz_;                              \
        ra3 = v_ ? *(const uint4*)(ap_ + 24) : zz_;                              \
        const ushort* wp_ = w2b + (size_t)(n0 + rb_row) * 1152 + s_ * 128 + ich_ + rb_c; \
        rb0 = *(const uint4*)(wp_ + 0);                                          \
        rb1 = *(const uint4*)(wp_ + 8);                                          \
    }

__global__ __launch_bounds__(256, 2) void conv2_mfma(
    const ushort* __restrict__ h1b, const ushort* __restrict__ w2b,
    const float* __restrict__ cb, const float* __restrict__ g,
    const float* __restrict__ bb, ushort* __restrict__ h2b)
{
    constexpr int PAD = 72;
    __shared__ __align__(16) ushort As[128 * PAD];
    __shared__ __align__(16) ushort Bs[64 * PAD];
    int t = threadIdx.x;
    int m0 = blockIdx.x * 128, n0 = blockIdx.y * 64;
    int b = m0 >> 12;
    int y0 = (m0 & 4095) >> 6;
    int lane = t & 63, wid = t >> 6;
    int wm = (wid & 1) * 64, wn = (wid >> 1) * 32;
    int fr = lane & 15, fk = (lane >> 4) * 8;
    int ra_row = t >> 1, ra_c = (t & 1) * 32;
    int rb_row = t >> 2, rb_c = (t & 3) * 16;
    floatx4 acc[4][2];
    #pragma unroll
    for (int i = 0; i < 4; ++i)
        #pragma unroll
        for (int j = 0; j < 2; ++j) acc[i][j] = {0.f, 0.f, 0.f, 0.f};
    const ushort* hb = h1b + (size_t)b * 4096 * 128;

    uint4 ra0, ra1, ra2, ra3, rb0, rb1;
    C2_LOAD(0);
    for (int step = 0; step < 18; ++step) {
        __syncthreads();
        *(uint4*)&As[ra_row * PAD + ra_c + 0]  = ra0;
        *(uint4*)&As[ra_row * PAD + ra_c + 8]  = ra1;
        *(uint4*)&As[ra_row * PAD + ra_c + 16] = ra2;
        *(uint4*)&As[ra_row * PAD + ra_c + 24] = ra3;
        *(uint4*)&Bs[rb_row * PAD + rb_c + 0]  = rb0;
        *(uint4*)&Bs[rb_row * PAD + rb_c + 8]  = rb1;
        __syncthreads();
        if (step + 1 < 18) C2_LOAD(step + 1);
        #pragma unroll
        for (int ks = 0; ks < 64; ks += 32) {
            bf16x8 af[4], bw[2];
            #pragma unroll
            for (int i = 0; i < 4; ++i)
                af[i] = *(const bf16x8*)&As[(wm + i * 16 + fr) * PAD + ks + fk];
            #pragma unroll
            for (int j = 0; j < 2; ++j)
                bw[j] = *(const bf16x8*)&Bs[(wn + j * 16 + fr) * PAD + ks + fk];
            #pragma unroll
            for (int i = 0; i < 4; ++i)
                #pragma unroll
                for (int j = 0; j < 2; ++j)
                    acc[i][j] = __builtin_amdgcn_mfma_f32_16x16x32_bf16(af[i], bw[j], acc[i][j], 0, 0, 0);
        }
    }
    int rbase = (lane >> 4) * 4, cc = lane & 15;
    #pragma unroll
    for (int j = 0; j < 2; ++j) {
        int n = n0 + wn + j * 16 + cc;
        float scl = g[n] * BN_RSQ, shf = bb[n], bv2 = cb[n];
        #pragma unroll
        for (int i = 0; i < 4; ++i) {
            #pragma unroll
            for (int r = 0; r < 4; ++r) {
                int m = m0 + wm + i * 16 + rbase + r;
                float v = gelu_f((acc[i][j][r] + bv2) * scl + shf);
                h2b[(size_t)m * 256 + n] = f2bf(v);
            }
        }
    }
}

// Apb[m][s*256+ic] = h2b[b, 2oy+ky, 2ox+kx, ic]
__global__ void im2col_bf16(const ushort* __restrict__ h2b, ushort* __restrict__ Apb)
{
    int idx = blockIdx.x * 256 + threadIdx.x;          // 524288 uint4 chunks
    int k8 = idx & 127;
    int m = idx >> 7;
    int b = m >> 10, oy = (m >> 5) & 31, ox = m & 31;
    int s = k8 >> 5, ic8 = k8 & 31;
    int ky = s >> 1, kx = s & 1;
    uint4 v = *(const uint4*)(h2b + ((size_t)(b * 4096 + (2 * oy + ky) * 64 + 2 * ox + kx)) * 256 + ic8 * 8);
    *(uint4*)(Apb + (size_t)m * 1024 + k8 * 8) = v;
}

// ---------------------------------------------------------------------------
// fp32 tiled GEMM (reg dbuf): C[m*ldc+n] = act(A @ W^T + bias). act 0/2.
// ---------------------------------------------------------------------------
template<int BM, int BN, int BK, int TM, int TN>
__global__ __launch_bounds__(256) void gemm_kernel(
    const float* __restrict__ A, int lda,
    const float* __restrict__ W, int ldw,
    const float* __restrict__ bias,
    float* __restrict__ C, int ldc,
    int M, int N, int K, int act)
{
    static_assert(BM * BK / 4 == 256 && BN * BK / 4 == 256, "staging shape");
    __shared__ float As[BK][BM + 4];
    __shared__ float Bs[BK][BN + 4];
    int t = threadIdx.x;
    int m0 = blockIdx.x * BM, n0 = blockIdx.y * BN;
    float acc[TM][TN];
    #pragma unroll
    for (int i = 0; i < TM; i++)
        #pragma unroll
        for (int j = 0; j < TN; j++) acc[i][j] = 0.f;
    const int LPR = BK / 4;
    int lr = t / LPR, lc4 = (t % LPR) * 4;
    int ty = t >> 4, tx = t & 15;
    int ma = m0 + lr, nb = n0 + lr;
    float4 va = make_float4(0.f, 0.f, 0.f, 0.f);
    float4 vb = make_float4(0.f, 0.f, 0.f, 0.f);
    if (ma < M) va = *(const float4*)(A + (size_t)ma * lda + lc4);
    if (nb < N) vb = *(const float4*)(W + (size_t)nb * ldw + lc4);
    for (int k0 = 0; k0 < K; k0 += BK) {
        __syncthreads();
        As[lc4 + 0][lr] = va.x; As[lc4 + 1][lr] = va.y;
        As[lc4 + 2][lr] = va.z; As[lc4 + 3][lr] = va.w;
        Bs[lc4 + 0][lr] = vb.x; Bs[lc4 + 1][lr] = vb.y;
        Bs[lc4 + 2][lr] = vb.z; Bs[lc4 + 3][lr] = vb.w;
        __syncthreads();
        if (k0 + BK < K) {
            if (ma < M) va = *(const float4*)(A + (size_t)ma * lda + k0 + BK + lc4);
            if (nb < N) vb = *(const float4*)(W + (size_t)nb * ldw + k0 + BK + lc4);
        }
        #pragma unroll
        for (int kk = 0; kk < BK; ++kk) {
            float a[TM], bfr[TN];
            #pragma unroll
            for (int i = 0; i < TM; i += 4)
                *(float4*)&a[i] = *(const float4*)&As[kk][ty * TM + i];
            #pragma unroll
            for (int j = 0; j < TN; j += 4)
                *(float4*)&bfr[j] = *(const float4*)&Bs[kk][tx * TN + j];
            #pragma unroll
            for (int i = 0; i < TM; i++)
                #pragma unroll
                for (int j = 0; j < TN; j++) acc[i][j] = fmaf(a[i], bfr[j], acc[i][j]);
        }
    }
    #pragma unroll
    for (int i = 0; i < TM; i++) {
        int m = m0 + ty * TM + i;
        if (m >= M) continue;
        #pragma unroll
        for (int j = 0; j < TN; j++) {
            int n = n0 + tx * TN + j;
            if (n >= N) continue;
            float v = acc[i][j];
            if (bias) v += bias[n];
            if (act == 2) v = softplus_f(v);
            C[(size_t)m * ldc + n] = v;
        }
    }
}

// ---------------------------------------------------------------------------
// Depthwise conv1d (K=4, pad(1,2)) in [b,l,d], bf16 input xib.
// Outputs xl fp32 (scan u) + xlb bf16 (x_proj A).
// ---------------------------------------------------------------------------
__global__ __launch_bounds__(256) void dwconv(
    const ushort* __restrict__ xib, const float* __restrict__ cw,
    const float* __restrict__ cb, float* __restrict__ xl, ushort* __restrict__ xlb)
{
    int idx = blockIdx.x * 256 + threadIdx.x;   // 524288
    int d4 = (idx & 127) * 4;
    int bl = idx >> 7;
    int b = bl >> 10, l = bl & 1023;
    float4 w0 = *(const float4*)(cw + d4 * 4);
    float4 w1 = *(const float4*)(cw + d4 * 4 + 4);
    float4 w2 = *(const float4*)(cw + d4 * 4 + 8);
    float4 w3 = *(const float4*)(cw + d4 * 4 + 12);
    float4 acc = *(const float4*)(cb + d4);
    const ushort* rowb = xib + ((size_t)b << 19) + d4;
    #pragma unroll
    for (int k = 0; k < 4; ++k) {
        int ll = l + k - 1;
        if ((unsigned)ll < 1024u) {
            uint2 p = *(const uint2*)(rowb + (size_t)ll * 512);
            acc.x = fmaf(bf2f((ushort)(p.x & 0xffffu)), ((const float*)&w0)[k], acc.x);
            acc.y = fmaf(bf2f((ushort)(p.x >> 16)),     ((const float*)&w1)[k], acc.y);
            acc.z = fmaf(bf2f((ushort)(p.y & 0xffffu)), ((const float*)&w2)[k], acc.z);
            acc.w = fmaf(bf2f((ushort)(p.y >> 16)),     ((const float*)&w3)[k], acc.w);
        }
    }
    *(float4*)(xl + (size_t)bl * 512 + d4) = acc;
    uint2 pk;
    pk.x = (uint)f2bf(acc.x) | ((uint)f2bf(acc.y) << 16);
    pk.y = (uint)f2bf(acc.z) | ((uint)f2bf(acc.w) << 16);
    *(uint2*)(xlb + (size_t)bl * 512 + d4) = pk;
}

// ---------------------------------------------------------------------------
// Chunked scan pass 1. Block = (b, dgG, ch): 512 thr, 8 waves x 4 d = 32 d.
// ---------------------------------------------------------------------------
__global__ __launch_bounds__(512) void scan_part1(
    const float* __restrict__ delta, const float* __restrict__ u,
    const float* __restrict__ xdbl, const float* __restrict__ alog,
    float* __restrict__ Psum, float* __restrict__ hFsum)
{
    __shared__ float Td[32][132];
    __shared__ float Tu[32][132];
    __shared__ float TB[16][132];
    int t = threadIdx.x;
    int bid = blockIdx.x;                 // 512 = b(4) x dgG(16) x ch(8)
    int ch = bid & 7, dgG = (bid >> 3) & 15, b = bid >> 7;
    int d0 = dgG * 32;
    int bl0 = b * 1024 + ch * 128;
    #pragma unroll
    for (int r = 0; r < 2; ++r) {
        int idx = r * 512 + t;
        int l = idx >> 3, d4 = (idx & 7) * 4;
        float4 dv = *(const float4*)(delta + (size_t)(bl0 + l) * 512 + d0 + d4);
        float4 uv = *(const float4*)(u + (size_t)(bl0 + l) * 512 + d0 + d4);
        Td[d4 + 0][l] = dv.x; Td[d4 + 1][l] = dv.y; Td[d4 + 2][l] = dv.z; Td[d4 + 3][l] = dv.w;
        Tu[d4 + 0][l] = uv.x; Tu[d4 + 1][l] = uv.y; Tu[d4 + 2][l] = uv.z; Tu[d4 + 3][l] = uv.w;
    }
    {
        int l = t >> 2, n4 = (t & 3) * 4;
        float4 bv = *(const float4*)(xdbl + (size_t)(bl0 + l) * 64 + 32 + n4);
        TB[n4 + 0][l] = bv.x; TB[n4 + 1][l] = bv.y; TB[n4 + 2][l] = bv.z; TB[n4 + 3][l] = bv.w;
    }
    __syncthreads();
    int w = t >> 6, lane = t & 63;
    int dl = lane >> 4, n = lane & 15;
    int col = w * 4 + dl;
    int d = d0 + col;
    float Ac = -__expf(alog[d * 16 + n]);
    float h = 0.f, P = 1.f;
    for (int l4 = 0; l4 < 32; ++l4) {
        float4 de = *(const float4*)&Td[col][l4 * 4];
        float4 uu = *(const float4*)&Tu[col][l4 * 4];
        float4 Bv = *(const float4*)&TB[n][l4 * 4];
        float a;
        a = __expf(de.x * Ac); h = a * h + de.x * Bv.x * uu.x; P *= a;
        a = __expf(de.y * Ac); h = a * h + de.y * Bv.y * uu.y; P *= a;
        a = __expf(de.z * Ac); h = a * h + de.z * Bv.z * uu.z; P *= a;
        a = __expf(de.w * Ac); h = a * h + de.w * Bv.w * uu.w; P *= a;
    }
    size_t si = ((size_t)(b * 128 + dgG * 8 + w) * 8 + ch) * 64 + lane;
    Psum[si] = P;
    hFsum[si] = h;
}

// ---------------------------------------------------------------------------
// Chunked scan pass 2: combine summaries, rerun chunk, y + gate -> ybb bf16.
// ---------------------------------------------------------------------------
__global__ __launch_bounds__(512) void scan_part2(
    const float* __restrict__ delta, const float* __restrict__ u,
    const float* __restrict__ xdbl,
    const float* __restrict__ alog, const float* __restrict__ dssm,
    const ushort* __restrict__ resb, ushort* __restrict__ ybb,
    const float* __restrict__ Psum, const float* __restrict__ hFsum)
{
    __shared__ float Td[32][132];
    __shared__ float Tu[32][132];
    __shared__ float TB[16][132];
    __shared__ float TC[16][132];
    __shared__ float yb[128][33];
    int t = threadIdx.x;
    int bid = blockIdx.x;                 // 512 = b(4) x dgG(16) x ch(8)
    int ch = bid & 7, dgG = (bid >> 3) & 15, b = bid >> 7;
    int d0 = dgG * 32;
    int bl0 = b * 1024 + ch * 128;
    #pragma unroll
    for (int r = 0; r < 2; ++r) {
        int idx = r * 512 + t;
        int l = idx >> 3, d4 = (idx & 7) * 4;
        float4 dv = *(const float4*)(delta + (size_t)(bl0 + l) * 512 + d0 + d4);
        float4 uv = *(const float4*)(u + (size_t)(bl0 + l) * 512 + d0 + d4);
        Td[d4 + 0][l] = dv.x; Td[d4 + 1][l] = dv.y; Td[d4 + 2][l] = dv.z; Td[d4 + 3][l] = dv.w;
        Tu[d4 + 0][l] = uv.x; Tu[d4 + 1][l] = uv.y; Tu[d4 + 2][l] = uv.z; Tu[d4 + 3][l] = uv.w;
    }
    {
        int l = t >> 2, n4 = (t & 3) * 4;
        float4 bv = *(const float4*)(xdbl + (size_t)(bl0 + l) * 64 + 32 + n4);
        float4 cv = *(const float4*)(xdbl + (size_t)(bl0 + l) * 64 + 48 + n4);
        TB[n4 + 0][l] = bv.x; TB[n4 + 1][l] = bv.y; TB[n4 + 2][l] = bv.z; TB[n4 + 3][l] = bv.w;
        TC[n4 + 0][l] = cv.x; TC[n4 + 1][l] = cv.y; TC[n4 + 2][l] = cv.z; TC[n4 + 3][l] = cv.w;
    }
    __syncthreads();
    int w = t >> 6, lane = t & 63;
    int dl = lane >> 4, n = lane & 15;
    int col = w * 4 + dl;
    int d = d0 + col;
    float Ac = -__expf(alog[d * 16 + n]);
    float Dd = dssm[d];
    float h = 0.f;
    {
        size_t sbase = (size_t)(b * 128 + dgG * 8 + w) * 512 + lane;
        for (int cc = 0; cc < ch; ++cc) {
            float Pv = Psum[sbase + (size_t)cc * 64];
            float hv = hFsum[sbase + (size_t)cc * 64];
            h = Pv * h + hv;
        }
    }
    for (int l4 = 0; l4 < 32; ++l4) {
        float4 de = *(const float4*)&Td[col][l4 * 4];
        float4 uu = *(const float4*)&Tu[col][l4 * 4];
        float4 Bv = *(const float4*)&TB[n][l4 * 4];
        float4 Cv = *(const float4*)&TC[n][l4 * 4];
        float p0, p1, p2, p3;
        h = __expf(de.x * Ac) * h + de.x * Bv.x * uu.x; p0 = h * Cv.x;
        h = __expf(de.y * Ac) * h + de.y * Bv.y * uu.y; p1 = h * Cv.y;
        h = __expf(de.z * Ac) * h + de.z * Bv.z * uu.z; p2 = h * Cv.z;
        h = __expf(de.w * Ac) * h + de.w * Bv.w * uu.w; p3 = h * Cv.w;
        #pragma unroll
        for (int off = 1; off < 16; off <<= 1) {
            p0 += __shfl_xor(p0, off);
            p1 += __shfl_xor(p1, off);
            p2 += __shfl_xor(p2, off);
            p3 += __shfl_xor(p3, off);
        }
        if (n == 0) {
            int l = l4 * 4;
            yb[l + 0][col] = fmaf(uu.x, Dd, p0);
            yb[l + 1][col] = fmaf(uu.y, Dd, p1);
            yb[l + 2][col] = fmaf(uu.z, Dd, p2);
            yb[l + 3][col] = fmaf(uu.w, Dd, p3);
        }
    }
    __syncthreads();
    size_t base = ((size_t)(b * 1024 + ch * 128)) * 512 + d0;   // ushort offset
    const uint* rp32 = (const uint*)(resb + base);
    uint* yp32 = (uint*)(ybb + base);
    #pragma unroll
    for (int j = 0; j < 4; ++j) {
        int idx = j * 512 + t;
        int l = idx >> 4, du = idx & 15;
        float v0 = yb[l][du * 2 + 0];
        float v1 = yb[l][du * 2 + 1];
        uint rr = rp32[(size_t)l * 256 + du];
        float y0 = v0 * bf2f((ushort)(rr & 0xffffu));
        float y1 = v1 * bf2f((ushort)(rr >> 16));
        yp32[(size_t)l * 256 + du] = (uint)f2bf(y0) | ((uint)f2bf(y1) << 16);
    }
}

// s[row] = LN(o[row])*g + b + s[row]; also writes bf16 copy sb. One wave/row.
__global__ __launch_bounds__(256) void ln_res_kernel(
    const float* __restrict__ o, const float* __restrict__ g,
    const float* __restrict__ bb, float* __restrict__ s, ushort* __restrict__ sb)
{
    int row = blockIdx.x * 4 + (threadIdx.x >> 6);
    int lane = threadIdx.x & 63;
    const float4* orow = (const float4*)(o + (size_t)row * 256);
    float4 v = orow[lane];
    float sum = v.x + v.y + v.z + v.w;
    float sq = v.x * v.x + v.y * v.y + v.z * v.z + v.w * v.w;
    #pragma unroll
    for (int off = 1; off < 64; off <<= 1) {
        sum += __shfl_xor(sum, off);
        sq += __shfl_xor(sq, off);
    }
    float m = sum * (1.f / 256.f);
    float var = sq * (1.f / 256.f) - m * m;
    float rstd = rsqrtf(var + 1e-5f);
    float4 gg = ((const float4*)g)[lane];
    float4 bv = ((const float4*)bb)[lane];
    float4* srow = (float4*)(s + (size_t)row * 256);
    float4 sv = srow[lane];
    sv.x += (v.x - m) * rstd * gg.x + bv.x;
    sv.y += (v.y - m) * rstd * gg.y + bv.y;
    sv.z += (v.z - m) * rstd * gg.z + bv.z;
    sv.w += (v.w - m) * rstd * gg.w + bv.w;
    srow[lane] = sv;
    uint2 pk;
    pk.x = (uint)f2bf(sv.x) | ((uint)f2bf(sv.y) << 16);
    pk.y = (uint)f2bf(sv.z) | ((uint)f2bf(sv.w) << 16);
    *(uint2*)(sb + (size_t)row * 256 + lane * 4) = pk;
}

// mean over l then LN over 256 channels. grid 4 x 256.
__global__ __launch_bounds__(256) void pool_ln_kernel(
    const float* __restrict__ s, const float* __restrict__ nw,
    const float* __restrict__ nb, float* __restrict__ sln)
{
    int b = blockIdx.x, c = threadIdx.x;
    const float* p = s + (size_t)b * 262144 + c;
    float acc = 0.f;
    for (int l = 0; l < 1024; ++l) acc += p[(size_t)l * 256];
    float pooled = acc * (1.f / 1024.f);
    __shared__ float rs[4], rq[4];
    float sum = pooled, sq = pooled * pooled;
    #pragma unroll
    for (int off = 1; off < 64; off <<= 1) {
        sum += __shfl_xor(sum, off);
        sq += __shfl_xor(sq, off);
    }
    int w = threadIdx.x >> 6;
    if ((threadIdx.x & 63) == 0) { rs[w] = sum; rq[w] = sq; }
    __syncthreads();
    sum = rs[0] + rs[1] + rs[2] + rs[3];
    sq = rq[0] + rq[1] + rq[2] + rq[3];
    float m = sum * (1.f / 256.f);
    float var = sq * (1.f / 256.f) - m * m;
    float rstd = rsqrtf(var + 1e-5f);
    sln[b * 256 + c] = (pooled - m) * rstd * nw[c] + nb[c];
}

// softmax over 1000 logits per b
__global__ __launch_bounds__(256) void softmax_kernel(float* __restrict__ out)
{
    int b = threadIdx.x >> 6, lane = threadIdx.x & 63;
    const float* lg = out + b * 1000;
    float v[16];
    float mx = -1e30f;
    #pragma unroll
    for (int j = 0; j < 16; ++j) {
        int i = lane + j * 64;
        v[j] = (i < 1000) ? lg[i] : -1e30f;
        mx = fmaxf(mx, v[j]);
    }
    #pragma unroll
    for (int off = 1; off < 64; off <<= 1) mx = fmaxf(mx, __shfl_xor(mx, off));
    float sum = 0.f;
    #pragma unroll
    for (int j = 0; j < 16; ++j) {
        int i = lane + j * 64;
        if (i < 1000) { v[j] = __expf(v[j] - mx); sum += v[j]; }
    }
    #pragma unroll
    for (int off = 1; off < 64; off <<= 1) sum += __shfl_xor(sum, off);
    float inv = 1.f / sum;
    float* so = out + 4000 + b * 1000;
    #pragma unroll
    for (int j = 0; j < 16; ++j) {
        int i = lane + j * 64;
        if (i < 1000) so[i] = v[j] * inv;
    }
}

// ---------------------------------------------------------------------------
extern "C" void kernel_launch(void* const* d_in, const int* in_sizes, int n_in,
                              void* d_out, int out_size, void* d_ws, size_t ws_size,
                              hipStream_t stream)
{
    const float* x    = (const float*)d_in[0];
    const float* c1w  = (const float*)d_in[1];
    const float* c1b  = (const float*)d_in[2];
    const float* g1   = (const float*)d_in[3];
    const float* b1   = (const float*)d_in[4];
    const float* c2w  = (const float*)d_in[5];
    const float* c2b  = (const float*)d_in[6];
    const float* g2   = (const float*)d_in[7];
    const float* b2   = (const float*)d_in[8];
    const float* pw   = (const float*)d_in[9];
    const float* pb   = (const float*)d_in[10];
    const float* g3   = (const float*)d_in[11];
    const float* b3   = (const float*)d_in[12];
    const float* ipw  = (const float*)d_in[13];
    const float* ipb  = (const float*)d_in[14];
    const float* cw   = (const float*)d_in[15];
    const float* cb   = (const float*)d_in[16];
    const float* xpw  = (const float*)d_in[17];
    const float* dpw  = (const float*)d_in[18];
    const float* dpb  = (const float*)d_in[19];
    const float* alog = (const float*)d_in[20];
    const float* dssm = (const float*)d_in[21];
    const float* opw  = (const float*)d_in[22];
    const float* opb  = (const float*)d_in[23];
    const float* lnw  = (const float*)d_in[24];
    const float* lnb  = (const float*)d_in[25];
    const float* nw   = (const float*)d_in[26];
    const float* nb   = (const float*)d_in[27];
    const float* fcw  = (const float*)d_in[28];
    const float* fcb  = (const float*)d_in[29];
    float* out = (float*)d_out;
    float* wsf = (float*)d_ws;

    float*  s_   = wsf;
    ushort* sb   = (ushort*)(wsf + 1048576);
    ushort* xib  = (ushort*)(wsf + 1572864);
    ushort* h2b  = (ushort*)(wsf + 1572864);
    float*  delta= wsf + 1572864;
    float*  obuf = wsf + 1572864;
    ushort* resb = (ushort*)(wsf + 3670016);
    ushort* xlb  = (ushort*)(wsf + 4718592);
    ushort* ybb  = (ushort*)(wsf + 4718592);
    ushort* h1b  = (ushort*)(wsf + 4718592);
    float*  xl   = wsf + 6815744;
    ushort* Apb  = (ushort*)(wsf + 6815744);
    float*  xdbl = wsf + 8912896;
    ushort* ipwb = (ushort*)(wsf + 9175040);
    ushort* opwb = (ushort*)(wsf + 9699328);
    ushort* w2b  = (ushort*)(wsf + 9961472);
    ushort* pwTb = (ushort*)(wsf + 10108928);
    float*  sln  = wsf + 10240000;
    float*  Psum = wsf + 10241024;
    float*  hFsum= wsf + 10503168;
    ushort* xpwb = (ushort*)(wsf + 10765312);

    // --- fused weight prep (1 dispatch) ---
    hipLaunchKernelGGL(wprep, dim3(8832), dim3(256), 0, stream,
                       ipw, opw, c2w, pw, xpw, ipwb, opwb, w2b, pwTb, xpwb);

    // --- conv stem ---
    hipLaunchKernelGGL(conv1_nhwc, dim3(256), dim3(256), 0, stream, x, c1w, c1b, g1, b1, h1b);
    hipLaunchKernelGGL(conv2_mfma, dim3(128, 4), dim3(256), 0, stream, h1b, w2b, c2b, g2, b2, h2b);
    hipLaunchKernelGGL(im2col_bf16, dim3(2048), dim3(256), 0, stream, h2b, Apb);
    hipLaunchKernelGGL((mfma_gemm_bt<64, 64, 2>), dim3(64, 4), dim3(256), 0, stream,
                       Apb, 1024, pwTb, 1024, pb, g3, b3, s_, sb, nullptr, 256, 1024);

    // --- mamba blocks ---
    for (int i = 0; i < 4; ++i) {
        const ushort* ipwb_i = ipwb + (size_t)i * 1024 * 256;
        const float*  ipb_i  = ipb + i * 1024;
        const float*  cw_i   = cw + i * 512 * 4;
        const float*  cb_i   = cb + i * 512;
        const ushort* xpwb_i = xpwb + (size_t)i * 64 * 512;
        const float*  dpw_i  = dpw + (size_t)i * 512 * 32;
        const float*  dpb_i  = dpb + i * 512;
        const float*  alog_i = alog + (size_t)i * 512 * 16;
        const float*  dssm_i = dssm + i * 512;
        const ushort* opwb_i = opwb + (size_t)i * 256 * 512;
        const float*  opb_i  = opb + i * 256;
        const float*  lnw_i  = lnw + i * 256;
        const float*  lnb_i  = lnb + i * 256;

        // in_proj (bf16 MFMA): xib bf16 + silu(res) bf16
        hipLaunchKernelGGL((mfma_gemm_bt<64, 128, 3>), dim3(64, 8), dim3(256), 0, stream,
                           sb, 256, ipwb_i, 256, ipb_i, nullptr, nullptr,
                           nullptr, xib, resb, 0, 256);
        // dwconv -> xl fp32 + xlb bf16
        hipLaunchKernelGGL(dwconv, dim3(2048), dim3(256), 0, stream, xib, cw_i, cb_i, xl, xlb);
        // x_proj (bf16 MFMA) -> xdbl fp32 [m,64]
        hipLaunchKernelGGL((mfma_gemm_bt<64, 64, 0>), dim3(64, 1), dim3(256), 0, stream,
                           xlb, 512, xpwb_i, 512, nullptr, nullptr, nullptr,
                           xdbl, nullptr, nullptr, 64, 512);
        // dt_proj + softplus -> delta fp32 [m,512]
        hipLaunchKernelGGL((gemm_kernel<64, 64, 16, 4, 4>), dim3(64, 8), dim3(256), 0, stream,
                           xdbl, 64, dpw_i, 32, dpb_i, delta, 512, 4096, 512, 32, 2);
        // chunked scan
        hipLaunchKernelGGL(scan_part1, dim3(512), dim3(512), 0, stream,
                           delta, xl, xdbl, alog_i, Psum, hFsum);
        hipLaunchKernelGGL(scan_part2, dim3(512), dim3(512), 0, stream,
                           delta, xl, xdbl, alog_i, dssm_i, resb, ybb, Psum, hFsum);
        // out_proj (bf16 MFMA) -> obuf fp32
        hipLaunchKernelGGL((mfma_gemm_bt<64, 64, 0>), dim3(64, 4), dim3(256), 0, stream,
                           ybb, 512, opwb_i, 512, opb_i, nullptr, nullptr,
                           obuf, nullptr, nullptr, 256, 512);
        hipLaunchKernelGGL(ln_res_kernel, dim3(1024), dim3(256), 0, stream,
                           obuf, lnw_i, lnb_i, s_, sb);
    }

    // --- head ---
    hipLaunchKernelGGL(pool_ln_kernel, dim3(4), dim3(256), 0, stream, s_, nw, nb, sln);
    hipLaunchKernelGGL((gemm_kernel<64, 64, 16, 4, 4>), dim3(1, 16), dim3(256), 0, stream,
                       sln, 256, fcw, 256, fcb, out, 1000, 4, 1000, 256, 0);
    hipLaunchKernelGGL(softmax_kernel, dim3(1), dim3(256), 0, stream, out);
}

// Round 12
// 655.774 us; speedup vs baseline: 1.1210x; 1.0219x over previous
//
#include <hip/hip_runtime.h>
#include <math.h>

// ---------------------------------------------------------------------------
// FastImageMamba forward. R12: dt_proj fused into scan passes (delta buffer
// deleted), u carried as bf16 (xlb), gated ybb written in-place over xlb.
// B=4, DM=256, NL=4, NC=1000, DI=512, NS=16, DTR=32, K=4, L=1024, H=W=64
// ---------------------------------------------------------------------------

#define BN_RSQ 0.99999500003749969f   // 1/sqrt(1+1e-5)

typedef unsigned int uint;
typedef unsigned short ushort;
typedef __bf16 bf16x8 __attribute__((ext_vector_type(8)));
typedef float floatx4 __attribute__((ext_vector_type(4)));

__device__ __forceinline__ float gelu_f(float v) {
    return 0.5f * v * (1.0f + erff(v * 0.70710678118654752f));
}
__device__ __forceinline__ float softplus_f(float v) {
    return (v > 20.f) ? v : log1pf(expf(v));
}
__device__ __forceinline__ ushort f2bf(float f) {
    uint x = __float_as_uint(f);
    x += 0x7fffu + ((x >> 16) & 1u);
    return (ushort)(x >> 16);
}
__device__ __forceinline__ float bf2f(ushort u) {
    return __uint_as_float((uint)u << 16);
}

// ---------------------------------------------------------------------------
// Fused weight prep: all fp32->bf16 weight conversions in one dispatch.
// ---------------------------------------------------------------------------
__global__ void wprep(const float* __restrict__ ipw, const float* __restrict__ opw,
                      const float* __restrict__ c2w, const float* __restrict__ pw,
                      const float* __restrict__ xpw,
                      ushort* __restrict__ ipwb, ushort* __restrict__ opwb,
                      ushort* __restrict__ w2b, ushort* __restrict__ pwTb,
                      ushort* __restrict__ xpwb)
{
    int idx = blockIdx.x * 256 + threadIdx.x;
    if (idx < 1048576) {
        ipwb[idx] = f2bf(ipw[idx]);
    } else if (idx < 1572864) {
        int i = idx - 1048576;
        opwb[i] = f2bf(opw[i]);
    } else if (idx < 1867776) {
        int i = idx - 1572864;
        int oc = i / 1152, k = i % 1152;
        int s = k >> 7, ic = k & 127;
        w2b[i] = f2bf(c2w[(size_t)(oc * 128 + ic) * 9 + s]);
    } else if (idx < 2129920) {
        int i = idx - 1867776;
        int oc = i >> 10, k = i & 1023;
        int s = k >> 8, ic = k & 255;
        int ky = s >> 1, kx = s & 1;
        pwTb[i] = f2bf(pw[((size_t)(oc * 256 + ic) * 2 + ky) * 2 + kx]);
    } else if (idx < 2260992) {
        int i = idx - 2129920;
        xpwb[i] = f2bf(xpw[i]);
    }
}

// ---------------------------------------------------------------------------
// conv1: 3x3 s1p1, IC=3 -> OC=128, NCHW fp32 in, NHWC bf16 out (+bias+BN+GELU)
// ---------------------------------------------------------------------------
__global__ __launch_bounds__(256) void conv1_nhwc(
    const float* __restrict__ x, const float* __restrict__ w,
    const float* __restrict__ cb, const float* __restrict__ g,
    const float* __restrict__ bb, ushort* __restrict__ out)
{
    __shared__ float tin[3][3][64];
    __shared__ float ws[3456];
    int t = threadIdx.x;
    int b = blockIdx.x >> 6, y = blockIdx.x & 63;
    for (int i = t; i < 3456; i += 256) ws[i] = w[i];
    for (int i = t; i < 576; i += 256) {
        int ic = i / 192, r = (i >> 6) % 3, xx = i & 63;
        int gy = y + r - 1;
        tin[ic][r][xx] = ((unsigned)gy < 64u) ? x[((b * 3 + ic) * 64 + gy) * 64 + xx] : 0.f;
    }
    __syncthreads();
    int tx = t & 15, ty = t >> 4;
    int oc0 = tx * 8, px0 = ty * 4;
    float acc[4][8];
    #pragma unroll
    for (int p = 0; p < 4; ++p)
        #pragma unroll
        for (int o = 0; o < 8; ++o) acc[p][o] = 0.f;
    for (int ic = 0; ic < 3; ++ic)
        #pragma unroll
        for (int ky = 0; ky < 3; ++ky)
            #pragma unroll
            for (int kx = 0; kx < 3; ++kx) {
                float av[4];
                #pragma unroll
                for (int p = 0; p < 4; ++p) {
                    int xx = px0 + p + kx - 1;
                    av[p] = ((unsigned)xx < 64u) ? tin[ic][ky][xx] : 0.f;
                }
                #pragma unroll
                for (int o = 0; o < 8; ++o) {
                    float wv = ws[(oc0 + o) * 27 + ic * 9 + ky * 3 + kx];
                    #pragma unroll
                    for (int p = 0; p < 4; ++p) acc[p][o] = fmaf(av[p], wv, acc[p][o]);
                }
            }
    #pragma unroll
    for (int p = 0; p < 4; ++p) {
        uint pk[4];
        #pragma unroll
        for (int o2 = 0; o2 < 4; ++o2) {
            int oc = oc0 + o2 * 2;
            float v0 = gelu_f((acc[p][o2 * 2] + cb[oc]) * (g[oc] * BN_RSQ) + bb[oc]);
            float v1 = gelu_f((acc[p][o2 * 2 + 1] + cb[oc + 1]) * (g[oc + 1] * BN_RSQ) + bb[oc + 1]);
            pk[o2] = (uint)f2bf(v0) | ((uint)f2bf(v1) << 16);
        }
        uint4 vv = make_uint4(pk[0], pk[1], pk[2], pk[3]);
        *(uint4*)(out + ((size_t)((b * 64 + y) * 64 + px0 + p)) * 128 + oc0) = vv;
    }
}

// ---------------------------------------------------------------------------
// bf16 MFMA GEMM (A @ W^T), BMxBN tile, BK=32, 4 waves (2x2), reg dbuf.
// EPI: 0 = +bias -> fp32 Cf[ldc]
//      2 = +bias,BN,GELU -> fp32 Cf + bf16 Cb (same ldc)
//      3 = in_proj: n<512 -> bf16 Cb[m*512+n]; n>=512 -> bf16 silu -> Cb2
// ---------------------------------------------------------------------------
template<int BM, int BN, int EPI>
__global__ __launch_bounds__(256, 2) void mfma_gemm_bt(
    const ushort* __restrict__ A, int lda,
    const ushort* __restrict__ W, int ldw,
    const float* __restrict__ bias,
    const float* __restrict__ bnG, const float* __restrict__ bnB,
    float* __restrict__ Cf, ushort* __restrict__ Cb, ushort* __restrict__ Cb2,
    int ldc, int K)
{
    constexpr int PAD = 40;
    constexpr int AP = BM / 64;
    constexpr int BP = BN / 64;
    constexpr int FM = BM / 32;
    constexpr int FN = BN / 32;
    __shared__ __align__(16) ushort As[BM * PAD];
    __shared__ __align__(16) ushort Bs[BN * PAD];
    int t = threadIdx.x;
    int m0 = blockIdx.x * BM, n0 = blockIdx.y * BN;
    int lane = t & 63, wid = t >> 6;
    int wm = (wid & 1) * (BM / 2), wn = (wid >> 1) * (BN / 2);
    int fr = lane & 15, fk = (lane >> 4) * 8;
    int r0 = t >> 2, c0 = (t & 3) * 8;
    floatx4 acc[FM][FN];
    #pragma unroll
    for (int i = 0; i < FM; ++i)
        #pragma unroll
        for (int j = 0; j < FN; ++j) acc[i][j] = {0.f, 0.f, 0.f, 0.f};
    uint4 ra[AP], rb[BP];
    #pragma unroll
    for (int p = 0; p < AP; ++p)
        ra[p] = *(const uint4*)(A + (size_t)(m0 + r0 + p * 64) * lda + c0);
    #pragma unroll
    for (int p = 0; p < BP; ++p)
        rb[p] = *(const uint4*)(W + (size_t)(n0 + r0 + p * 64) * ldw + c0);
    for (int k0 = 0; k0 < K; k0 += 32) {
        __syncthreads();
        #pragma unroll
        for (int p = 0; p < AP; ++p) *(uint4*)&As[(r0 + p * 64) * PAD + c0] = ra[p];
        #pragma unroll
        for (int p = 0; p < BP; ++p) *(uint4*)&Bs[(r0 + p * 64) * PAD + c0] = rb[p];
        __syncthreads();
        if (k0 + 32 < K) {
            #pragma unroll
            for (int p = 0; p < AP; ++p)
                ra[p] = *(const uint4*)(A + (size_t)(m0 + r0 + p * 64) * lda + k0 + 32 + c0);
            #pragma unroll
            for (int p = 0; p < BP; ++p)
                rb[p] = *(const uint4*)(W + (size_t)(n0 + r0 + p * 64) * ldw + k0 + 32 + c0);
        }
        bf16x8 af[FM], bw[FN];
        #pragma unroll
        for (int i = 0; i < FM; ++i)
            af[i] = *(const bf16x8*)&As[(wm + i * 16 + fr) * PAD + fk];
        #pragma unroll
        for (int j = 0; j < FN; ++j)
            bw[j] = *(const bf16x8*)&Bs[(wn + j * 16 + fr) * PAD + fk];
        #pragma unroll
        for (int i = 0; i < FM; ++i)
            #pragma unroll
            for (int j = 0; j < FN; ++j)
                acc[i][j] = __builtin_amdgcn_mfma_f32_16x16x32_bf16(af[i], bw[j], acc[i][j], 0, 0, 0);
    }
    int rbase = (lane >> 4) * 4, cc = lane & 15;
    #pragma unroll
    for (int j = 0; j < FN; ++j) {
        int n = n0 + wn + j * 16 + cc;
        float bv = bias ? bias[n] : 0.f;
        float scl = 0.f, shf = 0.f;
        if (EPI == 2) { scl = bnG[n] * BN_RSQ; shf = bnB[n]; }
        #pragma unroll
        for (int i = 0; i < FM; ++i) {
            #pragma unroll
            for (int r = 0; r < 4; ++r) {
                int m = m0 + wm + i * 16 + rbase + r;
                float v = acc[i][j][r] + bv;
                if (EPI == 2) v = gelu_f(v * scl + shf);
                if (EPI == 0) {
                    Cf[(size_t)m * ldc + n] = v;
                } else if (EPI == 2) {
                    Cf[(size_t)m * ldc + n] = v;
                    Cb[(size_t)m * ldc + n] = f2bf(v);
                } else {
                    if (n < 512) Cb[(size_t)m * 512 + n] = f2bf(v);
                    else Cb2[(size_t)m * 512 + (n - 512)] = f2bf(v / (1.f + __expf(-v)));
                }
            }
        }
    }
}

// ---------------------------------------------------------------------------
// conv2: 9-shift implicit MFMA GEMM, 128px x 64oc tile, BK=64 (18 steps),
// reg dbuf with EXPLICIT SCALAR uint4s (array-by-ref spills to scratch).
// ---------------------------------------------------------------------------
#define C2_LOAD(step)                                                            \
    {                                                                            \
        int s_ = (step) >> 1, ich_ = ((step) & 1) * 64;                          \
        int ky_ = s_ / 3, kx_ = s_ % 3;                                          \
        int sy_ = y0 + (ra_row >> 6) + ky_ - 1;                                  \
        int sx_ = (ra_row & 63) + kx_ - 1;                                       \
        bool v_ = ((unsigned)sy_ < 64u) && ((unsigned)sx_ < 64u);                \
        const ushort* ap_ = hb + ((size_t)(sy_ * 64 + sx_)) * 128 + ich_ + ra_c; \
        uint4 zz_ = make_uint4(0u, 0u, 0u, 0u);                                  \
        ra0 = v_ ? *(const uint4*)(ap_ + 0)  : zz_;                              \
        ra1 = v_ ? *(const uint4*)(ap_ + 8)  : zz_;                              \
        ra2 = v_ ? *(const uint4*)(ap_ + 16) : zz_;                              \
        ra3 = v_ ? *(const uint4*)(ap_ + 24) : zz_;                              \
        const ushort* wp_ = w2b + (size_t)(n0 + rb_row) * 1152 + s_ * 128 + ich_ + rb_c; \
        rb0 = *(const uint4*)(wp_ + 0);                                          \
        rb1 = *(const uint4*)(wp_ + 8);                                          \
    }

__global__ __launch_bounds__(256, 2) void conv2_mfma(
    const ushort* __restrict__ h1b, const ushort* __restrict__ w2b,
    const float* __restrict__ cb, const float* __restrict__ g,
    const float* __restrict__ bb, ushort* __restrict__ h2b)
{
    constexpr int PAD = 72;
    __shared__ __align__(16) ushort As[128 * PAD];
    __shared__ __align__(16) ushort Bs[64 * PAD];
    int t = threadIdx.x;
    int m0 = blockIdx.x * 128, n0 = blockIdx.y * 64;
    int b = m0 >> 12;
    int y0 = (m0 & 4095) >> 6;
    int lane = t & 63, wid = t >> 6;
    int wm = (wid & 1) * 64, wn = (wid >> 1) * 32;
    int fr = lane & 15, fk = (lane >> 4) * 8;
    int ra_row = t >> 1, ra_c = (t & 1) * 32;
    int rb_row = t >> 2, rb_c = (t & 3) * 16;
    floatx4 acc[4][2];
    #pragma unroll
    for (int i = 0; i < 4; ++i)
        #pragma unroll
        for (int j = 0; j < 2; ++j) acc[i][j] = {0.f, 0.f, 0.f, 0.f};
    const ushort* hb = h1b + (size_t)b * 4096 * 128;

    uint4 ra0, ra1, ra2, ra3, rb0, rb1;
    C2_LOAD(0);
    for (int step = 0; step < 18; ++step) {
        __syncthreads();
        *(uint4*)&As[ra_row * PAD + ra_c + 0]  = ra0;
        *(uint4*)&As[ra_row * PAD + ra_c + 8]  = ra1;
        *(uint4*)&As[ra_row * PAD + ra_c + 16] = ra2;
        *(uint4*)&As[ra_row * PAD + ra_c + 24] = ra3;
        *(uint4*)&Bs[rb_row * PAD + rb_c + 0]  = rb0;
        *(uint4*)&Bs[rb_row * PAD + rb_c + 8]  = rb1;
        __syncthreads();
        if (step + 1 < 18) C2_LOAD(step + 1);
        #pragma unroll
        for (int ks = 0; ks < 64; ks += 32) {
            bf16x8 af[4], bw[2];
            #pragma unroll
            for (int i = 0; i < 4; ++i)
                af[i] = *(const bf16x8*)&As[(wm + i * 16 + fr) * PAD + ks + fk];
            #pragma unroll
            for (int j = 0; j < 2; ++j)
                bw[j] = *(const bf16x8*)&Bs[(wn + j * 16 + fr) * PAD + ks + fk];
            #pragma unroll
            for (int i = 0; i < 4; ++i)
                #pragma unroll
                for (int j = 0; j < 2; ++j)
                    acc[i][j] = __builtin_amdgcn_mfma_f32_16x16x32_bf16(af[i], bw[j], acc[i][j], 0, 0, 0);
        }
    }
    int rbase = (lane >> 4) * 4, cc = lane & 15;
    #pragma unroll
    for (int j = 0; j < 2; ++j) {
        int n = n0 + wn + j * 16 + cc;
        float scl = g[n] * BN_RSQ, shf = bb[n], bv2 = cb[n];
        #pragma unroll
        for (int i = 0; i < 4; ++i) {
            #pragma unroll
            for (int r = 0; r < 4; ++r) {
                int m = m0 + wm + i * 16 + rbase + r;
                float v = gelu_f((acc[i][j][r] + bv2) * scl + shf);
                h2b[(size_t)m * 256 + n] = f2bf(v);
            }
        }
    }
}

// Apb[m][s*256+ic] = h2b[b, 2oy+ky, 2ox+kx, ic]
__global__ void im2col_bf16(const ushort* __restrict__ h2b, ushort* __restrict__ Apb)
{
    int idx = blockIdx.x * 256 + threadIdx.x;          // 524288 uint4 chunks
    int k8 = idx & 127;
    int m = idx >> 7;
    int b = m >> 10, oy = (m >> 5) & 31, ox = m & 31;
    int s = k8 >> 5, ic8 = k8 & 31;
    int ky = s >> 1, kx = s & 1;
    uint4 v = *(const uint4*)(h2b + ((size_t)(b * 4096 + (2 * oy + ky) * 64 + 2 * ox + kx)) * 256 + ic8 * 8);
    *(uint4*)(Apb + (size_t)m * 1024 + k8 * 8) = v;
}

// ---------------------------------------------------------------------------
// fp32 tiled GEMM (reg dbuf): C[m*ldc+n] = act(A @ W^T + bias). act 0/2.
// (used for head FC only now)
// ---------------------------------------------------------------------------
template<int BM, int BN, int BK, int TM, int TN>
__global__ __launch_bounds__(256) void gemm_kernel(
    const float* __restrict__ A, int lda,
    const float* __restrict__ W, int ldw,
    const float* __restrict__ bias,
    float* __restrict__ C, int ldc,
    int M, int N, int K, int act)
{
    static_assert(BM * BK / 4 == 256 && BN * BK / 4 == 256, "staging shape");
    __shared__ float As[BK][BM + 4];
    __shared__ float Bs[BK][BN + 4];
    int t = threadIdx.x;
    int m0 = blockIdx.x * BM, n0 = blockIdx.y * BN;
    float acc[TM][TN];
    #pragma unroll
    for (int i = 0; i < TM; i++)
        #pragma unroll
        for (int j = 0; j < TN; j++) acc[i][j] = 0.f;
    const int LPR = BK / 4;
    int lr = t / LPR, lc4 = (t % LPR) * 4;
    int ty = t >> 4, tx = t & 15;
    int ma = m0 + lr, nb = n0 + lr;
    float4 va = make_float4(0.f, 0.f, 0.f, 0.f);
    float4 vb = make_float4(0.f, 0.f, 0.f, 0.f);
    if (ma < M) va = *(const float4*)(A + (size_t)ma * lda + lc4);
    if (nb < N) vb = *(const float4*)(W + (size_t)nb * ldw + lc4);
    for (int k0 = 0; k0 < K; k0 += BK) {
        __syncthreads();
        As[lc4 + 0][lr] = va.x; As[lc4 + 1][lr] = va.y;
        As[lc4 + 2][lr] = va.z; As[lc4 + 3][lr] = va.w;
        Bs[lc4 + 0][lr] = vb.x; Bs[lc4 + 1][lr] = vb.y;
        Bs[lc4 + 2][lr] = vb.z; Bs[lc4 + 3][lr] = vb.w;
        __syncthreads();
        if (k0 + BK < K) {
            if (ma < M) va = *(const float4*)(A + (size_t)ma * lda + k0 + BK + lc4);
            if (nb < N) vb = *(const float4*)(W + (size_t)nb * ldw + k0 + BK + lc4);
        }
        #pragma unroll
        for (int kk = 0; kk < BK; ++kk) {
            float a[TM], bfr[TN];
            #pragma unroll
            for (int i = 0; i < TM; i += 4)
                *(float4*)&a[i] = *(const float4*)&As[kk][ty * TM + i];
            #pragma unroll
            for (int j = 0; j < TN; j += 4)
                *(float4*)&bfr[j] = *(const float4*)&Bs[kk][tx * TN + j];
            #pragma unroll
            for (int i = 0; i < TM; i++)
                #pragma unroll
                for (int j = 0; j < TN; j++) acc[i][j] = fmaf(a[i], bfr[j], acc[i][j]);
        }
    }
    #pragma unroll
    for (int i = 0; i < TM; i++) {
        int m = m0 + ty * TM + i;
        if (m >= M) continue;
        #pragma unroll
        for (int j = 0; j < TN; j++) {
            int n = n0 + tx * TN + j;
            if (n >= N) continue;
            float v = acc[i][j];
            if (bias) v += bias[n];
            if (act == 2) v = softplus_f(v);
            C[(size_t)m * ldc + n] = v;
        }
    }
}

// ---------------------------------------------------------------------------
// Depthwise conv1d (K=4, pad(1,2)) in [b,l,d], bf16 in -> bf16 out (xlb == u).
// ---------------------------------------------------------------------------
__global__ __launch_bounds__(256) void dwconv(
    const ushort* __restrict__ xib, const float* __restrict__ cw,
    const float* __restrict__ cb, ushort* __restrict__ xlb)
{
    int idx = blockIdx.x * 256 + threadIdx.x;   // 524288
    int d4 = (idx & 127) * 4;
    int bl = idx >> 7;
    int b = bl >> 10, l = bl & 1023;
    float4 w0 = *(const float4*)(cw + d4 * 4);
    float4 w1 = *(const float4*)(cw + d4 * 4 + 4);
    float4 w2 = *(const float4*)(cw + d4 * 4 + 8);
    float4 w3 = *(const float4*)(cw + d4 * 4 + 12);
    float4 acc = *(const float4*)(cb + d4);
    const ushort* rowb = xib + ((size_t)b << 19) + d4;
    #pragma unroll
    for (int k = 0; k < 4; ++k) {
        int ll = l + k - 1;
        if ((unsigned)ll < 1024u) {
            uint2 p = *(const uint2*)(rowb + (size_t)ll * 512);
            acc.x = fmaf(bf2f((ushort)(p.x & 0xffffu)), ((const float*)&w0)[k], acc.x);
            acc.y = fmaf(bf2f((ushort)(p.x >> 16)),     ((const float*)&w1)[k], acc.y);
            acc.z = fmaf(bf2f((ushort)(p.y & 0xffffu)), ((const float*)&w2)[k], acc.z);
            acc.w = fmaf(bf2f((ushort)(p.y >> 16)),     ((const float*)&w3)[k], acc.w);
        }
    }
    uint2 pk;
    pk.x = (uint)f2bf(acc.x) | ((uint)f2bf(acc.y) << 16);
    pk.y = (uint)f2bf(acc.z) | ((uint)f2bf(acc.w) << 16);
    *(uint2*)(xlb + (size_t)bl * 512 + d4) = pk;
}

// ---------------------------------------------------------------------------
// Chunked scan pass 1 w/ fused dt_proj. Block = (b, dgG, ch): 512 thr, 32 d.
// Td computed in-LDS: softplus(xdbl[:, :32] @ dpw^T + dpb). u read from xlb.
// ---------------------------------------------------------------------------
__global__ __launch_bounds__(512) void scan_part1(
    const float* __restrict__ xdbl, const ushort* __restrict__ xlb,
    const float* __restrict__ dpw, const float* __restrict__ dpb,
    const float* __restrict__ alog,
    float* __restrict__ Psum, float* __restrict__ hFsum)
{
    __shared__ float Td[32][132];
    __shared__ float Tu[32][132];
    __shared__ float TB[16][132];
    __shared__ float xd[128][32];
    __shared__ float dpw_s[32][33];
    __shared__ float dpb_s[32];
    int t = threadIdx.x;
    int bid = blockIdx.x;                 // 512 = b(4) x dgG(16) x ch(8)
    int ch = bid & 7, dgG = (bid >> 3) & 15, b = bid >> 7;
    int d0 = dgG * 32;
    int bl0 = b * 1024 + ch * 128;
    // stage xd (dt slice of xdbl, row-major) : 1024 float4s
    #pragma unroll
    for (int r = 0; r < 2; ++r) {
        int idx = r * 512 + t;
        int l = idx >> 3, k4 = (idx & 7) * 4;
        float4 v = *(const float4*)(xdbl + (size_t)(bl0 + l) * 64 + k4);
        *(float4*)&xd[l][k4] = v;
    }
    // stage Tu from bf16 xlb (transposed)
    {
        int l = t >> 2, d8 = (t & 3) * 8;
        uint4 p = *(const uint4*)(xlb + (size_t)(bl0 + l) * 512 + d0 + d8);
        Tu[d8 + 0][l] = bf2f((ushort)(p.x & 0xffffu));
        Tu[d8 + 1][l] = bf2f((ushort)(p.x >> 16));
        Tu[d8 + 2][l] = bf2f((ushort)(p.y & 0xffffu));
        Tu[d8 + 3][l] = bf2f((ushort)(p.y >> 16));
        Tu[d8 + 4][l] = bf2f((ushort)(p.z & 0xffffu));
        Tu[d8 + 5][l] = bf2f((ushort)(p.z >> 16));
        Tu[d8 + 6][l] = bf2f((ushort)(p.w & 0xffffu));
        Tu[d8 + 7][l] = bf2f((ushort)(p.w >> 16));
    }
    // stage TB
    {
        int l = t >> 2, n4 = (t & 3) * 4;
        float4 bv = *(const float4*)(xdbl + (size_t)(bl0 + l) * 64 + 32 + n4);
        TB[n4 + 0][l] = bv.x; TB[n4 + 1][l] = bv.y; TB[n4 + 2][l] = bv.z; TB[n4 + 3][l] = bv.w;
    }
    // stage dpw (block's 32 d rows x 32 k), dpb
    #pragma unroll
    for (int r = 0; r < 2; ++r) {
        int idx = r * 512 + t;
        int dd = idx >> 5, kk = idx & 31;
        dpw_s[dd][kk] = dpw[(size_t)(d0 + dd) * 32 + kk];
    }
    if (t < 32) dpb_s[t] = dpb[d0 + t];
    __syncthreads();
    // fused dt_proj: Td[d][l] = softplus(xd[l][:] . dpw_s[d][:] + dpb_s[d])
    {
        int dd = t & 31, lb = (t >> 5) * 8;
        #pragma unroll
        for (int j = 0; j < 8; ++j) {
            int l = lb + j;
            float s = dpb_s[dd];
            #pragma unroll
            for (int k = 0; k < 32; ++k) s = fmaf(xd[l][k], dpw_s[dd][k], s);
            Td[dd][l] = softplus_f(s);
        }
    }
    __syncthreads();
    int w = t >> 6, lane = t & 63;
    int dl = lane >> 4, n = lane & 15;
    int col = w * 4 + dl;
    int d = d0 + col;
    float Ac = -__expf(alog[d * 16 + n]);
    float h = 0.f, P = 1.f;
    for (int l4 = 0; l4 < 32; ++l4) {
        float4 de = *(const float4*)&Td[col][l4 * 4];
        float4 uu = *(const float4*)&Tu[col][l4 * 4];
        float4 Bv = *(const float4*)&TB[n][l4 * 4];
        float a;
        a = __expf(de.x * Ac); h = a * h + de.x * Bv.x * uu.x; P *= a;
        a = __expf(de.y * Ac); h = a * h + de.y * Bv.y * uu.y; P *= a;
        a = __expf(de.z * Ac); h = a * h + de.z * Bv.z * uu.z; P *= a;
        a = __expf(de.w * Ac); h = a * h + de.w * Bv.w * uu.w; P *= a;
    }
    size_t si = ((size_t)(b * 128 + dgG * 8 + w) * 8 + ch) * 64 + lane;
    Psum[si] = P;
    hFsum[si] = h;
}

// ---------------------------------------------------------------------------
// Chunked scan pass 2 w/ fused dt_proj: combine summaries, rerun chunk,
// y + gate -> ybb bf16 IN PLACE over xlb (each block owns its tile).
// yb array double-duty: xd staging before the scan, y accumulator after.
// ---------------------------------------------------------------------------
__global__ __launch_bounds__(512) void scan_part2(
    const float* __restrict__ xdbl, const ushort* __restrict__ xlb,
    const float* __restrict__ dpw, const float* __restrict__ dpb,
    const float* __restrict__ alog, const float* __restrict__ dssm,
    const ushort* __restrict__ resb, ushort* __restrict__ ybb,
    const float* __restrict__ Psum, const float* __restrict__ hFsum)
{
    __shared__ float Td[32][132];
    __shared__ float Tu[32][132];
    __shared__ float TB[16][132];
    __shared__ float TC[16][132];
    __shared__ float yb[128][33];          // staging: xd[l][k] (k<32); later y
    __shared__ float dpw_s[32][33];
    __shared__ float dpb_s[32];
    int t = threadIdx.x;
    int bid = blockIdx.x;                 // 512 = b(4) x dgG(16) x ch(8)
    int ch = bid & 7, dgG = (bid >> 3) & 15, b = bid >> 7;
    int d0 = dgG * 32;
    int bl0 = b * 1024 + ch * 128;
    #pragma unroll
    for (int r = 0; r < 2; ++r) {
        int idx = r * 512 + t;
        int l = idx >> 3, k4 = (idx & 7) * 4;
        float4 v = *(const float4*)(xdbl + (size_t)(bl0 + l) * 64 + k4);
        *(float4*)&yb[l][k4] = v;
    }
    {
        int l = t >> 2, d8 = (t & 3) * 8;
        uint4 p = *(const uint4*)(xlb + (size_t)(bl0 + l) * 512 + d0 + d8);
        Tu[d8 + 0][l] = bf2f((ushort)(p.x & 0xffffu));
        Tu[d8 + 1][l] = bf2f((ushort)(p.x >> 16));
        Tu[d8 + 2][l] = bf2f((ushort)(p.y & 0xffffu));
        Tu[d8 + 3][l] = bf2f((ushort)(p.y >> 16));
        Tu[d8 + 4][l] = bf2f((ushort)(p.z & 0xffffu));
        Tu[d8 + 5][l] = bf2f((ushort)(p.z >> 16));
        Tu[d8 + 6][l] = bf2f((ushort)(p.w & 0xffffu));
        Tu[d8 + 7][l] = bf2f((ushort)(p.w >> 16));
    }
    {
        int l = t >> 2, n4 = (t & 3) * 4;
        float4 bv = *(const float4*)(xdbl + (size_t)(bl0 + l) * 64 + 32 + n4);
        float4 cv = *(const float4*)(xdbl + (size_t)(bl0 + l) * 64 + 48 + n4);
        TB[n4 + 0][l] = bv.x; TB[n4 + 1][l] = bv.y; TB[n4 + 2][l] = bv.z; TB[n4 + 3][l] = bv.w;
        TC[n4 + 0][l] = cv.x; TC[n4 + 1][l] = cv.y; TC[n4 + 2][l] = cv.z; TC[n4 + 3][l] = cv.w;
    }
    #pragma unroll
    for (int r = 0; r < 2; ++r) {
        int idx = r * 512 + t;
        int dd = idx >> 5, kk = idx & 31;
        dpw_s[dd][kk] = dpw[(size_t)(d0 + dd) * 32 + kk];
    }
    if (t < 32) dpb_s[t] = dpb[d0 + t];
    __syncthreads();
    {
        int dd = t & 31, lb = (t >> 5) * 8;
        #pragma unroll
        for (int j = 0; j < 8; ++j) {
            int l = lb + j;
            float s = dpb_s[dd];
            #pragma unroll
            for (int k = 0; k < 32; ++k) s = fmaf(yb[l][k], dpw_s[dd][k], s);
            Td[dd][l] = softplus_f(s);
        }
    }
    int w = t >> 6, lane = t & 63;
    int dl = lane >> 4, n = lane & 15;
    int col = w * 4 + dl;
    int d = d0 + col;
    float Ac = -__expf(alog[d * 16 + n]);
    float Dd = dssm[d];
    float h = 0.f;
    {
        size_t sbase = (size_t)(b * 128 + dgG * 8 + w) * 512 + lane;
        for (int cc = 0; cc < ch; ++cc) {
            float Pv = Psum[sbase + (size_t)cc * 64];
            float hv = hFsum[sbase + (size_t)cc * 64];
            h = Pv * h + hv;
        }
    }
    __syncthreads();        // Td ready; xd reads (in yb) done before yb writes
    for (int l4 = 0; l4 < 32; ++l4) {
        float4 de = *(const float4*)&Td[col][l4 * 4];
        float4 uu = *(const float4*)&Tu[col][l4 * 4];
        float4 Bv = *(const float4*)&TB[n][l4 * 4];
        float4 Cv = *(const float4*)&TC[n][l4 * 4];
        float p0, p1, p2, p3;
        h = __expf(de.x * Ac) * h + de.x * Bv.x * uu.x; p0 = h * Cv.x;
        h = __expf(de.y * Ac) * h + de.y * Bv.y * uu.y; p1 = h * Cv.y;
        h = __expf(de.z * Ac) * h + de.z * Bv.z * uu.z; p2 = h * Cv.z;
        h = __expf(de.w * Ac) * h + de.w * Bv.w * uu.w; p3 = h * Cv.w;
        #pragma unroll
        for (int off = 1; off < 16; off <<= 1) {
            p0 += __shfl_xor(p0, off);
            p1 += __shfl_xor(p1, off);
            p2 += __shfl_xor(p2, off);
            p3 += __shfl_xor(p3, off);
        }
        if (n == 0) {
            int l = l4 * 4;
            yb[l + 0][col] = fmaf(uu.x, Dd, p0);
            yb[l + 1][col] = fmaf(uu.y, Dd, p1);
            yb[l + 2][col] = fmaf(uu.z, Dd, p2);
            yb[l + 3][col] = fmaf(uu.w, Dd, p3);
        }
    }
    __syncthreads();
    size_t base = ((size_t)(b * 1024 + ch * 128)) * 512 + d0;   // ushort offset
    const uint* rp32 = (const uint*)(resb + base);
    uint* yp32 = (uint*)(ybb + base);
    #pragma unroll
    for (int j = 0; j < 4; ++j) {
        int idx = j * 512 + t;
        int l = idx >> 4, du = idx & 15;
        float v0 = yb[l][du * 2 + 0];
        float v1 = yb[l][du * 2 + 1];
        uint rr = rp32[(size_t)l * 256 + du];
        float y0 = v0 * bf2f((ushort)(rr & 0xffffu));
        float y1 = v1 * bf2f((ushort)(rr >> 16));
        yp32[(size_t)l * 256 + du] = (uint)f2bf(y0) | ((uint)f2bf(y1) << 16);
    }
}

// s[row] = LN(o[row])*g + b + s[row]; also writes bf16 copy sb. One wave/row.
__global__ __launch_bounds__(256) void ln_res_kernel(
    const float* __restrict__ o, const float* __restrict__ g,
    const float* __restrict__ bb, float* __restrict__ s, ushort* __restrict__ sb)
{
    int row = blockIdx.x * 4 + (threadIdx.x >> 6);
    int lane = threadIdx.x & 63;
    const float4* orow = (const float4*)(o + (size_t)row * 256);
    float4 v = orow[lane];
    float sum = v.x + v.y + v.z + v.w;
    float sq = v.x * v.x + v.y * v.y + v.z * v.z + v.w * v.w;
    #pragma unroll
    for (int off = 1; off < 64; off <<= 1) {
        sum += __shfl_xor(sum, off);
        sq += __shfl_xor(sq, off);
    }
    float m = sum * (1.f / 256.f);
    float var = sq * (1.f / 256.f) - m * m;
    float rstd = rsqrtf(var + 1e-5f);
    float4 gg = ((const float4*)g)[lane];
    float4 bv = ((const float4*)bb)[lane];
    float4* srow = (float4*)(s + (size_t)row * 256);
    float4 sv = srow[lane];
    sv.x += (v.x - m) * rstd * gg.x + bv.x;
    sv.y += (v.y - m) * rstd * gg.y + bv.y;
    sv.z += (v.z - m) * rstd * gg.z + bv.z;
    sv.w += (v.w - m) * rstd * gg.w + bv.w;
    srow[lane] = sv;
    uint2 pk;
    pk.x = (uint)f2bf(sv.x) | ((uint)f2bf(sv.y) << 16);
    pk.y = (uint)f2bf(sv.z) | ((uint)f2bf(sv.w) << 16);
    *(uint2*)(sb + (size_t)row * 256 + lane * 4) = pk;
}

// mean over l then LN over 256 channels. grid 4 x 256.
__global__ __launch_bounds__(256) void pool_ln_kernel(
    const float* __restrict__ s, const float* __restrict__ nw,
    const float* __restrict__ nb, float* __restrict__ sln)
{
    int b = blockIdx.x, c = threadIdx.x;
    const float* p = s + (size_t)b * 262144 + c;
    float acc = 0.f;
    for (int l = 0; l < 1024; ++l) acc += p[(size_t)l * 256];
    float pooled = acc * (1.f / 1024.f);
    __shared__ float rs[4], rq[4];
    float sum = pooled, sq = pooled * pooled;
    #pragma unroll
    for (int off = 1; off < 64; off <<= 1) {
        sum += __shfl_xor(sum, off);
        sq += __shfl_xor(sq, off);
    }
    int w = threadIdx.x >> 6;
    if ((threadIdx.x & 63) == 0) { rs[w] = sum; rq[w] = sq; }
    __syncthreads();
    sum = rs[0] + rs[1] + rs[2] + rs[3];
    sq = rq[0] + rq[1] + rq[2] + rq[3];
    float m = sum * (1.f / 256.f);
    float var = sq * (1.f / 256.f) - m * m;
    float rstd = rsqrtf(var + 1e-5f);
    sln[b * 256 + c] = (pooled - m) * rstd * nw[c] + nb[c];
}

// softmax over 1000 logits per b
__global__ __launch_bounds__(256) void softmax_kernel(float* __restrict__ out)
{
    int b = threadIdx.x >> 6, lane = threadIdx.x & 63;
    const float* lg = out + b * 1000;
    float v[16];
    float mx = -1e30f;
    #pragma unroll
    for (int j = 0; j < 16; ++j) {
        int i = lane + j * 64;
        v[j] = (i < 1000) ? lg[i] : -1e30f;
        mx = fmaxf(mx, v[j]);
    }
    #pragma unroll
    for (int off = 1; off < 64; off <<= 1) mx = fmaxf(mx, __shfl_xor(mx, off));
    float sum = 0.f;
    #pragma unroll
    for (int j = 0; j < 16; ++j) {
        int i = lane + j * 64;
        if (i < 1000) { v[j] = __expf(v[j] - mx); sum += v[j]; }
    }
    #pragma unroll
    for (int off = 1; off < 64; off <<= 1) sum += __shfl_xor(sum, off);
    float inv = 1.f / sum;
    float* so = out + 4000 + b * 1000;
    #pragma unroll
    for (int j = 0; j < 16; ++j) {
        int i = lane + j * 64;
        if (i < 1000) so[i] = v[j] * inv;
    }
}

// ---------------------------------------------------------------------------
extern "C" void kernel_launch(void* const* d_in, const int* in_sizes, int n_in,
                              void* d_out, int out_size, void* d_ws, size_t ws_size,
                              hipStream_t stream)
{
    const float* x    = (const float*)d_in[0];
    const float* c1w  = (const float*)d_in[1];
    const float* c1b  = (const float*)d_in[2];
    const float* g1   = (const float*)d_in[3];
    const float* b1   = (const float*)d_in[4];
    const float* c2w  = (const float*)d_in[5];
    const float* c2b  = (const float*)d_in[6];
    const float* g2   = (const float*)d_in[7];
    const float* b2   = (const float*)d_in[8];
    const float* pw   = (const float*)d_in[9];
    const float* pb   = (const float*)d_in[10];
    const float* g3   = (const float*)d_in[11];
    const float* b3   = (const float*)d_in[12];
    const float* ipw  = (const float*)d_in[13];
    const float* ipb  = (const float*)d_in[14];
    const float* cw   = (const float*)d_in[15];
    const float* cb   = (const float*)d_in[16];
    const float* xpw  = (const float*)d_in[17];
    const float* dpw  = (const float*)d_in[18];
    const float* dpb  = (const float*)d_in[19];
    const float* alog = (const float*)d_in[20];
    const float* dssm = (const float*)d_in[21];
    const float* opw  = (const float*)d_in[22];
    const float* opb  = (const float*)d_in[23];
    const float* lnw  = (const float*)d_in[24];
    const float* lnb  = (const float*)d_in[25];
    const float* nw   = (const float*)d_in[26];
    const float* nb   = (const float*)d_in[27];
    const float* fcw  = (const float*)d_in[28];
    const float* fcb  = (const float*)d_in[29];
    float* out = (float*)d_out;
    float* wsf = (float*)d_ws;

    float*  s_   = wsf;
    ushort* sb   = (ushort*)(wsf + 1048576);
    ushort* xib  = (ushort*)(wsf + 1572864);
    ushort* h2b  = (ushort*)(wsf + 1572864);
    float*  obuf = wsf + 1572864;
    ushort* resb = (ushort*)(wsf + 3670016);
    ushort* xlb  = (ushort*)(wsf + 4718592);   // == u == ybb (in-place gate)
    ushort* ybb  = (ushort*)(wsf + 4718592);
    ushort* h1b  = (ushort*)(wsf + 4718592);
    ushort* Apb  = (ushort*)(wsf + 6815744);
    float*  xdbl = wsf + 8912896;
    ushort* ipwb = (ushort*)(wsf + 9175040);
    ushort* opwb = (ushort*)(wsf + 9699328);
    ushort* w2b  = (ushort*)(wsf + 9961472);
    ushort* pwTb = (ushort*)(wsf + 10108928);
    float*  sln  = wsf + 10240000;
    float*  Psum = wsf + 10241024;
    float*  hFsum= wsf + 10503168;
    ushort* xpwb = (ushort*)(wsf + 10765312);

    // --- fused weight prep (1 dispatch) ---
    hipLaunchKernelGGL(wprep, dim3(8832), dim3(256), 0, stream,
                       ipw, opw, c2w, pw, xpw, ipwb, opwb, w2b, pwTb, xpwb);

    // --- conv stem ---
    hipLaunchKernelGGL(conv1_nhwc, dim3(256), dim3(256), 0, stream, x, c1w, c1b, g1, b1, h1b);
    hipLaunchKernelGGL(conv2_mfma, dim3(128, 4), dim3(256), 0, stream, h1b, w2b, c2b, g2, b2, h2b);
    hipLaunchKernelGGL(im2col_bf16, dim3(2048), dim3(256), 0, stream, h2b, Apb);
    hipLaunchKernelGGL((mfma_gemm_bt<64, 64, 2>), dim3(64, 4), dim3(256), 0, stream,
                       Apb, 1024, pwTb, 1024, pb, g3, b3, s_, sb, nullptr, 256, 1024);

    // --- mamba blocks ---
    for (int i = 0; i < 4; ++i) {
        const ushort* ipwb_i = ipwb + (size_t)i * 1024 * 256;
        const float*  ipb_i  = ipb + i * 1024;
        const float*  cw_i   = cw + i * 512 * 4;
        const float*  cb_i   = cb + i * 512;
        const ushort* xpwb_i = xpwb + (size_t)i * 64 * 512;
        const float*  dpw_i  = dpw + (size_t)i * 512 * 32;
        const float*  dpb_i  = dpb + i * 512;
        const float*  alog_i = alog + (size_t)i * 512 * 16;
        const float*  dssm_i = dssm + i * 512;
        const ushort* opwb_i = opwb + (size_t)i * 256 * 512;
        const float*  opb_i  = opb + i * 256;
        const float*  lnw_i  = lnw + i * 256;
        const float*  lnb_i  = lnb + i * 256;

        // in_proj (bf16 MFMA): xib bf16 + silu(res) bf16
        hipLaunchKernelGGL((mfma_gemm_bt<64, 128, 3>), dim3(64, 8), dim3(256), 0, stream,
                           sb, 256, ipwb_i, 256, ipb_i, nullptr, nullptr,
                           nullptr, xib, resb, 0, 256);
        // dwconv -> xlb bf16 (== u)
        hipLaunchKernelGGL(dwconv, dim3(2048), dim3(256), 0, stream, xib, cw_i, cb_i, xlb);
        // x_proj (bf16 MFMA) -> xdbl fp32 [m,64]
        hipLaunchKernelGGL((mfma_gemm_bt<64, 64, 0>), dim3(64, 1), dim3(256), 0, stream,
                           xlb, 512, xpwb_i, 512, nullptr, nullptr, nullptr,
                           xdbl, nullptr, nullptr, 64, 512);
        // chunked scan (dt_proj fused, in-place gate into ybb == xlb)
        hipLaunchKernelGGL(scan_part1, dim3(512), dim3(512), 0, stream,
                           xdbl, xlb, dpw_i, dpb_i, alog_i, Psum, hFsum);
        hipLaunchKernelGGL(scan_part2, dim3(512), dim3(512), 0, stream,
                           xdbl, xlb, dpw_i, dpb_i, alog_i, dssm_i, resb, ybb, Psum, hFsum);
        // out_proj (bf16 MFMA) -> obuf fp32
        hipLaunchKernelGGL((mfma_gemm_bt<64, 64, 0>), dim3(64, 4), dim3(256), 0, stream,
                           ybb, 512, opwb_i, 512, opb_i, nullptr, nullptr,
                           obuf, nullptr, nullptr, 256, 512);
        hipLaunchKernelGGL(ln_res_kernel, dim3(1024), dim3(256), 0, stream,
                           obuf, lnw_i, lnb_i, s_, sb);
    }

    // --- head ---
    hipLaunchKernelGGL(pool_ln_kernel, dim3(4), dim3(256), 0, stream, s_, nw, nb, sln);
    hipLaunchKernelGGL((gemm_kernel<64, 64, 16, 4, 4>), dim3(1, 16), dim3(256), 0, stream,
                       sln, 256, fcw, 256, fcb, out, 1000, 4, 1000, 256, 0);
    hipLaunchKernelGGL(softmax_kernel, dim3(1), dim3(256), 0, stream, out);
}

// Round 13
// 655.015 us; speedup vs baseline: 1.1223x; 1.0012x over previous
//
#include <hip/hip_runtime.h>
#include <math.h>

// ---------------------------------------------------------------------------
// FastImageMamba forward. R13: R12 + 4-step associative composition in both
// scan passes (critical path 4x shorter: 1 fma per 4 timesteps; exps and
// coefficient composition hoisted off the h-dependency chain).
// B=4, DM=256, NL=4, NC=1000, DI=512, NS=16, DTR=32, K=4, L=1024, H=W=64
// ---------------------------------------------------------------------------

#define BN_RSQ 0.99999500003749969f   // 1/sqrt(1+1e-5)

typedef unsigned int uint;
typedef unsigned short ushort;
typedef __bf16 bf16x8 __attribute__((ext_vector_type(8)));
typedef float floatx4 __attribute__((ext_vector_type(4)));

__device__ __forceinline__ float gelu_f(float v) {
    return 0.5f * v * (1.0f + erff(v * 0.70710678118654752f));
}
__device__ __forceinline__ float softplus_f(float v) {
    return (v > 20.f) ? v : log1pf(expf(v));
}
__device__ __forceinline__ ushort f2bf(float f) {
    uint x = __float_as_uint(f);
    x += 0x7fffu + ((x >> 16) & 1u);
    return (ushort)(x >> 16);
}
__device__ __forceinline__ float bf2f(ushort u) {
    return __uint_as_float((uint)u << 16);
}

// ---------------------------------------------------------------------------
// Fused weight prep: all fp32->bf16 weight conversions in one dispatch.
// ---------------------------------------------------------------------------
__global__ void wprep(const float* __restrict__ ipw, const float* __restrict__ opw,
                      const float* __restrict__ c2w, const float* __restrict__ pw,
                      const float* __restrict__ xpw,
                      ushort* __restrict__ ipwb, ushort* __restrict__ opwb,
                      ushort* __restrict__ w2b, ushort* __restrict__ pwTb,
                      ushort* __restrict__ xpwb)
{
    int idx = blockIdx.x * 256 + threadIdx.x;
    if (idx < 1048576) {
        ipwb[idx] = f2bf(ipw[idx]);
    } else if (idx < 1572864) {
        int i = idx - 1048576;
        opwb[i] = f2bf(opw[i]);
    } else if (idx < 1867776) {
        int i = idx - 1572864;
        int oc = i / 1152, k = i % 1152;
        int s = k >> 7, ic = k & 127;
        w2b[i] = f2bf(c2w[(size_t)(oc * 128 + ic) * 9 + s]);
    } else if (idx < 2129920) {
        int i = idx - 1867776;
        int oc = i >> 10, k = i & 1023;
        int s = k >> 8, ic = k & 255;
        int ky = s >> 1, kx = s & 1;
        pwTb[i] = f2bf(pw[((size_t)(oc * 256 + ic) * 2 + ky) * 2 + kx]);
    } else if (idx < 2260992) {
        int i = idx - 2129920;
        xpwb[i] = f2bf(xpw[i]);
    }
}

// ---------------------------------------------------------------------------
// conv1: 3x3 s1p1, IC=3 -> OC=128, NCHW fp32 in, NHWC bf16 out (+bias+BN+GELU)
// ---------------------------------------------------------------------------
__global__ __launch_bounds__(256) void conv1_nhwc(
    const float* __restrict__ x, const float* __restrict__ w,
    const float* __restrict__ cb, const float* __restrict__ g,
    const float* __restrict__ bb, ushort* __restrict__ out)
{
    __shared__ float tin[3][3][64];
    __shared__ float ws[3456];
    int t = threadIdx.x;
    int b = blockIdx.x >> 6, y = blockIdx.x & 63;
    for (int i = t; i < 3456; i += 256) ws[i] = w[i];
    for (int i = t; i < 576; i += 256) {
        int ic = i / 192, r = (i >> 6) % 3, xx = i & 63;
        int gy = y + r - 1;
        tin[ic][r][xx] = ((unsigned)gy < 64u) ? x[((b * 3 + ic) * 64 + gy) * 64 + xx] : 0.f;
    }
    __syncthreads();
    int tx = t & 15, ty = t >> 4;
    int oc0 = tx * 8, px0 = ty * 4;
    float acc[4][8];
    #pragma unroll
    for (int p = 0; p < 4; ++p)
        #pragma unroll
        for (int o = 0; o < 8; ++o) acc[p][o] = 0.f;
    for (int ic = 0; ic < 3; ++ic)
        #pragma unroll
        for (int ky = 0; ky < 3; ++ky)
            #pragma unroll
            for (int kx = 0; kx < 3; ++kx) {
                float av[4];
                #pragma unroll
                for (int p = 0; p < 4; ++p) {
                    int xx = px0 + p + kx - 1;
                    av[p] = ((unsigned)xx < 64u) ? tin[ic][ky][xx] : 0.f;
                }
                #pragma unroll
                for (int o = 0; o < 8; ++o) {
                    float wv = ws[(oc0 + o) * 27 + ic * 9 + ky * 3 + kx];
                    #pragma unroll
                    for (int p = 0; p < 4; ++p) acc[p][o] = fmaf(av[p], wv, acc[p][o]);
                }
            }
    #pragma unroll
    for (int p = 0; p < 4; ++p) {
        uint pk[4];
        #pragma unroll
        for (int o2 = 0; o2 < 4; ++o2) {
            int oc = oc0 + o2 * 2;
            float v0 = gelu_f((acc[p][o2 * 2] + cb[oc]) * (g[oc] * BN_RSQ) + bb[oc]);
            float v1 = gelu_f((acc[p][o2 * 2 + 1] + cb[oc + 1]) * (g[oc + 1] * BN_RSQ) + bb[oc + 1]);
            pk[o2] = (uint)f2bf(v0) | ((uint)f2bf(v1) << 16);
        }
        uint4 vv = make_uint4(pk[0], pk[1], pk[2], pk[3]);
        *(uint4*)(out + ((size_t)((b * 64 + y) * 64 + px0 + p)) * 128 + oc0) = vv;
    }
}

// ---------------------------------------------------------------------------
// bf16 MFMA GEMM (A @ W^T), BMxBN tile, BK=32, 4 waves (2x2), reg dbuf.
// EPI: 0 = +bias -> fp32 Cf[ldc]
//      2 = +bias,BN,GELU -> fp32 Cf + bf16 Cb (same ldc)
//      3 = in_proj: n<512 -> bf16 Cb[m*512+n]; n>=512 -> bf16 silu -> Cb2
// ---------------------------------------------------------------------------
template<int BM, int BN, int EPI>
__global__ __launch_bounds__(256, 2) void mfma_gemm_bt(
    const ushort* __restrict__ A, int lda,
    const ushort* __restrict__ W, int ldw,
    const float* __restrict__ bias,
    const float* __restrict__ bnG, const float* __restrict__ bnB,
    float* __restrict__ Cf, ushort* __restrict__ Cb, ushort* __restrict__ Cb2,
    int ldc, int K)
{
    constexpr int PAD = 40;
    constexpr int AP = BM / 64;
    constexpr int BP = BN / 64;
    constexpr int FM = BM / 32;
    constexpr int FN = BN / 32;
    __shared__ __align__(16) ushort As[BM * PAD];
    __shared__ __align__(16) ushort Bs[BN * PAD];
    int t = threadIdx.x;
    int m0 = blockIdx.x * BM, n0 = blockIdx.y * BN;
    int lane = t & 63, wid = t >> 6;
    int wm = (wid & 1) * (BM / 2), wn = (wid >> 1) * (BN / 2);
    int fr = lane & 15, fk = (lane >> 4) * 8;
    int r0 = t >> 2, c0 = (t & 3) * 8;
    floatx4 acc[FM][FN];
    #pragma unroll
    for (int i = 0; i < FM; ++i)
        #pragma unroll
        for (int j = 0; j < FN; ++j) acc[i][j] = {0.f, 0.f, 0.f, 0.f};
    uint4 ra[AP], rb[BP];
    #pragma unroll
    for (int p = 0; p < AP; ++p)
        ra[p] = *(const uint4*)(A + (size_t)(m0 + r0 + p * 64) * lda + c0);
    #pragma unroll
    for (int p = 0; p < BP; ++p)
        rb[p] = *(const uint4*)(W + (size_t)(n0 + r0 + p * 64) * ldw + c0);
    for (int k0 = 0; k0 < K; k0 += 32) {
        __syncthreads();
        #pragma unroll
        for (int p = 0; p < AP; ++p) *(uint4*)&As[(r0 + p * 64) * PAD + c0] = ra[p];
        #pragma unroll
        for (int p = 0; p < BP; ++p) *(uint4*)&Bs[(r0 + p * 64) * PAD + c0] = rb[p];
        __syncthreads();
        if (k0 + 32 < K) {
            #pragma unroll
            for (int p = 0; p < AP; ++p)
                ra[p] = *(const uint4*)(A + (size_t)(m0 + r0 + p * 64) * lda + k0 + 32 + c0);
            #pragma unroll
            for (int p = 0; p < BP; ++p)
                rb[p] = *(const uint4*)(W + (size_t)(n0 + r0 + p * 64) * ldw + k0 + 32 + c0);
        }
        bf16x8 af[FM], bw[FN];
        #pragma unroll
        for (int i = 0; i < FM; ++i)
            af[i] = *(const bf16x8*)&As[(wm + i * 16 + fr) * PAD + fk];
        #pragma unroll
        for (int j = 0; j < FN; ++j)
            bw[j] = *(const bf16x8*)&Bs[(wn + j * 16 + fr) * PAD + fk];
        #pragma unroll
        for (int i = 0; i < FM; ++i)
            #pragma unroll
            for (int j = 0; j < FN; ++j)
                acc[i][j] = __builtin_amdgcn_mfma_f32_16x16x32_bf16(af[i], bw[j], acc[i][j], 0, 0, 0);
    }
    int rbase = (lane >> 4) * 4, cc = lane & 15;
    #pragma unroll
    for (int j = 0; j < FN; ++j) {
        int n = n0 + wn + j * 16 + cc;
        float bv = bias ? bias[n] : 0.f;
        float scl = 0.f, shf = 0.f;
        if (EPI == 2) { scl = bnG[n] * BN_RSQ; shf = bnB[n]; }
        #pragma unroll
        for (int i = 0; i < FM; ++i) {
            #pragma unroll
            for (int r = 0; r < 4; ++r) {
                int m = m0 + wm + i * 16 + rbase + r;
                float v = acc[i][j][r] + bv;
                if (EPI == 2) v = gelu_f(v * scl + shf);
                if (EPI == 0) {
                    Cf[(size_t)m * ldc + n] = v;
                } else if (EPI == 2) {
                    Cf[(size_t)m * ldc + n] = v;
                    Cb[(size_t)m * ldc + n] = f2bf(v);
                } else {
                    if (n < 512) Cb[(size_t)m * 512 + n] = f2bf(v);
                    else Cb2[(size_t)m * 512 + (n - 512)] = f2bf(v / (1.f + __expf(-v)));
                }
            }
        }
    }
}

// ---------------------------------------------------------------------------
// conv2: 9-shift implicit MFMA GEMM, 128px x 64oc tile, BK=64 (18 steps),
// reg dbuf with EXPLICIT SCALAR uint4s (array-by-ref spills to scratch).
// ---------------------------------------------------------------------------
#define C2_LOAD(step)                                                            \
    {                                                                            \
        int s_ = (step) >> 1, ich_ = ((step) & 1) * 64;                          \
        int ky_ = s_ / 3, kx_ = s_ % 3;                                          \
        int sy_ = y0 + (ra_row >> 6) + ky_ - 1;                                  \
        int sx_ = (ra_row & 63) + kx_ - 1;                                       \
        bool v_ = ((unsigned)sy_ < 64u) && ((unsigned)sx_ < 64u);                \
        const ushort* ap_ = hb + ((size_t)(sy_ * 64 + sx_)) * 128 + ich_ + ra_c; \
        uint4 zz_ = make_uint4(0u, 0u, 0u, 0u);                                  \
        ra0 = v_ ? *(const uint4*)(ap_ + 0)  : zz_;                              \
        ra1 = v_ ? *(const uint4*)(ap_ + 8)  : zz_;                              \
        ra2 = v_ ? *(const uint4*)(ap_ + 16) : zz_;                              \
        ra3 = v_ ? *(const uint4*)(ap_ + 24) : zz_;                              \
        const ushort* wp_ = w2b + (size_t)(n0 + rb_row) * 1152 + s_ * 128 + ich_ + rb_c; \
        rb0 = *(const uint4*)(wp_ + 0);                                          \
        rb1 = *(const uint4*)(wp_ + 8);                                          \
    }

__global__ __launch_bounds__(256, 2) void conv2_mfma(
    const ushort* __restrict__ h1b, const ushort* __restrict__ w2b,
    const float* __restrict__ cb, const float* __restrict__ g,
    const float* __restrict__ bb, ushort* __restrict__ h2b)
{
    constexpr int PAD = 72;
    __shared__ __align__(16) ushort As[128 * PAD];
    __shared__ __align__(16) ushort Bs[64 * PAD];
    int t = threadIdx.x;
    int m0 = blockIdx.x * 128, n0 = blockIdx.y * 64;
    int b = m0 >> 12;
    int y0 = (m0 & 4095) >> 6;
    int lane = t & 63, wid = t >> 6;
    int wm = (wid & 1) * 64, wn = (wid >> 1) * 32;
    int fr = lane & 15, fk = (lane >> 4) * 8;
    int ra_row = t >> 1, ra_c = (t & 1) * 32;
    int rb_row = t >> 2, rb_c = (t & 3) * 16;
    floatx4 acc[4][2];
    #pragma unroll
    for (int i = 0; i < 4; ++i)
        #pragma unroll
        for (int j = 0; j < 2; ++j) acc[i][j] = {0.f, 0.f, 0.f, 0.f};
    const ushort* hb = h1b + (size_t)b * 4096 * 128;

    uint4 ra0, ra1, ra2, ra3, rb0, rb1;
    C2_LOAD(0);
    for (int step = 0; step < 18; ++step) {
        __syncthreads();
        *(uint4*)&As[ra_row * PAD + ra_c + 0]  = ra0;
        *(uint4*)&As[ra_row * PAD + ra_c + 8]  = ra1;
        *(uint4*)&As[ra_row * PAD + ra_c + 16] = ra2;
        *(uint4*)&As[ra_row * PAD + ra_c + 24] = ra3;
        *(uint4*)&Bs[rb_row * PAD + rb_c + 0]  = rb0;
        *(uint4*)&Bs[rb_row * PAD + rb_c + 8]  = rb1;
        __syncthreads();
        if (step + 1 < 18) C2_LOAD(step + 1);
        #pragma unroll
        for (int ks = 0; ks < 64; ks += 32) {
            bf16x8 af[4], bw[2];
            #pragma unroll
            for (int i = 0; i < 4; ++i)
                af[i] = *(const bf16x8*)&As[(wm + i * 16 + fr) * PAD + ks + fk];
            #pragma unroll
            for (int j = 0; j < 2; ++j)
                bw[j] = *(const bf16x8*)&Bs[(wn + j * 16 + fr) * PAD + ks + fk];
            #pragma unroll
            for (int i = 0; i < 4; ++i)
                #pragma unroll
                for (int j = 0; j < 2; ++j)
                    acc[i][j] = __builtin_amdgcn_mfma_f32_16x16x32_bf16(af[i], bw[j], acc[i][j], 0, 0, 0);
        }
    }
    int rbase = (lane >> 4) * 4, cc = lane & 15;
    #pragma unroll
    for (int j = 0; j < 2; ++j) {
        int n = n0 + wn + j * 16 + cc;
        float scl = g[n] * BN_RSQ, shf = bb[n], bv2 = cb[n];
        #pragma unroll
        for (int i = 0; i < 4; ++i) {
            #pragma unroll
            for (int r = 0; r < 4; ++r) {
                int m = m0 + wm + i * 16 + rbase + r;
                float v = gelu_f((acc[i][j][r] + bv2) * scl + shf);
                h2b[(size_t)m * 256 + n] = f2bf(v);
            }
        }
    }
}

// Apb[m][s*256+ic] = h2b[b, 2oy+ky, 2ox+kx, ic]
__global__ void im2col_bf16(const ushort* __restrict__ h2b, ushort* __restrict__ Apb)
{
    int idx = blockIdx.x * 256 + threadIdx.x;          // 524288 uint4 chunks
    int k8 = idx & 127;
    int m = idx >> 7;
    int b = m >> 10, oy = (m >> 5) & 31, ox = m & 31;
    int s = k8 >> 5, ic8 = k8 & 31;
    int ky = s >> 1, kx = s & 1;
    uint4 v = *(const uint4*)(h2b + ((size_t)(b * 4096 + (2 * oy + ky) * 64 + 2 * ox + kx)) * 256 + ic8 * 8);
    *(uint4*)(Apb + (size_t)m * 1024 + k8 * 8) = v;
}

// ---------------------------------------------------------------------------
// fp32 tiled GEMM (reg dbuf): C[m*ldc+n] = act(A @ W^T + bias). act 0/2.
// (used for head FC only now)
// ---------------------------------------------------------------------------
template<int BM, int BN, int BK, int TM, int TN>
__global__ __launch_bounds__(256) void gemm_kernel(
    const float* __restrict__ A, int lda,
    const float* __restrict__ W, int ldw,
    const float* __restrict__ bias,
    float* __restrict__ C, int ldc,
    int M, int N, int K, int act)
{
    static_assert(BM * BK / 4 == 256 && BN * BK / 4 == 256, "staging shape");
    __shared__ float As[BK][BM + 4];
    __shared__ float Bs[BK][BN + 4];
    int t = threadIdx.x;
    int m0 = blockIdx.x * BM, n0 = blockIdx.y * BN;
    float acc[TM][TN];
    #pragma unroll
    for (int i = 0; i < TM; i++)
        #pragma unroll
        for (int j = 0; j < TN; j++) acc[i][j] = 0.f;
    const int LPR = BK / 4;
    int lr = t / LPR, lc4 = (t % LPR) * 4;
    int ty = t >> 4, tx = t & 15;
    int ma = m0 + lr, nb = n0 + lr;
    float4 va = make_float4(0.f, 0.f, 0.f, 0.f);
    float4 vb = make_float4(0.f, 0.f, 0.f, 0.f);
    if (ma < M) va = *(const float4*)(A + (size_t)ma * lda + lc4);
    if (nb < N) vb = *(const float4*)(W + (size_t)nb * ldw + lc4);
    for (int k0 = 0; k0 < K; k0 += BK) {
        __syncthreads();
        As[lc4 + 0][lr] = va.x; As[lc4 + 1][lr] = va.y;
        As[lc4 + 2][lr] = va.z; As[lc4 + 3][lr] = va.w;
        Bs[lc4 + 0][lr] = vb.x; Bs[lc4 + 1][lr] = vb.y;
        Bs[lc4 + 2][lr] = vb.z; Bs[lc4 + 3][lr] = vb.w;
        __syncthreads();
        if (k0 + BK < K) {
            if (ma < M) va = *(const float4*)(A + (size_t)ma * lda + k0 + BK + lc4);
            if (nb < N) vb = *(const float4*)(W + (size_t)nb * ldw + k0 + BK + lc4);
        }
        #pragma unroll
        for (int kk = 0; kk < BK; ++kk) {
            float a[TM], bfr[TN];
            #pragma unroll
            for (int i = 0; i < TM; i += 4)
                *(float4*)&a[i] = *(const float4*)&As[kk][ty * TM + i];
            #pragma unroll
            for (int j = 0; j < TN; j += 4)
                *(float4*)&bfr[j] = *(const float4*)&Bs[kk][tx * TN + j];
            #pragma unroll
            for (int i = 0; i < TM; i++)
                #pragma unroll
                for (int j = 0; j < TN; j++) acc[i][j] = fmaf(a[i], bfr[j], acc[i][j]);
        }
    }
    #pragma unroll
    for (int i = 0; i < TM; i++) {
        int m = m0 + ty * TM + i;
        if (m >= M) continue;
        #pragma unroll
        for (int j = 0; j < TN; j++) {
            int n = n0 + tx * TN + j;
            if (n >= N) continue;
            float v = acc[i][j];
            if (bias) v += bias[n];
            if (act == 2) v = softplus_f(v);
            C[(size_t)m * ldc + n] = v;
        }
    }
}

// ---------------------------------------------------------------------------
// Depthwise conv1d (K=4, pad(1,2)) in [b,l,d], bf16 in -> bf16 out (xlb == u).
// ---------------------------------------------------------------------------
__global__ __launch_bounds__(256) void dwconv(
    const ushort* __restrict__ xib, const float* __restrict__ cw,
    const float* __restrict__ cb, ushort* __restrict__ xlb)
{
    int idx = blockIdx.x * 256 + threadIdx.x;   // 524288
    int d4 = (idx & 127) * 4;
    int bl = idx >> 7;
    int b = bl >> 10, l = bl & 1023;
    float4 w0 = *(const float4*)(cw + d4 * 4);
    float4 w1 = *(const float4*)(cw + d4 * 4 + 4);
    float4 w2 = *(const float4*)(cw + d4 * 4 + 8);
    float4 w3 = *(const float4*)(cw + d4 * 4 + 12);
    float4 acc = *(const float4*)(cb + d4);
    const ushort* rowb = xib + ((size_t)b << 19) + d4;
    #pragma unroll
    for (int k = 0; k < 4; ++k) {
        int ll = l + k - 1;
        if ((unsigned)ll < 1024u) {
            uint2 p = *(const uint2*)(rowb + (size_t)ll * 512);
            acc.x = fmaf(bf2f((ushort)(p.x & 0xffffu)), ((const float*)&w0)[k], acc.x);
            acc.y = fmaf(bf2f((ushort)(p.x >> 16)),     ((const float*)&w1)[k], acc.y);
            acc.z = fmaf(bf2f((ushort)(p.y & 0xffffu)), ((const float*)&w2)[k], acc.z);
            acc.w = fmaf(bf2f((ushort)(p.y >> 16)),     ((const float*)&w3)[k], acc.w);
        }
    }
    uint2 pk;
    pk.x = (uint)f2bf(acc.x) | ((uint)f2bf(acc.y) << 16);
    pk.y = (uint)f2bf(acc.z) | ((uint)f2bf(acc.w) << 16);
    *(uint2*)(xlb + (size_t)bl * 512 + d4) = pk;
}

// ---------------------------------------------------------------------------
// Chunked scan pass 1 w/ fused dt_proj + 4-step composition.
// Block = (b, dgG, ch): 512 thr, 32 d. Critical path: 1 fma / 4 timesteps.
// ---------------------------------------------------------------------------
__global__ __launch_bounds__(512) void scan_part1(
    const float* __restrict__ xdbl, const ushort* __restrict__ xlb,
    const float* __restrict__ dpw, const float* __restrict__ dpb,
    const float* __restrict__ alog,
    float* __restrict__ Psum, float* __restrict__ hFsum)
{
    __shared__ float Td[32][132];
    __shared__ float Tu[32][132];
    __shared__ float TB[16][132];
    __shared__ float xd[128][32];
    __shared__ float dpw_s[32][33];
    __shared__ float dpb_s[32];
    int t = threadIdx.x;
    int bid = blockIdx.x;                 // 512 = b(4) x dgG(16) x ch(8)
    int ch = bid & 7, dgG = (bid >> 3) & 15, b = bid >> 7;
    int d0 = dgG * 32;
    int bl0 = b * 1024 + ch * 128;
    #pragma unroll
    for (int r = 0; r < 2; ++r) {
        int idx = r * 512 + t;
        int l = idx >> 3, k4 = (idx & 7) * 4;
        float4 v = *(const float4*)(xdbl + (size_t)(bl0 + l) * 64 + k4);
        *(float4*)&xd[l][k4] = v;
    }
    {
        int l = t >> 2, d8 = (t & 3) * 8;
        uint4 p = *(const uint4*)(xlb + (size_t)(bl0 + l) * 512 + d0 + d8);
        Tu[d8 + 0][l] = bf2f((ushort)(p.x & 0xffffu));
        Tu[d8 + 1][l] = bf2f((ushort)(p.x >> 16));
        Tu[d8 + 2][l] = bf2f((ushort)(p.y & 0xffffu));
        Tu[d8 + 3][l] = bf2f((ushort)(p.y >> 16));
        Tu[d8 + 4][l] = bf2f((ushort)(p.z & 0xffffu));
        Tu[d8 + 5][l] = bf2f((ushort)(p.z >> 16));
        Tu[d8 + 6][l] = bf2f((ushort)(p.w & 0xffffu));
        Tu[d8 + 7][l] = bf2f((ushort)(p.w >> 16));
    }
    {
        int l = t >> 2, n4 = (t & 3) * 4;
        float4 bv = *(const float4*)(xdbl + (size_t)(bl0 + l) * 64 + 32 + n4);
        TB[n4 + 0][l] = bv.x; TB[n4 + 1][l] = bv.y; TB[n4 + 2][l] = bv.z; TB[n4 + 3][l] = bv.w;
    }
    #pragma unroll
    for (int r = 0; r < 2; ++r) {
        int idx = r * 512 + t;
        int dd = idx >> 5, kk = idx & 31;
        dpw_s[dd][kk] = dpw[(size_t)(d0 + dd) * 32 + kk];
    }
    if (t < 32) dpb_s[t] = dpb[d0 + t];
    __syncthreads();
    {
        int dd = t & 31, lb = (t >> 5) * 8;
        #pragma unroll
        for (int j = 0; j < 8; ++j) {
            int l = lb + j;
            float s = dpb_s[dd];
            #pragma unroll
            for (int k = 0; k < 32; ++k) s = fmaf(xd[l][k], dpw_s[dd][k], s);
            Td[dd][l] = softplus_f(s);
        }
    }
    __syncthreads();
    int w = t >> 6, lane = t & 63;
    int dl = lane >> 4, n = lane & 15;
    int col = w * 4 + dl;
    int d = d0 + col;
    float Ac = -__expf(alog[d * 16 + n]);
    float h = 0.f, P = 1.f;
    for (int l4 = 0; l4 < 32; ++l4) {
        float4 de = *(const float4*)&Td[col][l4 * 4];
        float4 uu = *(const float4*)&Tu[col][l4 * 4];
        float4 Bv = *(const float4*)&TB[n][l4 * 4];
        float a1 = __expf(de.x * Ac), a2 = __expf(de.y * Ac);
        float a3 = __expf(de.z * Ac), a4 = __expf(de.w * Ac);
        float b1 = de.x * Bv.x * uu.x, b2 = de.y * Bv.y * uu.y;
        float b3 = de.z * Bv.z * uu.z, b4 = de.w * Bv.w * uu.w;
        float a21 = a2 * a1,     b21 = fmaf(a2, b1, b2);
        float a321 = a3 * a21,   b321 = fmaf(a3, b21, b3);
        float a4321 = a4 * a321, b4321 = fmaf(a4, b321, b4);
        h = fmaf(a4321, h, b4321);
        P *= a4321;
    }
    size_t si = ((size_t)(b * 128 + dgG * 8 + w) * 8 + ch) * 64 + lane;
    Psum[si] = P;
    hFsum[si] = h;
}

// ---------------------------------------------------------------------------
// Chunked scan pass 2 w/ fused dt_proj + 4-step composition: all four h's
// issue as parallel fmas off one h0; y + gate -> ybb bf16 in place over xlb.
// ---------------------------------------------------------------------------
__global__ __launch_bounds__(512) void scan_part2(
    const float* __restrict__ xdbl, const ushort* __restrict__ xlb,
    const float* __restrict__ dpw, const float* __restrict__ dpb,
    const float* __restrict__ alog, const float* __restrict__ dssm,
    const ushort* __restrict__ resb, ushort* __restrict__ ybb,
    const float* __restrict__ Psum, const float* __restrict__ hFsum)
{
    __shared__ float Td[32][132];
    __shared__ float Tu[32][132];
    __shared__ float TB[16][132];
    __shared__ float TC[16][132];
    __shared__ float yb[128][33];          // staging: xd[l][k] (k<32); later y
    __shared__ float dpw_s[32][33];
    __shared__ float dpb_s[32];
    int t = threadIdx.x;
    int bid = blockIdx.x;                 // 512 = b(4) x dgG(16) x ch(8)
    int ch = bid & 7, dgG = (bid >> 3) & 15, b = bid >> 7;
    int d0 = dgG * 32;
    int bl0 = b * 1024 + ch * 128;
    #pragma unroll
    for (int r = 0; r < 2; ++r) {
        int idx = r * 512 + t;
        int l = idx >> 3, k4 = (idx & 7) * 4;
        float4 v = *(const float4*)(xdbl + (size_t)(bl0 + l) * 64 + k4);
        *(float4*)&yb[l][k4] = v;
    }
    {
        int l = t >> 2, d8 = (t & 3) * 8;
        uint4 p = *(const uint4*)(xlb + (size_t)(bl0 + l) * 512 + d0 + d8);
        Tu[d8 + 0][l] = bf2f((ushort)(p.x & 0xffffu));
        Tu[d8 + 1][l] = bf2f((ushort)(p.x >> 16));
        Tu[d8 + 2][l] = bf2f((ushort)(p.y & 0xffffu));
        Tu[d8 + 3][l] = bf2f((ushort)(p.y >> 16));
        Tu[d8 + 4][l] = bf2f((ushort)(p.z & 0xffffu));
        Tu[d8 + 5][l] = bf2f((ushort)(p.z >> 16));
        Tu[d8 + 6][l] = bf2f((ushort)(p.w & 0xffffu));
        Tu[d8 + 7][l] = bf2f((ushort)(p.w >> 16));
    }
    {
        int l = t >> 2, n4 = (t & 3) * 4;
        float4 bv = *(const float4*)(xdbl + (size_t)(bl0 + l) * 64 + 32 + n4);
        float4 cv = *(const float4*)(xdbl + (size_t)(bl0 + l) * 64 + 48 + n4);
        TB[n4 + 0][l] = bv.x; TB[n4 + 1][l] = bv.y; TB[n4 + 2][l] = bv.z; TB[n4 + 3][l] = bv.w;
        TC[n4 + 0][l] = cv.x; TC[n4 + 1][l] = cv.y; TC[n4 + 2][l] = cv.z; TC[n4 + 3][l] = cv.w;
    }
    #pragma unroll
    for (int r = 0; r < 2; ++r) {
        int idx = r * 512 + t;
        int dd = idx >> 5, kk = idx & 31;
        dpw_s[dd][kk] = dpw[(size_t)(d0 + dd) * 32 + kk];
    }
    if (t < 32) dpb_s[t] = dpb[d0 + t];
    __syncthreads();
    {
        int dd = t & 31, lb = (t >> 5) * 8;
        #pragma unroll
        for (int j = 0; j < 8; ++j) {
            int l = lb + j;
            float s = dpb_s[dd];
            #pragma unroll
            for (int k = 0; k < 32; ++k) s = fmaf(yb[l][k], dpw_s[dd][k], s);
            Td[dd][l] = softplus_f(s);
        }
    }
    int w = t >> 6, lane = t & 63;
    int dl = lane >> 4, n = lane & 15;
    int col = w * 4 + dl;
    int d = d0 + col;
    float Ac = -__expf(alog[d * 16 + n]);
    float Dd = dssm[d];
    float h = 0.f;
    {
        size_t sbase = (size_t)(b * 128 + dgG * 8 + w) * 512 + lane;
        for (int cc = 0; cc < ch; ++cc) {
            float Pv = Psum[sbase + (size_t)cc * 64];
            float hv = hFsum[sbase + (size_t)cc * 64];
            h = Pv * h + hv;
        }
    }
    __syncthreads();        // Td ready; xd reads (in yb) done before yb writes
    for (int l4 = 0; l4 < 32; ++l4) {
        float4 de = *(const float4*)&Td[col][l4 * 4];
        float4 uu = *(const float4*)&Tu[col][l4 * 4];
        float4 Bv = *(const float4*)&TB[n][l4 * 4];
        float4 Cv = *(const float4*)&TC[n][l4 * 4];
        float a1 = __expf(de.x * Ac), a2 = __expf(de.y * Ac);
        float a3 = __expf(de.z * Ac), a4 = __expf(de.w * Ac);
        float b1 = de.x * Bv.x * uu.x, b2 = de.y * Bv.y * uu.y;
        float b3 = de.z * Bv.z * uu.z, b4 = de.w * Bv.w * uu.w;
        float a21 = a2 * a1,     b21 = fmaf(a2, b1, b2);
        float a321 = a3 * a21,   b321 = fmaf(a3, b21, b3);
        float a4321 = a4 * a321, b4321 = fmaf(a4, b321, b4);
        float h1 = fmaf(a1, h, b1);
        float h2 = fmaf(a21, h, b21);
        float h3 = fmaf(a321, h, b321);
        float h4 = fmaf(a4321, h, b4321);
        h = h4;
        float p0 = h1 * Cv.x, p1 = h2 * Cv.y, p2 = h3 * Cv.z, p3 = h4 * Cv.w;
        #pragma unroll
        for (int off = 1; off < 16; off <<= 1) {
            p0 += __shfl_xor(p0, off);
            p1 += __shfl_xor(p1, off);
            p2 += __shfl_xor(p2, off);
            p3 += __shfl_xor(p3, off);
        }
        if (n == 0) {
            int l = l4 * 4;
            yb[l + 0][col] = fmaf(uu.x, Dd, p0);
            yb[l + 1][col] = fmaf(uu.y, Dd, p1);
            yb[l + 2][col] = fmaf(uu.z, Dd, p2);
            yb[l + 3][col] = fmaf(uu.w, Dd, p3);
        }
    }
    __syncthreads();
    size_t base = ((size_t)(b * 1024 + ch * 128)) * 512 + d0;   // ushort offset
    const uint* rp32 = (const uint*)(resb + base);
    uint* yp32 = (uint*)(ybb + base);
    #pragma unroll
    for (int j = 0; j < 4; ++j) {
        int idx = j * 512 + t;
        int l = idx >> 4, du = idx & 15;
        float v0 = yb[l][du * 2 + 0];
        float v1 = yb[l][du * 2 + 1];
        uint rr = rp32[(size_t)l * 256 + du];
        float y0 = v0 * bf2f((ushort)(rr & 0xffffu));
        float y1 = v1 * bf2f((ushort)(rr >> 16));
        yp32[(size_t)l * 256 + du] = (uint)f2bf(y0) | ((uint)f2bf(y1) << 16);
    }
}

// s[row] = LN(o[row])*g + b + s[row]; also writes bf16 copy sb. One wave/row.
__global__ __launch_bounds__(256) void ln_res_kernel(
    const float* __restrict__ o, const float* __restrict__ g,
    const float* __restrict__ bb, float* __restrict__ s, ushort* __restrict__ sb)
{
    int row = blockIdx.x * 4 + (threadIdx.x >> 6);
    int lane = threadIdx.x & 63;
    const float4* orow = (const float4*)(o + (size_t)row * 256);
    float4 v = orow[lane];
    float sum = v.x + v.y + v.z + v.w;
    float sq = v.x * v.x + v.y * v.y + v.z * v.z + v.w * v.w;
    #pragma unroll
    for (int off = 1; off < 64; off <<= 1) {
        sum += __shfl_xor(sum, off);
        sq += __shfl_xor(sq, off);
    }
    float m = sum * (1.f / 256.f);
    float var = sq * (1.f / 256.f) - m * m;
    float rstd = rsqrtf(var + 1e-5f);
    float4 gg = ((const float4*)g)[lane];
    float4 bv = ((const float4*)bb)[lane];
    float4* srow = (float4*)(s + (size_t)row * 256);
    float4 sv = srow[lane];
    sv.x += (v.x - m) * rstd * gg.x + bv.x;
    sv.y += (v.y - m) * rstd * gg.y + bv.y;
    sv.z += (v.z - m) * rstd * gg.z + bv.z;
    sv.w += (v.w - m) * rstd * gg.w + bv.w;
    srow[lane] = sv;
    uint2 pk;
    pk.x = (uint)f2bf(sv.x) | ((uint)f2bf(sv.y) << 16);
    pk.y = (uint)f2bf(sv.z) | ((uint)f2bf(sv.w) << 16);
    *(uint2*)(sb + (size_t)row * 256 + lane * 4) = pk;
}

// mean over l then LN over 256 channels. grid 4 x 256.
__global__ __launch_bounds__(256) void pool_ln_kernel(
    const float* __restrict__ s, const float* __restrict__ nw,
    const float* __restrict__ nb, float* __restrict__ sln)
{
    int b = blockIdx.x, c = threadIdx.x;
    const float* p = s + (size_t)b * 262144 + c;
    float acc = 0.f;
    for (int l = 0; l < 1024; ++l) acc += p[(size_t)l * 256];
    float pooled = acc * (1.f / 1024.f);
    __shared__ float rs[4], rq[4];
    float sum = pooled, sq = pooled * pooled;
    #pragma unroll
    for (int off = 1; off < 64; off <<= 1) {
        sum += __shfl_xor(sum, off);
        sq += __shfl_xor(sq, off);
    }
    int w = threadIdx.x >> 6;
    if ((threadIdx.x & 63) == 0) { rs[w] = sum; rq[w] = sq; }
    __syncthreads();
    sum = rs[0] + rs[1] + rs[2] + rs[3];
    sq = rq[0] + rq[1] + rq[2] + rq[3];
    float m = sum * (1.f / 256.f);
    float var = sq * (1.f / 256.f) - m * m;
    float rstd = rsqrtf(var + 1e-5f);
    sln[b * 256 + c] = (pooled - m) * rstd * nw[c] + nb[c];
}

// softmax over 1000 logits per b
__global__ __launch_bounds__(256) void softmax_kernel(float* __restrict__ out)
{
    int b = threadIdx.x >> 6, lane = threadIdx.x & 63;
    const float* lg = out + b * 1000;
    float v[16];
    float mx = -1e30f;
    #pragma unroll
    for (int j = 0; j < 16; ++j) {
        int i = lane + j * 64;
        v[j] = (i < 1000) ? lg[i] : -1e30f;
        mx = fmaxf(mx, v[j]);
    }
    #pragma unroll
    for (int off = 1; off < 64; off <<= 1) mx = fmaxf(mx, __shfl_xor(mx, off));
    float sum = 0.f;
    #pragma unroll
    for (int j = 0; j < 16; ++j) {
        int i = lane + j * 64;
        if (i < 1000) { v[j] = __expf(v[j] - mx); sum += v[j]; }
    }
    #pragma unroll
    for (int off = 1; off < 64; off <<= 1) sum += __shfl_xor(sum, off);
    float inv = 1.f / sum;
    float* so = out + 4000 + b * 1000;
    #pragma unroll
    for (int j = 0; j < 16; ++j) {
        int i = lane + j * 64;
        if (i < 1000) so[i] = v[j] * inv;
    }
}

// ---------------------------------------------------------------------------
extern "C" void kernel_launch(void* const* d_in, const int* in_sizes, int n_in,
                              void* d_out, int out_size, void* d_ws, size_t ws_size,
                              hipStream_t stream)
{
    const float* x    = (const float*)d_in[0];
    const float* c1w  = (const float*)d_in[1];
    const float* c1b  = (const float*)d_in[2];
    const float* g1   = (const float*)d_in[3];
    const float* b1   = (const float*)d_in[4];
    const float* c2w  = (const float*)d_in[5];
    const float* c2b  = (const float*)d_in[6];
    const float* g2   = (const float*)d_in[7];
    const float* b2   = (const float*)d_in[8];
    const float* pw   = (const float*)d_in[9];
    const float* pb   = (const float*)d_in[10];
    const float* g3   = (const float*)d_in[11];
    const float* b3   = (const float*)d_in[12];
    const float* ipw  = (const float*)d_in[13];
    const float* ipb  = (const float*)d_in[14];
    const float* cw   = (const float*)d_in[15];
    const float* cb   = (const float*)d_in[16];
    const float* xpw  = (const float*)d_in[17];
    const float* dpw  = (const float*)d_in[18];
    const float* dpb  = (const float*)d_in[19];
    const float* alog = (const float*)d_in[20];
    const float* dssm = (const float*)d_in[21];
    const float* opw  = (const float*)d_in[22];
    const float* opb  = (const float*)d_in[23];
    const float* lnw  = (const float*)d_in[24];
    const float* lnb  = (const float*)d_in[25];
    const float* nw   = (const float*)d_in[26];
    const float* nb   = (const float*)d_in[27];
    const float* fcw  = (const float*)d_in[28];
    const float* fcb  = (const float*)d_in[29];
    float* out = (float*)d_out;
    float* wsf = (float*)d_ws;

    float*  s_   = wsf;
    ushort* sb   = (ushort*)(wsf + 1048576);
    ushort* xib  = (ushort*)(wsf + 1572864);
    ushort* h2b  = (ushort*)(wsf + 1572864);
    float*  obuf = wsf + 1572864;
    ushort* resb = (ushort*)(wsf + 3670016);
    ushort* xlb  = (ushort*)(wsf + 4718592);   // == u == ybb (in-place gate)
    ushort* ybb  = (ushort*)(wsf + 4718592);
    ushort* h1b  = (ushort*)(wsf + 4718592);
    ushort* Apb  = (ushort*)(wsf + 6815744);
    float*  xdbl = wsf + 8912896;
    ushort* ipwb = (ushort*)(wsf + 9175040);
    ushort* opwb = (ushort*)(wsf + 9699328);
    ushort* w2b  = (ushort*)(wsf + 9961472);
    ushort* pwTb = (ushort*)(wsf + 10108928);
    float*  sln  = wsf + 10240000;
    float*  Psum = wsf + 10241024;
    float*  hFsum= wsf + 10503168;
    ushort* xpwb = (ushort*)(wsf + 10765312);

    // --- fused weight prep (1 dispatch) ---
    hipLaunchKernelGGL(wprep, dim3(8832), dim3(256), 0, stream,
                       ipw, opw, c2w, pw, xpw, ipwb, opwb, w2b, pwTb, xpwb);

    // --- conv stem ---
    hipLaunchKernelGGL(conv1_nhwc, dim3(256), dim3(256), 0, stream, x, c1w, c1b, g1, b1, h1b);
    hipLaunchKernelGGL(conv2_mfma, dim3(128, 4), dim3(256), 0, stream, h1b, w2b, c2b, g2, b2, h2b);
    hipLaunchKernelGGL(im2col_bf16, dim3(2048), dim3(256), 0, stream, h2b, Apb);
    hipLaunchKernelGGL((mfma_gemm_bt<64, 64, 2>), dim3(64, 4), dim3(256), 0, stream,
                       Apb, 1024, pwTb, 1024, pb, g3, b3, s_, sb, nullptr, 256, 1024);

    // --- mamba blocks ---
    for (int i = 0; i < 4; ++i) {
        const ushort* ipwb_i = ipwb + (size_t)i * 1024 * 256;
        const float*  ipb_i  = ipb + i * 1024;
        const float*  cw_i   = cw + i * 512 * 4;
        const float*  cb_i   = cb + i * 512;
        const ushort* xpwb_i = xpwb + (size_t)i * 64 * 512;
        const float*  dpw_i  = dpw + (size_t)i * 512 * 32;
        const float*  dpb_i  = dpb + i * 512;
        const float*  alog_i = alog + (size_t)i * 512 * 16;
        const float*  dssm_i = dssm + i * 512;
        const ushort* opwb_i = opwb + (size_t)i * 256 * 512;
        const float*  opb_i  = opb + i * 256;
        const float*  lnw_i  = lnw + i * 256;
        const float*  lnb_i  = lnb + i * 256;

        // in_proj (bf16 MFMA): xib bf16 + silu(res) bf16
        hipLaunchKernelGGL((mfma_gemm_bt<64, 128, 3>), dim3(64, 8), dim3(256), 0, stream,
                           sb, 256, ipwb_i, 256, ipb_i, nullptr, nullptr,
                           nullptr, xib, resb, 0, 256);
        // dwconv -> xlb bf16 (== u)
        hipLaunchKernelGGL(dwconv, dim3(2048), dim3(256), 0, stream, xib, cw_i, cb_i, xlb);
        // x_proj (bf16 MFMA) -> xdbl fp32 [m,64]
        hipLaunchKernelGGL((mfma_gemm_bt<64, 64, 0>), dim3(64, 1), dim3(256), 0, stream,
                           xlb, 512, xpwb_i, 512, nullptr, nullptr, nullptr,
                           xdbl, nullptr, nullptr, 64, 512);
        // chunked scan (dt_proj fused, in-place gate into ybb == xlb)
        hipLaunchKernelGGL(scan_part1, dim3(512), dim3(512), 0, stream,
                           xdbl, xlb, dpw_i, dpb_i, alog_i, Psum, hFsum);
        hipLaunchKernelGGL(scan_part2, dim3(512), dim3(512), 0, stream,
                           xdbl, xlb, dpw_i, dpb_i, alog_i, dssm_i, resb, ybb, Psum, hFsum);
        // out_proj (bf16 MFMA) -> obuf fp32
        hipLaunchKernelGGL((mfma_gemm_bt<64, 64, 0>), dim3(64, 4), dim3(256), 0, stream,
                           ybb, 512, opwb_i, 512, opb_i, nullptr, nullptr,
                           obuf, nullptr, nullptr, 256, 512);
        hipLaunchKernelGGL(ln_res_kernel, dim3(1024), dim3(256), 0, stream,
                           obuf, lnw_i, lnb_i, s_, sb);
    }

    // --- head ---
    hipLaunchKernelGGL(pool_ln_kernel, dim3(4), dim3(256), 0, stream, s_, nw, nb, sln);
    hipLaunchKernelGGL((gemm_kernel<64, 64, 16, 4, 4>), dim3(1, 16), dim3(256), 0, stream,
                       sln, 256, fcw, 256, fcb, out, 1000, 4, 1000, 256, 0);
    hipLaunchKernelGGL(softmax_kernel, dim3(1), dim3(256), 0, stream, out);
}

// Round 14
// 653.957 us; speedup vs baseline: 1.1241x; 1.0016x over previous
//
#include <hip/hip_runtime.h>
#include <math.h>

// ---------------------------------------------------------------------------
// FastImageMamba forward. R14: R13 + scan LDS shrink for 3 blocks/CU
// (Tu/TB/TC staged bf16, yb packed bf16 pairs, xd overlaid on TB/TC/yb union).
// B=4, DM=256, NL=4, NC=1000, DI=512, NS=16, DTR=32, K=4, L=1024, H=W=64
// ---------------------------------------------------------------------------

#define BN_RSQ 0.99999500003749969f   // 1/sqrt(1+1e-5)

typedef unsigned int uint;
typedef unsigned short ushort;
typedef __bf16 bf16x8 __attribute__((ext_vector_type(8)));
typedef float floatx4 __attribute__((ext_vector_type(4)));

__device__ __forceinline__ float gelu_f(float v) {
    return 0.5f * v * (1.0f + erff(v * 0.70710678118654752f));
}
__device__ __forceinline__ float softplus_f(float v) {
    return (v > 20.f) ? v : log1pf(expf(v));
}
__device__ __forceinline__ ushort f2bf(float f) {
    uint x = __float_as_uint(f);
    x += 0x7fffu + ((x >> 16) & 1u);
    return (ushort)(x >> 16);
}
__device__ __forceinline__ float bf2f(ushort u) {
    return __uint_as_float((uint)u << 16);
}

// ---------------------------------------------------------------------------
// Fused weight prep: all fp32->bf16 weight conversions in one dispatch.
// ---------------------------------------------------------------------------
__global__ void wprep(const float* __restrict__ ipw, const float* __restrict__ opw,
                      const float* __restrict__ c2w, const float* __restrict__ pw,
                      const float* __restrict__ xpw,
                      ushort* __restrict__ ipwb, ushort* __restrict__ opwb,
                      ushort* __restrict__ w2b, ushort* __restrict__ pwTb,
                      ushort* __restrict__ xpwb)
{
    int idx = blockIdx.x * 256 + threadIdx.x;
    if (idx < 1048576) {
        ipwb[idx] = f2bf(ipw[idx]);
    } else if (idx < 1572864) {
        int i = idx - 1048576;
        opwb[i] = f2bf(opw[i]);
    } else if (idx < 1867776) {
        int i = idx - 1572864;
        int oc = i / 1152, k = i % 1152;
        int s = k >> 7, ic = k & 127;
        w2b[i] = f2bf(c2w[(size_t)(oc * 128 + ic) * 9 + s]);
    } else if (idx < 2129920) {
        int i = idx - 1867776;
        int oc = i >> 10, k = i & 1023;
        int s = k >> 8, ic = k & 255;
        int ky = s >> 1, kx = s & 1;
        pwTb[i] = f2bf(pw[((size_t)(oc * 256 + ic) * 2 + ky) * 2 + kx]);
    } else if (idx < 2260992) {
        int i = idx - 2129920;
        xpwb[i] = f2bf(xpw[i]);
    }
}

// ---------------------------------------------------------------------------
// conv1: 3x3 s1p1, IC=3 -> OC=128, NCHW fp32 in, NHWC bf16 out (+bias+BN+GELU)
// ---------------------------------------------------------------------------
__global__ __launch_bounds__(256) void conv1_nhwc(
    const float* __restrict__ x, const float* __restrict__ w,
    const float* __restrict__ cb, const float* __restrict__ g,
    const float* __restrict__ bb, ushort* __restrict__ out)
{
    __shared__ float tin[3][3][64];
    __shared__ float ws[3456];
    int t = threadIdx.x;
    int b = blockIdx.x >> 6, y = blockIdx.x & 63;
    for (int i = t; i < 3456; i += 256) ws[i] = w[i];
    for (int i = t; i < 576; i += 256) {
        int ic = i / 192, r = (i >> 6) % 3, xx = i & 63;
        int gy = y + r - 1;
        tin[ic][r][xx] = ((unsigned)gy < 64u) ? x[((b * 3 + ic) * 64 + gy) * 64 + xx] : 0.f;
    }
    __syncthreads();
    int tx = t & 15, ty = t >> 4;
    int oc0 = tx * 8, px0 = ty * 4;
    float acc[4][8];
    #pragma unroll
    for (int p = 0; p < 4; ++p)
        #pragma unroll
        for (int o = 0; o < 8; ++o) acc[p][o] = 0.f;
    for (int ic = 0; ic < 3; ++ic)
        #pragma unroll
        for (int ky = 0; ky < 3; ++ky)
            #pragma unroll
            for (int kx = 0; kx < 3; ++kx) {
                float av[4];
                #pragma unroll
                for (int p = 0; p < 4; ++p) {
                    int xx = px0 + p + kx - 1;
                    av[p] = ((unsigned)xx < 64u) ? tin[ic][ky][xx] : 0.f;
                }
                #pragma unroll
                for (int o = 0; o < 8; ++o) {
                    float wv = ws[(oc0 + o) * 27 + ic * 9 + ky * 3 + kx];
                    #pragma unroll
                    for (int p = 0; p < 4; ++p) acc[p][o] = fmaf(av[p], wv, acc[p][o]);
                }
            }
    #pragma unroll
    for (int p = 0; p < 4; ++p) {
        uint pk[4];
        #pragma unroll
        for (int o2 = 0; o2 < 4; ++o2) {
            int oc = oc0 + o2 * 2;
            float v0 = gelu_f((acc[p][o2 * 2] + cb[oc]) * (g[oc] * BN_RSQ) + bb[oc]);
            float v1 = gelu_f((acc[p][o2 * 2 + 1] + cb[oc + 1]) * (g[oc + 1] * BN_RSQ) + bb[oc + 1]);
            pk[o2] = (uint)f2bf(v0) | ((uint)f2bf(v1) << 16);
        }
        uint4 vv = make_uint4(pk[0], pk[1], pk[2], pk[3]);
        *(uint4*)(out + ((size_t)((b * 64 + y) * 64 + px0 + p)) * 128 + oc0) = vv;
    }
}

// ---------------------------------------------------------------------------
// bf16 MFMA GEMM (A @ W^T), BMxBN tile, BK=32, 4 waves (2x2), reg dbuf.
// EPI: 0 = +bias -> fp32 Cf[ldc]
//      2 = +bias,BN,GELU -> fp32 Cf + bf16 Cb (same ldc)
//      3 = in_proj: n<512 -> bf16 Cb[m*512+n]; n>=512 -> bf16 silu -> Cb2
// ---------------------------------------------------------------------------
template<int BM, int BN, int EPI>
__global__ __launch_bounds__(256, 2) void mfma_gemm_bt(
    const ushort* __restrict__ A, int lda,
    const ushort* __restrict__ W, int ldw,
    const float* __restrict__ bias,
    const float* __restrict__ bnG, const float* __restrict__ bnB,
    float* __restrict__ Cf, ushort* __restrict__ Cb, ushort* __restrict__ Cb2,
    int ldc, int K)
{
    constexpr int PAD = 40;
    constexpr int AP = BM / 64;
    constexpr int BP = BN / 64;
    constexpr int FM = BM / 32;
    constexpr int FN = BN / 32;
    __shared__ __align__(16) ushort As[BM * PAD];
    __shared__ __align__(16) ushort Bs[BN * PAD];
    int t = threadIdx.x;
    int m0 = blockIdx.x * BM, n0 = blockIdx.y * BN;
    int lane = t & 63, wid = t >> 6;
    int wm = (wid & 1) * (BM / 2), wn = (wid >> 1) * (BN / 2);
    int fr = lane & 15, fk = (lane >> 4) * 8;
    int r0 = t >> 2, c0 = (t & 3) * 8;
    floatx4 acc[FM][FN];
    #pragma unroll
    for (int i = 0; i < FM; ++i)
        #pragma unroll
        for (int j = 0; j < FN; ++j) acc[i][j] = {0.f, 0.f, 0.f, 0.f};
    uint4 ra[AP], rb[BP];
    #pragma unroll
    for (int p = 0; p < AP; ++p)
        ra[p] = *(const uint4*)(A + (size_t)(m0 + r0 + p * 64) * lda + c0);
    #pragma unroll
    for (int p = 0; p < BP; ++p)
        rb[p] = *(const uint4*)(W + (size_t)(n0 + r0 + p * 64) * ldw + c0);
    for (int k0 = 0; k0 < K; k0 += 32) {
        __syncthreads();
        #pragma unroll
        for (int p = 0; p < AP; ++p) *(uint4*)&As[(r0 + p * 64) * PAD + c0] = ra[p];
        #pragma unroll
        for (int p = 0; p < BP; ++p) *(uint4*)&Bs[(r0 + p * 64) * PAD + c0] = rb[p];
        __syncthreads();
        if (k0 + 32 < K) {
            #pragma unroll
            for (int p = 0; p < AP; ++p)
                ra[p] = *(const uint4*)(A + (size_t)(m0 + r0 + p * 64) * lda + k0 + 32 + c0);
            #pragma unroll
            for (int p = 0; p < BP; ++p)
                rb[p] = *(const uint4*)(W + (size_t)(n0 + r0 + p * 64) * ldw + k0 + 32 + c0);
        }
        bf16x8 af[FM], bw[FN];
        #pragma unroll
        for (int i = 0; i < FM; ++i)
            af[i] = *(const bf16x8*)&As[(wm + i * 16 + fr) * PAD + fk];
        #pragma unroll
        for (int j = 0; j < FN; ++j)
            bw[j] = *(const bf16x8*)&Bs[(wn + j * 16 + fr) * PAD + fk];
        #pragma unroll
        for (int i = 0; i < FM; ++i)
            #pragma unroll
            for (int j = 0; j < FN; ++j)
                acc[i][j] = __builtin_amdgcn_mfma_f32_16x16x32_bf16(af[i], bw[j], acc[i][j], 0, 0, 0);
    }
    int rbase = (lane >> 4) * 4, cc = lane & 15;
    #pragma unroll
    for (int j = 0; j < FN; ++j) {
        int n = n0 + wn + j * 16 + cc;
        float bv = bias ? bias[n] : 0.f;
        float scl = 0.f, shf = 0.f;
        if (EPI == 2) { scl = bnG[n] * BN_RSQ; shf = bnB[n]; }
        #pragma unroll
        for (int i = 0; i < FM; ++i) {
            #pragma unroll
            for (int r = 0; r < 4; ++r) {
                int m = m0 + wm + i * 16 + rbase + r;
                float v = acc[i][j][r] + bv;
                if (EPI == 2) v = gelu_f(v * scl + shf);
                if (EPI == 0) {
                    Cf[(size_t)m * ldc + n] = v;
                } else if (EPI == 2) {
                    Cf[(size_t)m * ldc + n] = v;
                    Cb[(size_t)m * ldc + n] = f2bf(v);
                } else {
                    if (n < 512) Cb[(size_t)m * 512 + n] = f2bf(v);
                    else Cb2[(size_t)m * 512 + (n - 512)] = f2bf(v / (1.f + __expf(-v)));
                }
            }
        }
    }
}

// ---------------------------------------------------------------------------
// conv2: 9-shift implicit MFMA GEMM, 128px x 64oc tile, BK=64 (18 steps),
// reg dbuf with EXPLICIT SCALAR uint4s (array-by-ref spills to scratch).
// ---------------------------------------------------------------------------
#define C2_LOAD(step)                                                            \
    {                                                                            \
        int s_ = (step) >> 1, ich_ = ((step) & 1) * 64;                          \
        int ky_ = s_ / 3, kx_ = s_ % 3;                                          \
        int sy_ = y0 + (ra_row >> 6) + ky_ - 1;                                  \
        int sx_ = (ra_row & 63) + kx_ - 1;                                       \
        bool v_ = ((unsigned)sy_ < 64u) && ((unsigned)sx_ < 64u);                \
        const ushort* ap_ = hb + ((size_t)(sy_ * 64 + sx_)) * 128 + ich_ + ra_c; \
        uint4 zz_ = make_uint4(0u, 0u, 0u, 0u);                                  \
        ra0 = v_ ? *(const uint4*)(ap_ + 0)  : zz_;                              \
        ra1 = v_ ? *(const uint4*)(ap_ + 8)  : zz_;                              \
        ra2 = v_ ? *(const uint4*)(ap_ + 16) : zz_;                              \
        ra3 = v_ ? *(const uint4*)(ap_ + 24) : zz_;                              \
        const ushort* wp_ = w2b + (size_t)(n0 + rb_row) * 1152 + s_ * 128 + ich_ + rb_c; \
        rb0 = *(const uint4*)(wp_ + 0);                                          \
        rb1 = *(const uint4*)(wp_ + 8);                                          \
    }

__global__ __launch_bounds__(256, 2) void conv2_mfma(
    const ushort* __restrict__ h1b, const ushort* __restrict__ w2b,
    const float* __restrict__ cb, const float* __restrict__ g,
    const float* __restrict__ bb, ushort* __restrict__ h2b)
{
    constexpr int PAD = 72;
    __shared__ __align__(16) ushort As[128 * PAD];
    __shared__ __align__(16) ushort Bs[64 * PAD];
    int t = threadIdx.x;
    int m0 = blockIdx.x * 128, n0 = blockIdx.y * 64;
    int b = m0 >> 12;
    int y0 = (m0 & 4095) >> 6;
    int lane = t & 63, wid = t >> 6;
    int wm = (wid & 1) * 64, wn = (wid >> 1) * 32;
    int fr = lane & 15, fk = (lane >> 4) * 8;
    int ra_row = t >> 1, ra_c = (t & 1) * 32;
    int rb_row = t >> 2, rb_c = (t & 3) * 16;
    floatx4 acc[4][2];
    #pragma unroll
    for (int i = 0; i < 4; ++i)
        #pragma unroll
        for (int j = 0; j < 2; ++j) acc[i][j] = {0.f, 0.f, 0.f, 0.f};
    const ushort* hb = h1b + (size_t)b * 4096 * 128;

    uint4 ra0, ra1, ra2, ra3, rb0, rb1;
    C2_LOAD(0);
    for (int step = 0; step < 18; ++step) {
        __syncthreads();
        *(uint4*)&As[ra_row * PAD + ra_c + 0]  = ra0;
        *(uint4*)&As[ra_row * PAD + ra_c + 8]  = ra1;
        *(uint4*)&As[ra_row * PAD + ra_c + 16] = ra2;
        *(uint4*)&As[ra_row * PAD + ra_c + 24] = ra3;
        *(uint4*)&Bs[rb_row * PAD + rb_c + 0]  = rb0;
        *(uint4*)&Bs[rb_row * PAD + rb_c + 8]  = rb1;
        __syncthreads();
        if (step + 1 < 18) C2_LOAD(step + 1);
        #pragma unroll
        for (int ks = 0; ks < 64; ks += 32) {
            bf16x8 af[4], bw[2];
            #pragma unroll
            for (int i = 0; i < 4; ++i)
                af[i] = *(const bf16x8*)&As[(wm + i * 16 + fr) * PAD + ks + fk];
            #pragma unroll
            for (int j = 0; j < 2; ++j)
                bw[j] = *(const bf16x8*)&Bs[(wn + j * 16 + fr) * PAD + ks + fk];
            #pragma unroll
            for (int i = 0; i < 4; ++i)
                #pragma unroll
                for (int j = 0; j < 2; ++j)
                    acc[i][j] = __builtin_amdgcn_mfma_f32_16x16x32_bf16(af[i], bw[j], acc[i][j], 0, 0, 0);
        }
    }
    int rbase = (lane >> 4) * 4, cc = lane & 15;
    #pragma unroll
    for (int j = 0; j < 2; ++j) {
        int n = n0 + wn + j * 16 + cc;
        float scl = g[n] * BN_RSQ, shf = bb[n], bv2 = cb[n];
        #pragma unroll
        for (int i = 0; i < 4; ++i) {
            #pragma unroll
            for (int r = 0; r < 4; ++r) {
                int m = m0 + wm + i * 16 + rbase + r;
                float v = gelu_f((acc[i][j][r] + bv2) * scl + shf);
                h2b[(size_t)m * 256 + n] = f2bf(v);
            }
        }
    }
}

// Apb[m][s*256+ic] = h2b[b, 2oy+ky, 2ox+kx, ic]
__global__ void im2col_bf16(const ushort* __restrict__ h2b, ushort* __restrict__ Apb)
{
    int idx = blockIdx.x * 256 + threadIdx.x;          // 524288 uint4 chunks
    int k8 = idx & 127;
    int m = idx >> 7;
    int b = m >> 10, oy = (m >> 5) & 31, ox = m & 31;
    int s = k8 >> 5, ic8 = k8 & 31;
    int ky = s >> 1, kx = s & 1;
    uint4 v = *(const uint4*)(h2b + ((size_t)(b * 4096 + (2 * oy + ky) * 64 + 2 * ox + kx)) * 256 + ic8 * 8);
    *(uint4*)(Apb + (size_t)m * 1024 + k8 * 8) = v;
}

// ---------------------------------------------------------------------------
// fp32 tiled GEMM (reg dbuf): head FC only.
// ---------------------------------------------------------------------------
template<int BM, int BN, int BK, int TM, int TN>
__global__ __launch_bounds__(256) void gemm_kernel(
    const float* __restrict__ A, int lda,
    const float* __restrict__ W, int ldw,
    const float* __restrict__ bias,
    float* __restrict__ C, int ldc,
    int M, int N, int K, int act)
{
    static_assert(BM * BK / 4 == 256 && BN * BK / 4 == 256, "staging shape");
    __shared__ float As[BK][BM + 4];
    __shared__ float Bs[BK][BN + 4];
    int t = threadIdx.x;
    int m0 = blockIdx.x * BM, n0 = blockIdx.y * BN;
    float acc[TM][TN];
    #pragma unroll
    for (int i = 0; i < TM; i++)
        #pragma unroll
        for (int j = 0; j < TN; j++) acc[i][j] = 0.f;
    const int LPR = BK / 4;
    int lr = t / LPR, lc4 = (t % LPR) * 4;
    int ty = t >> 4, tx = t & 15;
    int ma = m0 + lr, nb = n0 + lr;
    float4 va = make_float4(0.f, 0.f, 0.f, 0.f);
    float4 vb = make_float4(0.f, 0.f, 0.f, 0.f);
    if (ma < M) va = *(const float4*)(A + (size_t)ma * lda + lc4);
    if (nb < N) vb = *(const float4*)(W + (size_t)nb * ldw + lc4);
    for (int k0 = 0; k0 < K; k0 += BK) {
        __syncthreads();
        As[lc4 + 0][lr] = va.x; As[lc4 + 1][lr] = va.y;
        As[lc4 + 2][lr] = va.z; As[lc4 + 3][lr] = va.w;
        Bs[lc4 + 0][lr] = vb.x; Bs[lc4 + 1][lr] = vb.y;
        Bs[lc4 + 2][lr] = vb.z; Bs[lc4 + 3][lr] = vb.w;
        __syncthreads();
        if (k0 + BK < K) {
            if (ma < M) va = *(const float4*)(A + (size_t)ma * lda + k0 + BK + lc4);
            if (nb < N) vb = *(const float4*)(W + (size_t)nb * ldw + k0 + BK + lc4);
        }
        #pragma unroll
        for (int kk = 0; kk < BK; ++kk) {
            float a[TM], bfr[TN];
            #pragma unroll
            for (int i = 0; i < TM; i += 4)
                *(float4*)&a[i] = *(const float4*)&As[kk][ty * TM + i];
            #pragma unroll
            for (int j = 0; j < TN; j += 4)
                *(float4*)&bfr[j] = *(const float4*)&Bs[kk][tx * TN + j];
            #pragma unroll
            for (int i = 0; i < TM; i++)
                #pragma unroll
                for (int j = 0; j < TN; j++) acc[i][j] = fmaf(a[i], bfr[j], acc[i][j]);
        }
    }
    #pragma unroll
    for (int i = 0; i < TM; i++) {
        int m = m0 + ty * TM + i;
        if (m >= M) continue;
        #pragma unroll
        for (int j = 0; j < TN; j++) {
            int n = n0 + tx * TN + j;
            if (n >= N) continue;
            float v = acc[i][j];
            if (bias) v += bias[n];
            if (act == 2) v = softplus_f(v);
            C[(size_t)m * ldc + n] = v;
        }
    }
}

// ---------------------------------------------------------------------------
// Depthwise conv1d (K=4, pad(1,2)) in [b,l,d], bf16 in -> bf16 out (xlb == u).
// ---------------------------------------------------------------------------
__global__ __launch_bounds__(256) void dwconv(
    const ushort* __restrict__ xib, const float* __restrict__ cw,
    const float* __restrict__ cb, ushort* __restrict__ xlb)
{
    int idx = blockIdx.x * 256 + threadIdx.x;   // 524288
    int d4 = (idx & 127) * 4;
    int bl = idx >> 7;
    int b = bl >> 10, l = bl & 1023;
    float4 w0 = *(const float4*)(cw + d4 * 4);
    float4 w1 = *(const float4*)(cw + d4 * 4 + 4);
    float4 w2 = *(const float4*)(cw + d4 * 4 + 8);
    float4 w3 = *(const float4*)(cw + d4 * 4 + 12);
    float4 acc = *(const float4*)(cb + d4);
    const ushort* rowb = xib + ((size_t)b << 19) + d4;
    #pragma unroll
    for (int k = 0; k < 4; ++k) {
        int ll = l + k - 1;
        if ((unsigned)ll < 1024u) {
            uint2 p = *(const uint2*)(rowb + (size_t)ll * 512);
            acc.x = fmaf(bf2f((ushort)(p.x & 0xffffu)), ((const float*)&w0)[k], acc.x);
            acc.y = fmaf(bf2f((ushort)(p.x >> 16)),     ((const float*)&w1)[k], acc.y);
            acc.z = fmaf(bf2f((ushort)(p.y & 0xffffu)), ((const float*)&w2)[k], acc.z);
            acc.w = fmaf(bf2f((ushort)(p.y >> 16)),     ((const float*)&w3)[k], acc.w);
        }
    }
    uint2 pk;
    pk.x = (uint)f2bf(acc.x) | ((uint)f2bf(acc.y) << 16);
    pk.y = (uint)f2bf(acc.z) | ((uint)f2bf(acc.w) << 16);
    *(uint2*)(xlb + (size_t)bl * 512 + d4) = pk;
}

// ---------------------------------------------------------------------------
// Chunked scan pass 1 (fused dt_proj, 4-step composition, bf16 Tu/TB).
// LDS ~49KB -> 3 blocks/CU.
// ---------------------------------------------------------------------------
__global__ __launch_bounds__(512, 6) void scan_part1(
    const float* __restrict__ xdbl, const ushort* __restrict__ xlb,
    const float* __restrict__ dpw, const float* __restrict__ dpb,
    const float* __restrict__ alog,
    float* __restrict__ Psum, float* __restrict__ hFsum)
{
    __shared__ float Td[32][132];
    __shared__ __align__(8) ushort Tu[32][132];
    __shared__ __align__(8) ushort TB[16][132];
    __shared__ __align__(16) float xd[128][32];
    __shared__ float dpw_s[32][33];
    __shared__ float dpb_s[32];
    int t = threadIdx.x;
    int bid = blockIdx.x;                 // 512 = b(4) x dgG(16) x ch(8)
    int ch = bid & 7, dgG = (bid >> 3) & 15, b = bid >> 7;
    int d0 = dgG * 32;
    int bl0 = b * 1024 + ch * 128;
    #pragma unroll
    for (int r = 0; r < 2; ++r) {
        int idx = r * 512 + t;
        int l = idx >> 3, k4 = (idx & 7) * 4;
        float4 v = *(const float4*)(xdbl + (size_t)(bl0 + l) * 64 + k4);
        *(float4*)&xd[l][k4] = v;
    }
    {
        int l = t >> 2, d8 = (t & 3) * 8;
        uint4 p = *(const uint4*)(xlb + (size_t)(bl0 + l) * 512 + d0 + d8);
        Tu[d8 + 0][l] = (ushort)(p.x & 0xffffu);
        Tu[d8 + 1][l] = (ushort)(p.x >> 16);
        Tu[d8 + 2][l] = (ushort)(p.y & 0xffffu);
        Tu[d8 + 3][l] = (ushort)(p.y >> 16);
        Tu[d8 + 4][l] = (ushort)(p.z & 0xffffu);
        Tu[d8 + 5][l] = (ushort)(p.z >> 16);
        Tu[d8 + 6][l] = (ushort)(p.w & 0xffffu);
        Tu[d8 + 7][l] = (ushort)(p.w >> 16);
    }
    {
        int l = t >> 2, n4 = (t & 3) * 4;
        float4 bv = *(const float4*)(xdbl + (size_t)(bl0 + l) * 64 + 32 + n4);
        TB[n4 + 0][l] = f2bf(bv.x); TB[n4 + 1][l] = f2bf(bv.y);
        TB[n4 + 2][l] = f2bf(bv.z); TB[n4 + 3][l] = f2bf(bv.w);
    }
    #pragma unroll
    for (int r = 0; r < 2; ++r) {
        int idx = r * 512 + t;
        int dd = idx >> 5, kk = idx & 31;
        dpw_s[dd][kk] = dpw[(size_t)(d0 + dd) * 32 + kk];
    }
    if (t < 32) dpb_s[t] = dpb[d0 + t];
    __syncthreads();
    {
        int dd = t & 31, lb = (t >> 5) * 8;
        #pragma unroll
        for (int j = 0; j < 8; ++j) {
            int l = lb + j;
            float s = dpb_s[dd];
            #pragma unroll
            for (int k = 0; k < 32; ++k) s = fmaf(xd[l][k], dpw_s[dd][k], s);
            Td[dd][l] = softplus_f(s);
        }
    }
    __syncthreads();
    int w = t >> 6, lane = t & 63;
    int dl = lane >> 4, n = lane & 15;
    int col = w * 4 + dl;
    int d = d0 + col;
    float Ac = -__expf(alog[d * 16 + n]);
    float h = 0.f, P = 1.f;
    for (int l4 = 0; l4 < 32; ++l4) {
        float4 de = *(const float4*)&Td[col][l4 * 4];
        uint2 tu2 = *(const uint2*)&Tu[col][l4 * 4];
        uint2 tb2 = *(const uint2*)&TB[n][l4 * 4];
        float ux = bf2f((ushort)(tu2.x & 0xffffu)), uy = bf2f((ushort)(tu2.x >> 16));
        float uz = bf2f((ushort)(tu2.y & 0xffffu)), uw = bf2f((ushort)(tu2.y >> 16));
        float Bx = bf2f((ushort)(tb2.x & 0xffffu)), By = bf2f((ushort)(tb2.x >> 16));
        float Bz = bf2f((ushort)(tb2.y & 0xffffu)), Bw = bf2f((ushort)(tb2.y >> 16));
        float a1 = __expf(de.x * Ac), a2 = __expf(de.y * Ac);
        float a3 = __expf(de.z * Ac), a4 = __expf(de.w * Ac);
        float b1 = de.x * Bx * ux, b2 = de.y * By * uy;
        float b3 = de.z * Bz * uz, b4 = de.w * Bw * uw;
        float a21 = a2 * a1,     b21 = fmaf(a2, b1, b2);
        float a321 = a3 * a21,   b321 = fmaf(a3, b21, b3);
        float a4321 = a4 * a321, b4321 = fmaf(a4, b321, b4);
        h = fmaf(a4321, h, b4321);
        P *= a4321;
    }
    size_t si = ((size_t)(b * 128 + dgG * 8 + w) * 8 + ch) * 64 + lane;
    Psum[si] = P;
    hFsum[si] = h;
}

// ---------------------------------------------------------------------------
// Chunked scan pass 2 (fused dt_proj, 4-step composition, bf16 staging,
// yb packed bf16 pairs-along-l; xd overlaid on TB/TC/yb union). ~46KB LDS.
// ---------------------------------------------------------------------------
__global__ __launch_bounds__(512, 6) void scan_part2(
    const float* __restrict__ xdbl, const ushort* __restrict__ xlb,
    const float* __restrict__ dpw, const float* __restrict__ dpb,
    const float* __restrict__ alog, const float* __restrict__ dssm,
    const ushort* __restrict__ resb, ushort* __restrict__ ybb,
    const float* __restrict__ Psum, const float* __restrict__ hFsum)
{
    __shared__ float Td[32][132];
    __shared__ __align__(8) ushort Tu[32][132];
    // union: xd fp32[128][32] (16384B) overlays TB+TC+yb2 (4224+4224+8448B)
    __shared__ __align__(16) unsigned char uni[16896];
    __shared__ float dpw_s[32][33];
    __shared__ float dpb_s[32];
    float* xd = (float*)uni;                          // [128][32]
    ushort (*TB)[132] = (ushort(*)[132])uni;          // [16][132]
    ushort (*TC)[132] = (ushort(*)[132])(uni + 4224); // [16][132]
    uint (*yb2)[33] = (uint(*)[33])(uni + 8448);      // [64][33]
    int t = threadIdx.x;
    int bid = blockIdx.x;                 // 512 = b(4) x dgG(16) x ch(8)
    int ch = bid & 7, dgG = (bid >> 3) & 15, b = bid >> 7;
    int d0 = dgG * 32;
    int bl0 = b * 1024 + ch * 128;
    // stage xd (into union), Tu, dpw, dpb
    #pragma unroll
    for (int r = 0; r < 2; ++r) {
        int idx = r * 512 + t;
        int l = idx >> 3, k4 = (idx & 7) * 4;
        float4 v = *(const float4*)(xdbl + (size_t)(bl0 + l) * 64 + k4);
        *(float4*)&xd[l * 32 + k4] = v;
    }
    {
        int l = t >> 2, d8 = (t & 3) * 8;
        uint4 p = *(const uint4*)(xlb + (size_t)(bl0 + l) * 512 + d0 + d8);
        Tu[d8 + 0][l] = (ushort)(p.x & 0xffffu);
        Tu[d8 + 1][l] = (ushort)(p.x >> 16);
        Tu[d8 + 2][l] = (ushort)(p.y & 0xffffu);
        Tu[d8 + 3][l] = (ushort)(p.y >> 16);
        Tu[d8 + 4][l] = (ushort)(p.z & 0xffffu);
        Tu[d8 + 5][l] = (ushort)(p.z >> 16);
        Tu[d8 + 6][l] = (ushort)(p.w & 0xffffu);
        Tu[d8 + 7][l] = (ushort)(p.w >> 16);
    }
    #pragma unroll
    for (int r = 0; r < 2; ++r) {
        int idx = r * 512 + t;
        int dd = idx >> 5, kk = idx & 31;
        dpw_s[dd][kk] = dpw[(size_t)(d0 + dd) * 32 + kk];
    }
    if (t < 32) dpb_s[t] = dpb[d0 + t];
    __syncthreads();
    // fused dt_proj -> Td (reads xd)
    {
        int dd = t & 31, lb = (t >> 5) * 8;
        #pragma unroll
        for (int j = 0; j < 8; ++j) {
            int l = lb + j;
            float s = dpb_s[dd];
            #pragma unroll
            for (int k = 0; k < 32; ++k) s = fmaf(xd[l * 32 + k], dpw_s[dd][k], s);
            Td[dd][l] = softplus_f(s);
        }
    }
    __syncthreads();   // xd dead; Td visible
    // stage TB/TC (over dead xd region)
    {
        int l = t >> 2, n4 = (t & 3) * 4;
        float4 bv = *(const float4*)(xdbl + (size_t)(bl0 + l) * 64 + 32 + n4);
        float4 cv = *(const float4*)(xdbl + (size_t)(bl0 + l) * 64 + 48 + n4);
        TB[n4 + 0][l] = f2bf(bv.x); TB[n4 + 1][l] = f2bf(bv.y);
        TB[n4 + 2][l] = f2bf(bv.z); TB[n4 + 3][l] = f2bf(bv.w);
        TC[n4 + 0][l] = f2bf(cv.x); TC[n4 + 1][l] = f2bf(cv.y);
        TC[n4 + 2][l] = f2bf(cv.z); TC[n4 + 3][l] = f2bf(cv.w);
    }
    int w = t >> 6, lane = t & 63;
    int dl = lane >> 4, n = lane & 15;
    int col = w * 4 + dl;
    int d = d0 + col;
    float Ac = -__expf(alog[d * 16 + n]);
    float Dd = dssm[d];
    float h = 0.f;
    {
        size_t sbase = (size_t)(b * 128 + dgG * 8 + w) * 512 + lane;
        for (int cc = 0; cc < ch; ++cc) {
            float Pv = Psum[sbase + (size_t)cc * 64];
            float hv = hFsum[sbase + (size_t)cc * 64];
            h = Pv * h + hv;
        }
    }
    __syncthreads();   // TB/TC visible
    for (int l4 = 0; l4 < 32; ++l4) {
        float4 de = *(const float4*)&Td[col][l4 * 4];
        uint2 tu2 = *(const uint2*)&Tu[col][l4 * 4];
        uint2 tb2 = *(const uint2*)&TB[n][l4 * 4];
        uint2 tc2 = *(const uint2*)&TC[n][l4 * 4];
        float ux = bf2f((ushort)(tu2.x & 0xffffu)), uy = bf2f((ushort)(tu2.x >> 16));
        float uz = bf2f((ushort)(tu2.y & 0xffffu)), uw = bf2f((ushort)(tu2.y >> 16));
        float Bx = bf2f((ushort)(tb2.x & 0xffffu)), By = bf2f((ushort)(tb2.x >> 16));
        float Bz = bf2f((ushort)(tb2.y & 0xffffu)), Bw = bf2f((ushort)(tb2.y >> 16));
        float Cx = bf2f((ushort)(tc2.x & 0xffffu)), Cy = bf2f((ushort)(tc2.x >> 16));
        float Cz = bf2f((ushort)(tc2.y & 0xffffu)), Cw = bf2f((ushort)(tc2.y >> 16));
        float a1 = __expf(de.x * Ac), a2 = __expf(de.y * Ac);
        float a3 = __expf(de.z * Ac), a4 = __expf(de.w * Ac);
        float b1 = de.x * Bx * ux, b2 = de.y * By * uy;
        float b3 = de.z * Bz * uz, b4 = de.w * Bw * uw;
        float a21 = a2 * a1,     b21 = fmaf(a2, b1, b2);
        float a321 = a3 * a21,   b321 = fmaf(a3, b21, b3);
        float a4321 = a4 * a321, b4321 = fmaf(a4, b321, b4);
        float h1 = fmaf(a1, h, b1);
        float h2 = fmaf(a21, h, b21);
        float h3 = fmaf(a321, h, b321);
        float h4 = fmaf(a4321, h, b4321);
        h = h4;
        float p0 = h1 * Cx, p1 = h2 * Cy, p2 = h3 * Cz, p3 = h4 * Cw;
        #pragma unroll
        for (int off = 1; off < 16; off <<= 1) {
            p0 += __shfl_xor(p0, off);
            p1 += __shfl_xor(p1, off);
            p2 += __shfl_xor(p2, off);
            p3 += __shfl_xor(p3, off);
        }
        if (n == 0) {
            int l2 = l4 * 2;
            float y0 = fmaf(ux, Dd, p0), y1 = fmaf(uy, Dd, p1);
            float y2 = fmaf(uz, Dd, p2), y3 = fmaf(uw, Dd, p3);
            yb2[l2 + 0][col] = (uint)f2bf(y0) | ((uint)f2bf(y1) << 16);
            yb2[l2 + 1][col] = (uint)f2bf(y2) | ((uint)f2bf(y3) << 16);
        }
    }
    __syncthreads();
    // gated store: thread handles (l2, col); 2 ushort stores (64B runs/half-wave)
    size_t base = ((size_t)(b * 1024 + ch * 128)) * 512 + d0;   // ushort offset
    #pragma unroll
    for (int j = 0; j < 4; ++j) {
        int idx = j * 512 + t;                 // 2048 = 64 l2 x 32 col
        int l2 = idx >> 5, col2 = idx & 31;
        uint yv = yb2[l2][col2];
        int l0 = l2 * 2;
        float r0 = bf2f(resb[base + (size_t)l0 * 512 + col2]);
        float r1 = bf2f(resb[base + (size_t)(l0 + 1) * 512 + col2]);
        float y0 = bf2f((ushort)(yv & 0xffffu)) * r0;
        float y1 = bf2f((ushort)(yv >> 16)) * r1;
        ybb[base + (size_t)l0 * 512 + col2] = f2bf(y0);
        ybb[base + (size_t)(l0 + 1) * 512 + col2] = f2bf(y1);
    }
}

// s[row] = LN(o[row])*g + b + s[row]; also writes bf16 copy sb. One wave/row.
__global__ __launch_bounds__(256) void ln_res_kernel(
    const float* __restrict__ o, const float* __restrict__ g,
    const float* __restrict__ bb, float* __restrict__ s, ushort* __restrict__ sb)
{
    int row = blockIdx.x * 4 + (threadIdx.x >> 6);
    int lane = threadIdx.x & 63;
    const float4* orow = (const float4*)(o + (size_t)row * 256);
    float4 v = orow[lane];
    float sum = v.x + v.y + v.z + v.w;
    float sq = v.x * v.x + v.y * v.y + v.z * v.z + v.w * v.w;
    #pragma unroll
    for (int off = 1; off < 64; off <<= 1) {
        sum += __shfl_xor(sum, off);
        sq += __shfl_xor(sq, off);
    }
    float m = sum * (1.f / 256.f);
    float var = sq * (1.f / 256.f) - m * m;
    float rstd = rsqrtf(var + 1e-5f);
    float4 gg = ((const float4*)g)[lane];
    float4 bv = ((const float4*)bb)[lane];
    float4* srow = (float4*)(s + (size_t)row * 256);
    float4 sv = srow[lane];
    sv.x += (v.x - m) * rstd * gg.x + bv.x;
    sv.y += (v.y - m) * rstd * gg.y + bv.y;
    sv.z += (v.z - m) * rstd * gg.z + bv.z;
    sv.w += (v.w - m) * rstd * gg.w + bv.w;
    srow[lane] = sv;
    uint2 pk;
    pk.x = (uint)f2bf(sv.x) | ((uint)f2bf(sv.y) << 16);
    pk.y = (uint)f2bf(sv.z) | ((uint)f2bf(sv.w) << 16);
    *(uint2*)(sb + (size_t)row * 256 + lane * 4) = pk;
}

// mean over l then LN over 256 channels. grid 4 x 256.
__global__ __launch_bounds__(256) void pool_ln_kernel(
    const float* __restrict__ s, const float* __restrict__ nw,
    const float* __restrict__ nb, float* __restrict__ sln)
{
    int b = blockIdx.x, c = threadIdx.x;
    const float* p = s + (size_t)b * 262144 + c;
    float acc = 0.f;
    for (int l = 0; l < 1024; ++l) acc += p[(size_t)l * 256];
    float pooled = acc * (1.f / 1024.f);
    __shared__ float rs[4], rq[4];
    float sum = pooled, sq = pooled * pooled;
    #pragma unroll
    for (int off = 1; off < 64; off <<= 1) {
        sum += __shfl_xor(sum, off);
        sq += __shfl_xor(sq, off);
    }
    int w = threadIdx.x >> 6;
    if ((threadIdx.x & 63) == 0) { rs[w] = sum; rq[w] = sq; }
    __syncthreads();
    sum = rs[0] + rs[1] + rs[2] + rs[3];
    sq = rq[0] + rq[1] + rq[2] + rq[3];
    float m = sum * (1.f / 256.f);
    float var = sq * (1.f / 256.f) - m * m;
    float rstd = rsqrtf(var + 1e-5f);
    sln[b * 256 + c] = (pooled - m) * rstd * nw[c] + nb[c];
}

// softmax over 1000 logits per b
__global__ __launch_bounds__(256) void softmax_kernel(float* __restrict__ out)
{
    int b = threadIdx.x >> 6, lane = threadIdx.x & 63;
    const float* lg = out + b * 1000;
    float v[16];
    float mx = -1e30f;
    #pragma unroll
    for (int j = 0; j < 16; ++j) {
        int i = lane + j * 64;
        v[j] = (i < 1000) ? lg[i] : -1e30f;
        mx = fmaxf(mx, v[j]);
    }
    #pragma unroll
    for (int off = 1; off < 64; off <<= 1) mx = fmaxf(mx, __shfl_xor(mx, off));
    float sum = 0.f;
    #pragma unroll
    for (int j = 0; j < 16; ++j) {
        int i = lane + j * 64;
        if (i < 1000) { v[j] = __expf(v[j] - mx); sum += v[j]; }
    }
    #pragma unroll
    for (int off = 1; off < 64; off <<= 1) sum += __shfl_xor(sum, off);
    float inv = 1.f / sum;
    float* so = out + 4000 + b * 1000;
    #pragma unroll
    for (int j = 0; j < 16; ++j) {
        int i = lane + j * 64;
        if (i < 1000) so[i] = v[j] * inv;
    }
}

// ---------------------------------------------------------------------------
extern "C" void kernel_launch(void* const* d_in, const int* in_sizes, int n_in,
                              void* d_out, int out_size, void* d_ws, size_t ws_size,
                              hipStream_t stream)
{
    const float* x    = (const float*)d_in[0];
    const float* c1w  = (const float*)d_in[1];
    const float* c1b  = (const float*)d_in[2];
    const float* g1   = (const float*)d_in[3];
    const float* b1   = (const float*)d_in[4];
    const float* c2w  = (const float*)d_in[5];
    const float* c2b  = (const float*)d_in[6];
    const float* g2   = (const float*)d_in[7];
    const float* b2   = (const float*)d_in[8];
    const float* pw   = (const float*)d_in[9];
    const float* pb   = (const float*)d_in[10];
    const float* g3   = (const float*)d_in[11];
    const float* b3   = (const float*)d_in[12];
    const float* ipw  = (const float*)d_in[13];
    const float* ipb  = (const float*)d_in[14];
    const float* cw   = (const float*)d_in[15];
    const float* cb   = (const float*)d_in[16];
    const float* xpw  = (const float*)d_in[17];
    const float* dpw  = (const float*)d_in[18];
    const float* dpb  = (const float*)d_in[19];
    const float* alog = (const float*)d_in[20];
    const float* dssm = (const float*)d_in[21];
    const float* opw  = (const float*)d_in[22];
    const float* opb  = (const float*)d_in[23];
    const float* lnw  = (const float*)d_in[24];
    const float* lnb  = (const float*)d_in[25];
    const float* nw   = (const float*)d_in[26];
    const float* nb   = (const float*)d_in[27];
    const float* fcw  = (const float*)d_in[28];
    const float* fcb  = (const float*)d_in[29];
    float* out = (float*)d_out;
    float* wsf = (float*)d_ws;

    float*  s_   = wsf;
    ushort* sb   = (ushort*)(wsf + 1048576);
    ushort* xib  = (ushort*)(wsf + 1572864);
    ushort* h2b  = (ushort*)(wsf + 1572864);
    float*  obuf = wsf + 1572864;
    ushort* resb = (ushort*)(wsf + 3670016);
    ushort* xlb  = (ushort*)(wsf + 4718592);   // == u == ybb (in-place gate)
    ushort* ybb  = (ushort*)(wsf + 4718592);
    ushort* h1b  = (ushort*)(wsf + 4718592);
    ushort* Apb  = (ushort*)(wsf + 6815744);
    float*  xdbl = wsf + 8912896;
    ushort* ipwb = (ushort*)(wsf + 9175040);
    ushort* opwb = (ushort*)(wsf + 9699328);
    ushort* w2b  = (ushort*)(wsf + 9961472);
    ushort* pwTb = (ushort*)(wsf + 10108928);
    float*  sln  = wsf + 10240000;
    float*  Psum = wsf + 10241024;
    float*  hFsum= wsf + 10503168;
    ushort* xpwb = (ushort*)(wsf + 10765312);

    // --- fused weight prep (1 dispatch) ---
    hipLaunchKernelGGL(wprep, dim3(8832), dim3(256), 0, stream,
                       ipw, opw, c2w, pw, xpw, ipwb, opwb, w2b, pwTb, xpwb);

    // --- conv stem ---
    hipLaunchKernelGGL(conv1_nhwc, dim3(256), dim3(256), 0, stream, x, c1w, c1b, g1, b1, h1b);
    hipLaunchKernelGGL(conv2_mfma, dim3(128, 4), dim3(256), 0, stream, h1b, w2b, c2b, g2, b2, h2b);
    hipLaunchKernelGGL(im2col_bf16, dim3(2048), dim3(256), 0, stream, h2b, Apb);
    hipLaunchKernelGGL((mfma_gemm_bt<64, 64, 2>), dim3(64, 4), dim3(256), 0, stream,
                       Apb, 1024, pwTb, 1024, pb, g3, b3, s_, sb, nullptr, 256, 1024);

    // --- mamba blocks ---
    for (int i = 0; i < 4; ++i) {
        const ushort* ipwb_i = ipwb + (size_t)i * 1024 * 256;
        const float*  ipb_i  = ipb + i * 1024;
        const float*  cw_i   = cw + i * 512 * 4;
        const float*  cb_i   = cb + i * 512;
        const ushort* xpwb_i = xpwb + (size_t)i * 64 * 512;
        const float*  dpw_i  = dpw + (size_t)i * 512 * 32;
        const float*  dpb_i  = dpb + i * 512;
        const float*  alog_i = alog + (size_t)i * 512 * 16;
        const float*  dssm_i = dssm + i * 512;
        const ushort* opwb_i = opwb + (size_t)i * 256 * 512;
        const float*  opb_i  = opb + i * 256;
        const float*  lnw_i  = lnw + i * 256;
        const float*  lnb_i  = lnb + i * 256;

        hipLaunchKernelGGL((mfma_gemm_bt<64, 128, 3>), dim3(64, 8), dim3(256), 0, stream,
                           sb, 256, ipwb_i, 256, ipb_i, nullptr, nullptr,
                           nullptr, xib, resb, 0, 256);
        hipLaunchKernelGGL(dwconv, dim3(2048), dim3(256), 0, stream, xib, cw_i, cb_i, xlb);
        hipLaunchKernelGGL((mfma_gemm_bt<64, 64, 0>), dim3(64, 1), dim3(256), 0, stream,
                           xlb, 512, xpwb_i, 512, nullptr, nullptr, nullptr,
                           xdbl, nullptr, nullptr, 64, 512);
        hipLaunchKernelGGL(scan_part1, dim3(512), dim3(512), 0, stream,
                           xdbl, xlb, dpw_i, dpb_i, alog_i, Psum, hFsum);
        hipLaunchKernelGGL(scan_part2, dim3(512), dim3(512), 0, stream,
                           xdbl, xlb, dpw_i, dpb_i, alog_i, dssm_i, resb, ybb, Psum, hFsum);
        hipLaunchKernelGGL((mfma_gemm_bt<64, 64, 0>), dim3(64, 4), dim3(256), 0, stream,
                           ybb, 512, opwb_i, 512, opb_i, nullptr, nullptr,
                           obuf, nullptr, nullptr, 256, 512);
        hipLaunchKernelGGL(ln_res_kernel, dim3(1024), dim3(256), 0, stream,
                           obuf, lnw_i, lnb_i, s_, sb);
    }

    // --- head ---
    hipLaunchKernelGGL(pool_ln_kernel, dim3(4), dim3(256), 0, stream, s_, nw, nb, sln);
    hipLaunchKernelGGL((gemm_kernel<64, 64, 16, 4, 4>), dim3(1, 16), dim3(256), 0, stream,
                       sln, 256, fcw, 256, fcb, out, 1000, 4, 1000, 256, 0);
    hipLaunchKernelGGL(softmax_kernel, dim3(1), dim3(256), 0, stream, out);
}

// Round 15
// 626.962 us; speedup vs baseline: 1.1725x; 1.0431x over previous
//
#include <hip/hip_runtime.h>
#include <math.h>

// ---------------------------------------------------------------------------
// FastImageMamba forward. R15: R14 + 16 chunks of 64 timesteps in the scan
// (grid 512 -> 1024 blocks: was grid-limited at 2 blocks/CU; now 4/CU).
// B=4, DM=256, NL=4, NC=1000, DI=512, NS=16, DTR=32, K=4, L=1024, H=W=64
// ---------------------------------------------------------------------------

#define BN_RSQ 0.99999500003749969f   // 1/sqrt(1+1e-5)

typedef unsigned int uint;
typedef unsigned short ushort;
typedef __bf16 bf16x8 __attribute__((ext_vector_type(8)));
typedef float floatx4 __attribute__((ext_vector_type(4)));

__device__ __forceinline__ float gelu_f(float v) {
    return 0.5f * v * (1.0f + erff(v * 0.70710678118654752f));
}
__device__ __forceinline__ float softplus_f(float v) {
    return (v > 20.f) ? v : log1pf(expf(v));
}
__device__ __forceinline__ ushort f2bf(float f) {
    uint x = __float_as_uint(f);
    x += 0x7fffu + ((x >> 16) & 1u);
    return (ushort)(x >> 16);
}
__device__ __forceinline__ float bf2f(ushort u) {
    return __uint_as_float((uint)u << 16);
}

// ---------------------------------------------------------------------------
// Fused weight prep: all fp32->bf16 weight conversions in one dispatch.
// ---------------------------------------------------------------------------
__global__ void wprep(const float* __restrict__ ipw, const float* __restrict__ opw,
                      const float* __restrict__ c2w, const float* __restrict__ pw,
                      const float* __restrict__ xpw,
                      ushort* __restrict__ ipwb, ushort* __restrict__ opwb,
                      ushort* __restrict__ w2b, ushort* __restrict__ pwTb,
                      ushort* __restrict__ xpwb)
{
    int idx = blockIdx.x * 256 + threadIdx.x;
    if (idx < 1048576) {
        ipwb[idx] = f2bf(ipw[idx]);
    } else if (idx < 1572864) {
        int i = idx - 1048576;
        opwb[i] = f2bf(opw[i]);
    } else if (idx < 1867776) {
        int i = idx - 1572864;
        int oc = i / 1152, k = i % 1152;
        int s = k >> 7, ic = k & 127;
        w2b[i] = f2bf(c2w[(size_t)(oc * 128 + ic) * 9 + s]);
    } else if (idx < 2129920) {
        int i = idx - 1867776;
        int oc = i >> 10, k = i & 1023;
        int s = k >> 8, ic = k & 255;
        int ky = s >> 1, kx = s & 1;
        pwTb[i] = f2bf(pw[((size_t)(oc * 256 + ic) * 2 + ky) * 2 + kx]);
    } else if (idx < 2260992) {
        int i = idx - 2129920;
        xpwb[i] = f2bf(xpw[i]);
    }
}

// ---------------------------------------------------------------------------
// conv1: 3x3 s1p1, IC=3 -> OC=128, NCHW fp32 in, NHWC bf16 out (+bias+BN+GELU)
// ---------------------------------------------------------------------------
__global__ __launch_bounds__(256) void conv1_nhwc(
    const float* __restrict__ x, const float* __restrict__ w,
    const float* __restrict__ cb, const float* __restrict__ g,
    const float* __restrict__ bb, ushort* __restrict__ out)
{
    __shared__ float tin[3][3][64];
    __shared__ float ws[3456];
    int t = threadIdx.x;
    int b = blockIdx.x >> 6, y = blockIdx.x & 63;
    for (int i = t; i < 3456; i += 256) ws[i] = w[i];
    for (int i = t; i < 576; i += 256) {
        int ic = i / 192, r = (i >> 6) % 3, xx = i & 63;
        int gy = y + r - 1;
        tin[ic][r][xx] = ((unsigned)gy < 64u) ? x[((b * 3 + ic) * 64 + gy) * 64 + xx] : 0.f;
    }
    __syncthreads();
    int tx = t & 15, ty = t >> 4;
    int oc0 = tx * 8, px0 = ty * 4;
    float acc[4][8];
    #pragma unroll
    for (int p = 0; p < 4; ++p)
        #pragma unroll
        for (int o = 0; o < 8; ++o) acc[p][o] = 0.f;
    for (int ic = 0; ic < 3; ++ic)
        #pragma unroll
        for (int ky = 0; ky < 3; ++ky)
            #pragma unroll
            for (int kx = 0; kx < 3; ++kx) {
                float av[4];
                #pragma unroll
                for (int p = 0; p < 4; ++p) {
                    int xx = px0 + p + kx - 1;
                    av[p] = ((unsigned)xx < 64u) ? tin[ic][ky][xx] : 0.f;
                }
                #pragma unroll
                for (int o = 0; o < 8; ++o) {
                    float wv = ws[(oc0 + o) * 27 + ic * 9 + ky * 3 + kx];
                    #pragma unroll
                    for (int p = 0; p < 4; ++p) acc[p][o] = fmaf(av[p], wv, acc[p][o]);
                }
            }
    #pragma unroll
    for (int p = 0; p < 4; ++p) {
        uint pk[4];
        #pragma unroll
        for (int o2 = 0; o2 < 4; ++o2) {
            int oc = oc0 + o2 * 2;
            float v0 = gelu_f((acc[p][o2 * 2] + cb[oc]) * (g[oc] * BN_RSQ) + bb[oc]);
            float v1 = gelu_f((acc[p][o2 * 2 + 1] + cb[oc + 1]) * (g[oc + 1] * BN_RSQ) + bb[oc + 1]);
            pk[o2] = (uint)f2bf(v0) | ((uint)f2bf(v1) << 16);
        }
        uint4 vv = make_uint4(pk[0], pk[1], pk[2], pk[3]);
        *(uint4*)(out + ((size_t)((b * 64 + y) * 64 + px0 + p)) * 128 + oc0) = vv;
    }
}

// ---------------------------------------------------------------------------
// bf16 MFMA GEMM (A @ W^T), BMxBN tile, BK=32, 4 waves (2x2), reg dbuf.
// EPI: 0 = +bias -> fp32 Cf[ldc]
//      2 = +bias,BN,GELU -> fp32 Cf + bf16 Cb (same ldc)
//      3 = in_proj: n<512 -> bf16 Cb[m*512+n]; n>=512 -> bf16 silu -> Cb2
// ---------------------------------------------------------------------------
template<int BM, int BN, int EPI>
__global__ __launch_bounds__(256, 2) void mfma_gemm_bt(
    const ushort* __restrict__ A, int lda,
    const ushort* __restrict__ W, int ldw,
    const float* __restrict__ bias,
    const float* __restrict__ bnG, const float* __restrict__ bnB,
    float* __restrict__ Cf, ushort* __restrict__ Cb, ushort* __restrict__ Cb2,
    int ldc, int K)
{
    constexpr int PAD = 40;
    constexpr int AP = BM / 64;
    constexpr int BP = BN / 64;
    constexpr int FM = BM / 32;
    constexpr int FN = BN / 32;
    __shared__ __align__(16) ushort As[BM * PAD];
    __shared__ __align__(16) ushort Bs[BN * PAD];
    int t = threadIdx.x;
    int m0 = blockIdx.x * BM, n0 = blockIdx.y * BN;
    int lane = t & 63, wid = t >> 6;
    int wm = (wid & 1) * (BM / 2), wn = (wid >> 1) * (BN / 2);
    int fr = lane & 15, fk = (lane >> 4) * 8;
    int r0 = t >> 2, c0 = (t & 3) * 8;
    floatx4 acc[FM][FN];
    #pragma unroll
    for (int i = 0; i < FM; ++i)
        #pragma unroll
        for (int j = 0; j < FN; ++j) acc[i][j] = {0.f, 0.f, 0.f, 0.f};
    uint4 ra[AP], rb[BP];
    #pragma unroll
    for (int p = 0; p < AP; ++p)
        ra[p] = *(const uint4*)(A + (size_t)(m0 + r0 + p * 64) * lda + c0);
    #pragma unroll
    for (int p = 0; p < BP; ++p)
        rb[p] = *(const uint4*)(W + (size_t)(n0 + r0 + p * 64) * ldw + c0);
    for (int k0 = 0; k0 < K; k0 += 32) {
        __syncthreads();
        #pragma unroll
        for (int p = 0; p < AP; ++p) *(uint4*)&As[(r0 + p * 64) * PAD + c0] = ra[p];
        #pragma unroll
        for (int p = 0; p < BP; ++p) *(uint4*)&Bs[(r0 + p * 64) * PAD + c0] = rb[p];
        __syncthreads();
        if (k0 + 32 < K) {
            #pragma unroll
            for (int p = 0; p < AP; ++p)
                ra[p] = *(const uint4*)(A + (size_t)(m0 + r0 + p * 64) * lda + k0 + 32 + c0);
            #pragma unroll
            for (int p = 0; p < BP; ++p)
                rb[p] = *(const uint4*)(W + (size_t)(n0 + r0 + p * 64) * ldw + k0 + 32 + c0);
        }
        bf16x8 af[FM], bw[FN];
        #pragma unroll
        for (int i = 0; i < FM; ++i)
            af[i] = *(const bf16x8*)&As[(wm + i * 16 + fr) * PAD + fk];
        #pragma unroll
        for (int j = 0; j < FN; ++j)
            bw[j] = *(const bf16x8*)&Bs[(wn + j * 16 + fr) * PAD + fk];
        #pragma unroll
        for (int i = 0; i < FM; ++i)
            #pragma unroll
            for (int j = 0; j < FN; ++j)
                acc[i][j] = __builtin_amdgcn_mfma_f32_16x16x32_bf16(af[i], bw[j], acc[i][j], 0, 0, 0);
    }
    int rbase = (lane >> 4) * 4, cc = lane & 15;
    #pragma unroll
    for (int j = 0; j < FN; ++j) {
        int n = n0 + wn + j * 16 + cc;
        float bv = bias ? bias[n] : 0.f;
        float scl = 0.f, shf = 0.f;
        if (EPI == 2) { scl = bnG[n] * BN_RSQ; shf = bnB[n]; }
        #pragma unroll
        for (int i = 0; i < FM; ++i) {
            #pragma unroll
            for (int r = 0; r < 4; ++r) {
                int m = m0 + wm + i * 16 + rbase + r;
                float v = acc[i][j][r] + bv;
                if (EPI == 2) v = gelu_f(v * scl + shf);
                if (EPI == 0) {
                    Cf[(size_t)m * ldc + n] = v;
                } else if (EPI == 2) {
                    Cf[(size_t)m * ldc + n] = v;
                    Cb[(size_t)m * ldc + n] = f2bf(v);
                } else {
                    if (n < 512) Cb[(size_t)m * 512 + n] = f2bf(v);
                    else Cb2[(size_t)m * 512 + (n - 512)] = f2bf(v / (1.f + __expf(-v)));
                }
            }
        }
    }
}

// ---------------------------------------------------------------------------
// conv2: 9-shift implicit MFMA GEMM, 128px x 64oc tile, BK=64 (18 steps),
// reg dbuf with EXPLICIT SCALAR uint4s (array-by-ref spills to scratch).
// ---------------------------------------------------------------------------
#define C2_LOAD(step)                                                            \
    {                                                                            \
        int s_ = (step) >> 1, ich_ = ((step) & 1) * 64;                          \
        int ky_ = s_ / 3, kx_ = s_ % 3;                                          \
        int sy_ = y0 + (ra_row >> 6) + ky_ - 1;                                  \
        int sx_ = (ra_row & 63) + kx_ - 1;                                       \
        bool v_ = ((unsigned)sy_ < 64u) && ((unsigned)sx_ < 64u);                \
        const ushort* ap_ = hb + ((size_t)(sy_ * 64 + sx_)) * 128 + ich_ + ra_c; \
        uint4 zz_ = make_uint4(0u, 0u, 0u, 0u);                                  \
        ra0 = v_ ? *(const uint4*)(ap_ + 0)  : zz_;                              \
        ra1 = v_ ? *(const uint4*)(ap_ + 8)  : zz_;                              \
        ra2 = v_ ? *(const uint4*)(ap_ + 16) : zz_;                              \
        ra3 = v_ ? *(const uint4*)(ap_ + 24) : zz_;                              \
        const ushort* wp_ = w2b + (size_t)(n0 + rb_row) * 1152 + s_ * 128 + ich_ + rb_c; \
        rb0 = *(const uint4*)(wp_ + 0);                                          \
        rb1 = *(const uint4*)(wp_ + 8);                                          \
    }

__global__ __launch_bounds__(256, 2) void conv2_mfma(
    const ushort* __restrict__ h1b, const ushort* __restrict__ w2b,
    const float* __restrict__ cb, const float* __restrict__ g,
    const float* __restrict__ bb, ushort* __restrict__ h2b)
{
    constexpr int PAD = 72;
    __shared__ __align__(16) ushort As[128 * PAD];
    __shared__ __align__(16) ushort Bs[64 * PAD];
    int t = threadIdx.x;
    int m0 = blockIdx.x * 128, n0 = blockIdx.y * 64;
    int b = m0 >> 12;
    int y0 = (m0 & 4095) >> 6;
    int lane = t & 63, wid = t >> 6;
    int wm = (wid & 1) * 64, wn = (wid >> 1) * 32;
    int fr = lane & 15, fk = (lane >> 4) * 8;
    int ra_row = t >> 1, ra_c = (t & 1) * 32;
    int rb_row = t >> 2, rb_c = (t & 3) * 16;
    floatx4 acc[4][2];
    #pragma unroll
    for (int i = 0; i < 4; ++i)
        #pragma unroll
        for (int j = 0; j < 2; ++j) acc[i][j] = {0.f, 0.f, 0.f, 0.f};
    const ushort* hb = h1b + (size_t)b * 4096 * 128;

    uint4 ra0, ra1, ra2, ra3, rb0, rb1;
    C2_LOAD(0);
    for (int step = 0; step < 18; ++step) {
        __syncthreads();
        *(uint4*)&As[ra_row * PAD + ra_c + 0]  = ra0;
        *(uint4*)&As[ra_row * PAD + ra_c + 8]  = ra1;
        *(uint4*)&As[ra_row * PAD + ra_c + 16] = ra2;
        *(uint4*)&As[ra_row * PAD + ra_c + 24] = ra3;
        *(uint4*)&Bs[rb_row * PAD + rb_c + 0]  = rb0;
        *(uint4*)&Bs[rb_row * PAD + rb_c + 8]  = rb1;
        __syncthreads();
        if (step + 1 < 18) C2_LOAD(step + 1);
        #pragma unroll
        for (int ks = 0; ks < 64; ks += 32) {
            bf16x8 af[4], bw[2];
            #pragma unroll
            for (int i = 0; i < 4; ++i)
                af[i] = *(const bf16x8*)&As[(wm + i * 16 + fr) * PAD + ks + fk];
            #pragma unroll
            for (int j = 0; j < 2; ++j)
                bw[j] = *(const bf16x8*)&Bs[(wn + j * 16 + fr) * PAD + ks + fk];
            #pragma unroll
            for (int i = 0; i < 4; ++i)
                #pragma unroll
                for (int j = 0; j < 2; ++j)
                    acc[i][j] = __builtin_amdgcn_mfma_f32_16x16x32_bf16(af[i], bw[j], acc[i][j], 0, 0, 0);
        }
    }
    int rbase = (lane >> 4) * 4, cc = lane & 15;
    #pragma unroll
    for (int j = 0; j < 2; ++j) {
        int n = n0 + wn + j * 16 + cc;
        float scl = g[n] * BN_RSQ, shf = bb[n], bv2 = cb[n];
        #pragma unroll
        for (int i = 0; i < 4; ++i) {
            #pragma unroll
            for (int r = 0; r < 4; ++r) {
                int m = m0 + wm + i * 16 + rbase + r;
                float v = gelu_f((acc[i][j][r] + bv2) * scl + shf);
                h2b[(size_t)m * 256 + n] = f2bf(v);
            }
        }
    }
}

// Apb[m][s*256+ic] = h2b[b, 2oy+ky, 2ox+kx, ic]
__global__ void im2col_bf16(const ushort* __restrict__ h2b, ushort* __restrict__ Apb)
{
    int idx = blockIdx.x * 256 + threadIdx.x;          // 524288 uint4 chunks
    int k8 = idx & 127;
    int m = idx >> 7;
    int b = m >> 10, oy = (m >> 5) & 31, ox = m & 31;
    int s = k8 >> 5, ic8 = k8 & 31;
    int ky = s >> 1, kx = s & 1;
    uint4 v = *(const uint4*)(h2b + ((size_t)(b * 4096 + (2 * oy + ky) * 64 + 2 * ox + kx)) * 256 + ic8 * 8);
    *(uint4*)(Apb + (size_t)m * 1024 + k8 * 8) = v;
}

// ---------------------------------------------------------------------------
// fp32 tiled GEMM (reg dbuf): head FC only.
// ---------------------------------------------------------------------------
template<int BM, int BN, int BK, int TM, int TN>
__global__ __launch_bounds__(256) void gemm_kernel(
    const float* __restrict__ A, int lda,
    const float* __restrict__ W, int ldw,
    const float* __restrict__ bias,
    float* __restrict__ C, int ldc,
    int M, int N, int K, int act)
{
    static_assert(BM * BK / 4 == 256 && BN * BK / 4 == 256, "staging shape");
    __shared__ float As[BK][BM + 4];
    __shared__ float Bs[BK][BN + 4];
    int t = threadIdx.x;
    int m0 = blockIdx.x * BM, n0 = blockIdx.y * BN;
    float acc[TM][TN];
    #pragma unroll
    for (int i = 0; i < TM; i++)
        #pragma unroll
        for (int j = 0; j < TN; j++) acc[i][j] = 0.f;
    const int LPR = BK / 4;
    int lr = t / LPR, lc4 = (t % LPR) * 4;
    int ty = t >> 4, tx = t & 15;
    int ma = m0 + lr, nb = n0 + lr;
    float4 va = make_float4(0.f, 0.f, 0.f, 0.f);
    float4 vb = make_float4(0.f, 0.f, 0.f, 0.f);
    if (ma < M) va = *(const float4*)(A + (size_t)ma * lda + lc4);
    if (nb < N) vb = *(const float4*)(W + (size_t)nb * ldw + lc4);
    for (int k0 = 0; k0 < K; k0 += BK) {
        __syncthreads();
        As[lc4 + 0][lr] = va.x; As[lc4 + 1][lr] = va.y;
        As[lc4 + 2][lr] = va.z; As[lc4 + 3][lr] = va.w;
        Bs[lc4 + 0][lr] = vb.x; Bs[lc4 + 1][lr] = vb.y;
        Bs[lc4 + 2][lr] = vb.z; Bs[lc4 + 3][lr] = vb.w;
        __syncthreads();
        if (k0 + BK < K) {
            if (ma < M) va = *(const float4*)(A + (size_t)ma * lda + k0 + BK + lc4);
            if (nb < N) vb = *(const float4*)(W + (size_t)nb * ldw + k0 + BK + lc4);
        }
        #pragma unroll
        for (int kk = 0; kk < BK; ++kk) {
            float a[TM], bfr[TN];
            #pragma unroll
            for (int i = 0; i < TM; i += 4)
                *(float4*)&a[i] = *(const float4*)&As[kk][ty * TM + i];
            #pragma unroll
            for (int j = 0; j < TN; j += 4)
                *(float4*)&bfr[j] = *(const float4*)&Bs[kk][tx * TN + j];
            #pragma unroll
            for (int i = 0; i < TM; i++)
                #pragma unroll
                for (int j = 0; j < TN; j++) acc[i][j] = fmaf(a[i], bfr[j], acc[i][j]);
        }
    }
    #pragma unroll
    for (int i = 0; i < TM; i++) {
        int m = m0 + ty * TM + i;
        if (m >= M) continue;
        #pragma unroll
        for (int j = 0; j < TN; j++) {
            int n = n0 + tx * TN + j;
            if (n >= N) continue;
            float v = acc[i][j];
            if (bias) v += bias[n];
            if (act == 2) v = softplus_f(v);
            C[(size_t)m * ldc + n] = v;
        }
    }
}

// ---------------------------------------------------------------------------
// Depthwise conv1d (K=4, pad(1,2)) in [b,l,d], bf16 in -> bf16 out (xlb == u).
// ---------------------------------------------------------------------------
__global__ __launch_bounds__(256) void dwconv(
    const ushort* __restrict__ xib, const float* __restrict__ cw,
    const float* __restrict__ cb, ushort* __restrict__ xlb)
{
    int idx = blockIdx.x * 256 + threadIdx.x;   // 524288
    int d4 = (idx & 127) * 4;
    int bl = idx >> 7;
    int b = bl >> 10, l = bl & 1023;
    float4 w0 = *(const float4*)(cw + d4 * 4);
    float4 w1 = *(const float4*)(cw + d4 * 4 + 4);
    float4 w2 = *(const float4*)(cw + d4 * 4 + 8);
    float4 w3 = *(const float4*)(cw + d4 * 4 + 12);
    float4 acc = *(const float4*)(cb + d4);
    const ushort* rowb = xib + ((size_t)b << 19) + d4;
    #pragma unroll
    for (int k = 0; k < 4; ++k) {
        int ll = l + k - 1;
        if ((unsigned)ll < 1024u) {
            uint2 p = *(const uint2*)(rowb + (size_t)ll * 512);
            acc.x = fmaf(bf2f((ushort)(p.x & 0xffffu)), ((const float*)&w0)[k], acc.x);
            acc.y = fmaf(bf2f((ushort)(p.x >> 16)),     ((const float*)&w1)[k], acc.y);
            acc.z = fmaf(bf2f((ushort)(p.y & 0xffffu)), ((const float*)&w2)[k], acc.z);
            acc.w = fmaf(bf2f((ushort)(p.y >> 16)),     ((const float*)&w3)[k], acc.w);
        }
    }
    uint2 pk;
    pk.x = (uint)f2bf(acc.x) | ((uint)f2bf(acc.y) << 16);
    pk.y = (uint)f2bf(acc.z) | ((uint)f2bf(acc.w) << 16);
    *(uint2*)(xlb + (size_t)bl * 512 + d4) = pk;
}

// ---------------------------------------------------------------------------
// Chunked scan pass 1 (fused dt_proj, 4-step composition, bf16 Tu/TB).
// 16 chunks of 64 timesteps: grid 1024 blocks (4 blocks/CU). ~28KB LDS.
// ---------------------------------------------------------------------------
__global__ __launch_bounds__(512, 8) void scan_part1(
    const float* __restrict__ xdbl, const ushort* __restrict__ xlb,
    const float* __restrict__ dpw, const float* __restrict__ dpb,
    const float* __restrict__ alog,
    float* __restrict__ Psum, float* __restrict__ hFsum)
{
    __shared__ float Td[32][68];
    __shared__ __align__(8) ushort Tu[32][68];
    __shared__ __align__(8) ushort TB[16][68];
    __shared__ __align__(16) float xd[64][32];
    __shared__ float dpw_s[32][33];
    __shared__ float dpb_s[32];
    int t = threadIdx.x;
    int bid = blockIdx.x;                 // 1024 = b(4) x dgG(16) x ch(16)
    int ch = bid & 15, dgG = (bid >> 4) & 15, b = bid >> 8;
    int d0 = dgG * 32;
    int bl0 = b * 1024 + ch * 64;
    {   // xd: 64 l x 32 k, one float4/thread
        int l = t >> 3, k4 = (t & 7) * 4;
        float4 v = *(const float4*)(xdbl + (size_t)(bl0 + l) * 64 + k4);
        *(float4*)&xd[l][k4] = v;
    }
    if (t < 256) {   // Tu: 64 l x 32 d (raw bf16 copy)
        int l = t >> 2, d8 = (t & 3) * 8;
        uint4 p = *(const uint4*)(xlb + (size_t)(bl0 + l) * 512 + d0 + d8);
        Tu[d8 + 0][l] = (ushort)(p.x & 0xffffu);
        Tu[d8 + 1][l] = (ushort)(p.x >> 16);
        Tu[d8 + 2][l] = (ushort)(p.y & 0xffffu);
        Tu[d8 + 3][l] = (ushort)(p.y >> 16);
        Tu[d8 + 4][l] = (ushort)(p.z & 0xffffu);
        Tu[d8 + 5][l] = (ushort)(p.z >> 16);
        Tu[d8 + 6][l] = (ushort)(p.w & 0xffffu);
        Tu[d8 + 7][l] = (ushort)(p.w >> 16);
    } else {         // TB: 64 l x 16 n
        int tt = t - 256;
        int l = tt >> 2, n4 = (tt & 3) * 4;
        float4 bv = *(const float4*)(xdbl + (size_t)(bl0 + l) * 64 + 32 + n4);
        TB[n4 + 0][l] = f2bf(bv.x); TB[n4 + 1][l] = f2bf(bv.y);
        TB[n4 + 2][l] = f2bf(bv.z); TB[n4 + 3][l] = f2bf(bv.w);
    }
    #pragma unroll
    for (int r = 0; r < 2; ++r) {
        int idx = r * 512 + t;
        int dd = idx >> 5, kk = idx & 31;
        dpw_s[dd][kk] = dpw[(size_t)(d0 + dd) * 32 + kk];
    }
    if (t < 32) dpb_s[t] = dpb[d0 + t];
    __syncthreads();
    {   // fused dt_proj: 32 dd x 64 l, 4 entries/thread
        int dd = t & 31, lb = (t >> 5) * 4;
        #pragma unroll
        for (int j = 0; j < 4; ++j) {
            int l = lb + j;
            float s = dpb_s[dd];
            #pragma unroll
            for (int k = 0; k < 32; ++k) s = fmaf(xd[l][k], dpw_s[dd][k], s);
            Td[dd][l] = softplus_f(s);
        }
    }
    __syncthreads();
    int w = t >> 6, lane = t & 63;
    int dl = lane >> 4, n = lane & 15;
    int col = w * 4 + dl;
    int d = d0 + col;
    float Ac = -__expf(alog[d * 16 + n]);
    float h = 0.f, P = 1.f;
    for (int l4 = 0; l4 < 16; ++l4) {
        float4 de = *(const float4*)&Td[col][l4 * 4];
        uint2 tu2 = *(const uint2*)&Tu[col][l4 * 4];
        uint2 tb2 = *(const uint2*)&TB[n][l4 * 4];
        float ux = bf2f((ushort)(tu2.x & 0xffffu)), uy = bf2f((ushort)(tu2.x >> 16));
        float uz = bf2f((ushort)(tu2.y & 0xffffu)), uw = bf2f((ushort)(tu2.y >> 16));
        float Bx = bf2f((ushort)(tb2.x & 0xffffu)), By = bf2f((ushort)(tb2.x >> 16));
        float Bz = bf2f((ushort)(tb2.y & 0xffffu)), Bw = bf2f((ushort)(tb2.y >> 16));
        float a1 = __expf(de.x * Ac), a2 = __expf(de.y * Ac);
        float a3 = __expf(de.z * Ac), a4 = __expf(de.w * Ac);
        float b1 = de.x * Bx * ux, b2 = de.y * By * uy;
        float b3 = de.z * Bz * uz, b4 = de.w * Bw * uw;
        float a21 = a2 * a1,     b21 = fmaf(a2, b1, b2);
        float a321 = a3 * a21,   b321 = fmaf(a3, b21, b3);
        float a4321 = a4 * a321, b4321 = fmaf(a4, b321, b4);
        h = fmaf(a4321, h, b4321);
        P *= a4321;
    }
    size_t si = ((size_t)(b * 128 + dgG * 8 + w) * 16 + ch) * 64 + lane;
    Psum[si] = P;
    hFsum[si] = h;
}

// ---------------------------------------------------------------------------
// Chunked scan pass 2 (fused dt_proj, 4-step composition, bf16 staging,
// packed yb2, xd overlaid on TB/TC/yb2 union). 64-timestep chunks. ~26KB LDS.
// ---------------------------------------------------------------------------
__global__ __launch_bounds__(512, 8) void scan_part2(
    const float* __restrict__ xdbl, const ushort* __restrict__ xlb,
    const float* __restrict__ dpw, const float* __restrict__ dpb,
    const float* __restrict__ alog, const float* __restrict__ dssm,
    const ushort* __restrict__ resb, ushort* __restrict__ ybb,
    const float* __restrict__ Psum, const float* __restrict__ hFsum)
{
    __shared__ float Td[32][68];
    __shared__ __align__(8) ushort Tu[32][68];
    // union: xd fp32[64][32] (8192B) overlays TB(2176)+TC(2176)+yb2(4224)=8576B
    __shared__ __align__(16) unsigned char uni[8576];
    __shared__ float dpw_s[32][33];
    __shared__ float dpb_s[32];
    float* xd = (float*)uni;                          // [64][32]
    ushort (*TB)[68] = (ushort(*)[68])uni;            // [16][68]
    ushort (*TC)[68] = (ushort(*)[68])(uni + 2176);   // [16][68]
    uint (*yb2)[33] = (uint(*)[33])(uni + 4352);      // [32][33]
    int t = threadIdx.x;
    int bid = blockIdx.x;                 // 1024 = b(4) x dgG(16) x ch(16)
    int ch = bid & 15, dgG = (bid >> 4) & 15, b = bid >> 8;
    int d0 = dgG * 32;
    int bl0 = b * 1024 + ch * 64;
    {   // xd into union
        int l = t >> 3, k4 = (t & 7) * 4;
        float4 v = *(const float4*)(xdbl + (size_t)(bl0 + l) * 64 + k4);
        *(float4*)&xd[l * 32 + k4] = v;
    }
    if (t < 256) {   // Tu
        int l = t >> 2, d8 = (t & 3) * 8;
        uint4 p = *(const uint4*)(xlb + (size_t)(bl0 + l) * 512 + d0 + d8);
        Tu[d8 + 0][l] = (ushort)(p.x & 0xffffu);
        Tu[d8 + 1][l] = (ushort)(p.x >> 16);
        Tu[d8 + 2][l] = (ushort)(p.y & 0xffffu);
        Tu[d8 + 3][l] = (ushort)(p.y >> 16);
        Tu[d8 + 4][l] = (ushort)(p.z & 0xffffu);
        Tu[d8 + 5][l] = (ushort)(p.z >> 16);
        Tu[d8 + 6][l] = (ushort)(p.w & 0xffffu);
        Tu[d8 + 7][l] = (ushort)(p.w >> 16);
    }
    #pragma unroll
    for (int r = 0; r < 2; ++r) {
        int idx = r * 512 + t;
        int dd = idx >> 5, kk = idx & 31;
        dpw_s[dd][kk] = dpw[(size_t)(d0 + dd) * 32 + kk];
    }
    if (t < 32) dpb_s[t] = dpb[d0 + t];
    __syncthreads();
    {   // fused dt_proj (reads xd)
        int dd = t & 31, lb = (t >> 5) * 4;
        #pragma unroll
        for (int j = 0; j < 4; ++j) {
            int l = lb + j;
            float s = dpb_s[dd];
            #pragma unroll
            for (int k = 0; k < 32; ++k) s = fmaf(xd[l * 32 + k], dpw_s[dd][k], s);
            Td[dd][l] = softplus_f(s);
        }
    }
    __syncthreads();   // xd dead; Td visible
    if (t < 256) {     // TB/TC over dead xd
        int l = t >> 2, n4 = (t & 3) * 4;
        float4 bv = *(const float4*)(xdbl + (size_t)(bl0 + l) * 64 + 32 + n4);
        float4 cv = *(const float4*)(xdbl + (size_t)(bl0 + l) * 64 + 48 + n4);
        TB[n4 + 0][l] = f2bf(bv.x); TB[n4 + 1][l] = f2bf(bv.y);
        TB[n4 + 2][l] = f2bf(bv.z); TB[n4 + 3][l] = f2bf(bv.w);
        TC[n4 + 0][l] = f2bf(cv.x); TC[n4 + 1][l] = f2bf(cv.y);
        TC[n4 + 2][l] = f2bf(cv.z); TC[n4 + 3][l] = f2bf(cv.w);
    }
    int w = t >> 6, lane = t & 63;
    int dl = lane >> 4, n = lane & 15;
    int col = w * 4 + dl;
    int d = d0 + col;
    float Ac = -__expf(alog[d * 16 + n]);
    float Dd = dssm[d];
    float h = 0.f;
    {
        size_t sbase = (size_t)(b * 128 + dgG * 8 + w) * 1024 + lane;
        for (int cc = 0; cc < ch; ++cc) {
            float Pv = Psum[sbase + (size_t)cc * 64];
            float hv = hFsum[sbase + (size_t)cc * 64];
            h = Pv * h + hv;
        }
    }
    __syncthreads();   // TB/TC visible
    for (int l4 = 0; l4 < 16; ++l4) {
        float4 de = *(const float4*)&Td[col][l4 * 4];
        uint2 tu2 = *(const uint2*)&Tu[col][l4 * 4];
        uint2 tb2 = *(const uint2*)&TB[n][l4 * 4];
        uint2 tc2 = *(const uint2*)&TC[n][l4 * 4];
        float ux = bf2f((ushort)(tu2.x & 0xffffu)), uy = bf2f((ushort)(tu2.x >> 16));
        float uz = bf2f((ushort)(tu2.y & 0xffffu)), uw = bf2f((ushort)(tu2.y >> 16));
        float Bx = bf2f((ushort)(tb2.x & 0xffffu)), By = bf2f((ushort)(tb2.x >> 16));
        float Bz = bf2f((ushort)(tb2.y & 0xffffu)), Bw = bf2f((ushort)(tb2.y >> 16));
        float Cx = bf2f((ushort)(tc2.x & 0xffffu)), Cy = bf2f((ushort)(tc2.x >> 16));
        float Cz = bf2f((ushort)(tc2.y & 0xffffu)), Cw = bf2f((ushort)(tc2.y >> 16));
        float a1 = __expf(de.x * Ac), a2 = __expf(de.y * Ac);
        float a3 = __expf(de.z * Ac), a4 = __expf(de.w * Ac);
        float b1 = de.x * Bx * ux, b2 = de.y * By * uy;
        float b3 = de.z * Bz * uz, b4 = de.w * Bw * uw;
        float a21 = a2 * a1,     b21 = fmaf(a2, b1, b2);
        float a321 = a3 * a21,   b321 = fmaf(a3, b21, b3);
        float a4321 = a4 * a321, b4321 = fmaf(a4, b321, b4);
        float h1 = fmaf(a1, h, b1);
        float h2 = fmaf(a21, h, b21);
        float h3 = fmaf(a321, h, b321);
        float h4 = fmaf(a4321, h, b4321);
        h = h4;
        float p0 = h1 * Cx, p1 = h2 * Cy, p2 = h3 * Cz, p3 = h4 * Cw;
        #pragma unroll
        for (int off = 1; off < 16; off <<= 1) {
            p0 += __shfl_xor(p0, off);
            p1 += __shfl_xor(p1, off);
            p2 += __shfl_xor(p2, off);
            p3 += __shfl_xor(p3, off);
        }
        if (n == 0) {
            int l2 = l4 * 2;
            float y0 = fmaf(ux, Dd, p0), y1 = fmaf(uy, Dd, p1);
            float y2 = fmaf(uz, Dd, p2), y3 = fmaf(uw, Dd, p3);
            yb2[l2 + 0][col] = (uint)f2bf(y0) | ((uint)f2bf(y1) << 16);
            yb2[l2 + 1][col] = (uint)f2bf(y2) | ((uint)f2bf(y3) << 16);
        }
    }
    __syncthreads();
    // gated store: 32 l2 x 32 col = 1024 items over 512 threads x 2
    size_t base = ((size_t)(b * 1024 + ch * 64)) * 512 + d0;   // ushort offset
    #pragma unroll
    for (int j = 0; j < 2; ++j) {
        int idx = j * 512 + t;
        int l2 = idx >> 5, col2 = idx & 31;
        uint yv = yb2[l2][col2];
        int l0 = l2 * 2;
        float r0 = bf2f(resb[base + (size_t)l0 * 512 + col2]);
        float r1 = bf2f(resb[base + (size_t)(l0 + 1) * 512 + col2]);
        float y0 = bf2f((ushort)(yv & 0xffffu)) * r0;
        float y1 = bf2f((ushort)(yv >> 16)) * r1;
        ybb[base + (size_t)l0 * 512 + col2] = f2bf(y0);
        ybb[base + (size_t)(l0 + 1) * 512 + col2] = f2bf(y1);
    }
}

// s[row] = LN(o[row])*g + b + s[row]; also writes bf16 copy sb. One wave/row.
__global__ __launch_bounds__(256) void ln_res_kernel(
    const float* __restrict__ o, const float* __restrict__ g,
    const float* __restrict__ bb, float* __restrict__ s, ushort* __restrict__ sb)
{
    int row = blockIdx.x * 4 + (threadIdx.x >> 6);
    int lane = threadIdx.x & 63;
    const float4* orow = (const float4*)(o + (size_t)row * 256);
    float4 v = orow[lane];
    float sum = v.x + v.y + v.z + v.w;
    float sq = v.x * v.x + v.y * v.y + v.z * v.z + v.w * v.w;
    #pragma unroll
    for (int off = 1; off < 64; off <<= 1) {
        sum += __shfl_xor(sum, off);
        sq += __shfl_xor(sq, off);
    }
    float m = sum * (1.f / 256.f);
    float var = sq * (1.f / 256.f) - m * m;
    float rstd = rsqrtf(var + 1e-5f);
    float4 gg = ((const float4*)g)[lane];
    float4 bv = ((const float4*)bb)[lane];
    float4* srow = (float4*)(s + (size_t)row * 256);
    float4 sv = srow[lane];
    sv.x += (v.x - m) * rstd * gg.x + bv.x;
    sv.y += (v.y - m) * rstd * gg.y + bv.y;
    sv.z += (v.z - m) * rstd * gg.z + bv.z;
    sv.w += (v.w - m) * rstd * gg.w + bv.w;
    srow[lane] = sv;
    uint2 pk;
    pk.x = (uint)f2bf(sv.x) | ((uint)f2bf(sv.y) << 16);
    pk.y = (uint)f2bf(sv.z) | ((uint)f2bf(sv.w) << 16);
    *(uint2*)(sb + (size_t)row * 256 + lane * 4) = pk;
}

// mean over l then LN over 256 channels. grid 4 x 256.
__global__ __launch_bounds__(256) void pool_ln_kernel(
    const float* __restrict__ s, const float* __restrict__ nw,
    const float* __restrict__ nb, float* __restrict__ sln)
{
    int b = blockIdx.x, c = threadIdx.x;
    const float* p = s + (size_t)b * 262144 + c;
    float acc = 0.f;
    for (int l = 0; l < 1024; ++l) acc += p[(size_t)l * 256];
    float pooled = acc * (1.f / 1024.f);
    __shared__ float rs[4], rq[4];
    float sum = pooled, sq = pooled * pooled;
    #pragma unroll
    for (int off = 1; off < 64; off <<= 1) {
        sum += __shfl_xor(sum, off);
        sq += __shfl_xor(sq, off);
    }
    int w = threadIdx.x >> 6;
    if ((threadIdx.x & 63) == 0) { rs[w] = sum; rq[w] = sq; }
    __syncthreads();
    sum = rs[0] + rs[1] + rs[2] + rs[3];
    sq = rq[0] + rq[1] + rq[2] + rq[3];
    float m = sum * (1.f / 256.f);
    float var = sq * (1.f / 256.f) - m * m;
    float rstd = rsqrtf(var + 1e-5f);
    sln[b * 256 + c] = (pooled - m) * rstd * nw[c] + nb[c];
}

// softmax over 1000 logits per b
__global__ __launch_bounds__(256) void softmax_kernel(float* __restrict__ out)
{
    int b = threadIdx.x >> 6, lane = threadIdx.x & 63;
    const float* lg = out + b * 1000;
    float v[16];
    float mx = -1e30f;
    #pragma unroll
    for (int j = 0; j < 16; ++j) {
        int i = lane + j * 64;
        v[j] = (i < 1000) ? lg[i] : -1e30f;
        mx = fmaxf(mx, v[j]);
    }
    #pragma unroll
    for (int off = 1; off < 64; off <<= 1) mx = fmaxf(mx, __shfl_xor(mx, off));
    float sum = 0.f;
    #pragma unroll
    for (int j = 0; j < 16; ++j) {
        int i = lane + j * 64;
        if (i < 1000) { v[j] = __expf(v[j] - mx); sum += v[j]; }
    }
    #pragma unroll
    for (int off = 1; off < 64; off <<= 1) sum += __shfl_xor(sum, off);
    float inv = 1.f / sum;
    float* so = out + 4000 + b * 1000;
    #pragma unroll
    for (int j = 0; j < 16; ++j) {
        int i = lane + j * 64;
        if (i < 1000) so[i] = v[j] * inv;
    }
}

// ---------------------------------------------------------------------------
extern "C" void kernel_launch(void* const* d_in, const int* in_sizes, int n_in,
                              void* d_out, int out_size, void* d_ws, size_t ws_size,
                              hipStream_t stream)
{
    const float* x    = (const float*)d_in[0];
    const float* c1w  = (const float*)d_in[1];
    const float* c1b  = (const float*)d_in[2];
    const float* g1   = (const float*)d_in[3];
    const float* b1   = (const float*)d_in[4];
    const float* c2w  = (const float*)d_in[5];
    const float* c2b  = (const float*)d_in[6];
    const float* g2   = (const float*)d_in[7];
    const float* b2   = (const float*)d_in[8];
    const float* pw   = (const float*)d_in[9];
    const float* pb   = (const float*)d_in[10];
    const float* g3   = (const float*)d_in[11];
    const float* b3   = (const float*)d_in[12];
    const float* ipw  = (const float*)d_in[13];
    const float* ipb  = (const float*)d_in[14];
    const float* cw   = (const float*)d_in[15];
    const float* cb   = (const float*)d_in[16];
    const float* xpw  = (const float*)d_in[17];
    const float* dpw  = (const float*)d_in[18];
    const float* dpb  = (const float*)d_in[19];
    const float* alog = (const float*)d_in[20];
    const float* dssm = (const float*)d_in[21];
    const float* opw  = (const float*)d_in[22];
    const float* opb  = (const float*)d_in[23];
    const float* lnw  = (const float*)d_in[24];
    const float* lnb  = (const float*)d_in[25];
    const float* nw   = (const float*)d_in[26];
    const float* nb   = (const float*)d_in[27];
    const float* fcw  = (const float*)d_in[28];
    const float* fcb  = (const float*)d_in[29];
    float* out = (float*)d_out;
    float* wsf = (float*)d_ws;

    float*  s_   = wsf;
    ushort* sb   = (ushort*)(wsf + 1048576);
    ushort* xib  = (ushort*)(wsf + 1572864);
    ushort* h2b  = (ushort*)(wsf + 1572864);
    float*  obuf = wsf + 1572864;
    ushort* resb = (ushort*)(wsf + 3670016);
    ushort* xlb  = (ushort*)(wsf + 4718592);   // == u == ybb (in-place gate)
    ushort* ybb  = (ushort*)(wsf + 4718592);
    ushort* h1b  = (ushort*)(wsf + 4718592);
    ushort* Apb  = (ushort*)(wsf + 6815744);
    float*  xdbl = wsf + 8912896;
    ushort* ipwb = (ushort*)(wsf + 9175040);
    ushort* opwb = (ushort*)(wsf + 9699328);
    ushort* w2b  = (ushort*)(wsf + 9961472);
    ushort* pwTb = (ushort*)(wsf + 10108928);
    float*  sln  = wsf + 10240000;
    float*  Psum = wsf + 10241024;             // [4][128][16][64] = 524288 fl
    float*  hFsum= wsf + 10765312;             // 524288 fl
    ushort* xpwb = (ushort*)(wsf + 11289600);  // 131072 ushorts; end 11355136 fl

    // --- fused weight prep (1 dispatch) ---
    hipLaunchKernelGGL(wprep, dim3(8832), dim3(256), 0, stream,
                       ipw, opw, c2w, pw, xpw, ipwb, opwb, w2b, pwTb, xpwb);

    // --- conv stem ---
    hipLaunchKernelGGL(conv1_nhwc, dim3(256), dim3(256), 0, stream, x, c1w, c1b, g1, b1, h1b);
    hipLaunchKernelGGL(conv2_mfma, dim3(128, 4), dim3(256), 0, stream, h1b, w2b, c2b, g2, b2, h2b);
    hipLaunchKernelGGL(im2col_bf16, dim3(2048), dim3(256), 0, stream, h2b, Apb);
    hipLaunchKernelGGL((mfma_gemm_bt<64, 64, 2>), dim3(64, 4), dim3(256), 0, stream,
                       Apb, 1024, pwTb, 1024, pb, g3, b3, s_, sb, nullptr, 256, 1024);

    // --- mamba blocks ---
    for (int i = 0; i < 4; ++i) {
        const ushort* ipwb_i = ipwb + (size_t)i * 1024 * 256;
        const float*  ipb_i  = ipb + i * 1024;
        const float*  cw_i   = cw + i * 512 * 4;
        const float*  cb_i   = cb + i * 512;
        const ushort* xpwb_i = xpwb + (size_t)i * 64 * 512;
        const float*  dpw_i  = dpw + (size_t)i * 512 * 32;
        const float*  dpb_i  = dpb + i * 512;
        const float*  alog_i = alog + (size_t)i * 512 * 16;
        const float*  dssm_i = dssm + i * 512;
        const ushort* opwb_i = opwb + (size_t)i * 256 * 512;
        const float*  opb_i  = opb + i * 256;
        const float*  lnw_i  = lnw + i * 256;
        const float*  lnb_i  = lnb + i * 256;

        hipLaunchKernelGGL((mfma_gemm_bt<64, 128, 3>), dim3(64, 8), dim3(256), 0, stream,
                           sb, 256, ipwb_i, 256, ipb_i, nullptr, nullptr,
                           nullptr, xib, resb, 0, 256);
        hipLaunchKernelGGL(dwconv, dim3(2048), dim3(256), 0, stream, xib, cw_i, cb_i, xlb);
        hipLaunchKernelGGL((mfma_gemm_bt<64, 64, 0>), dim3(64, 1), dim3(256), 0, stream,
                           xlb, 512, xpwb_i, 512, nullptr, nullptr, nullptr,
                           xdbl, nullptr, nullptr, 64, 512);
        hipLaunchKernelGGL(scan_part1, dim3(1024), dim3(512), 0, stream,
                           xdbl, xlb, dpw_i, dpb_i, alog_i, Psum, hFsum);
        hipLaunchKernelGGL(scan_part2, dim3(1024), dim3(512), 0, stream,
                           xdbl, xlb, dpw_i, dpb_i, alog_i, dssm_i, resb, ybb, Psum, hFsum);
        hipLaunchKernelGGL((mfma_gemm_bt<64, 64, 0>), dim3(64, 4), dim3(256), 0, stream,
                           ybb, 512, opwb_i, 512, opb_i, nullptr, nullptr,
                           obuf, nullptr, nullptr, 256, 512);
        hipLaunchKernelGGL(ln_res_kernel, dim3(1024), dim3(256), 0, stream,
                           obuf, lnw_i, lnb_i, s_, sb);
    }

    // --- head ---
    hipLaunchKernelGGL(pool_ln_kernel, dim3(4), dim3(256), 0, stream, s_, nw, nb, sln);
    hipLaunchKernelGGL((gemm_kernel<64, 64, 16, 4, 4>), dim3(1, 16), dim3(256), 0, stream,
                       sln, 256, fcw, 256, fcb, out, 1000, 4, 1000, 256, 0);
    hipLaunchKernelGGL(softmax_kernel, dim3(1), dim3(256), 0, stream, out);
}